// Round 12
// baseline (496.454 us; speedup 1.0000x reference)
//
#include <hip/hip_runtime.h>

typedef unsigned short u16;
typedef __bf16 bf16x8 __attribute__((ext_vector_type(8)));
typedef float f32x4 __attribute__((ext_vector_type(4)));
typedef float f32x16 __attribute__((ext_vector_type(16)));
typedef unsigned short u16x8 __attribute__((ext_vector_type(8)));
typedef unsigned short u16x4 __attribute__((ext_vector_type(4)));

static constexpr size_t MD = 802816;   // 3136*256 elements

__device__ __forceinline__ u16 f2bf(float f) {
    __bf16 h = (__bf16)f;
    return __builtin_bit_cast(unsigned short, h);
}
__device__ __forceinline__ float bf2f(u16 u) {
    return __uint_as_float(((unsigned)u) << 16);
}
__device__ __forceinline__ float gelu_f(float x) {
    return 0.5f * x * (1.0f + erff(x * 0.70710678118654752f));
}
// pack two f32 -> two bf16 in one u32 (low = a, high = b)
__device__ __forceinline__ unsigned cvt_pk_bf16(float a, float b) {
    unsigned r;
    asm("v_cvt_pk_bf16_f32 %0, %1, %2" : "=v"(r) : "v"(a), "v"(b));
    return r;
}
// raw 2^x via the ISA instruction (v_exp_f32 -> D = 2^S0).
// NOTE: __builtin_amdgcn_exp2f gave WRONG results (R8/R9); inline asm pins it.
__device__ __forceinline__ float exp2_hw(float x) {
    float r;
    asm("v_exp_f32 %0, %1" : "=v"(r) : "v"(x));
    return r;
}
// async global->LDS, 16B per lane; LDS dest = wave-uniform base + lane*16
__device__ __forceinline__ void async16(const u16* g, u16* l) {
    __builtin_amdgcn_global_load_lds(
        (const __attribute__((address_space(1))) unsigned int*)g,
        (__attribute__((address_space(3))) unsigned int*)l, 16, 0, 0);
}
union u8_4 { u16x8 v8; u16x4 v4[2]; };
union bf8_4 { bf16x8 f; u16x4 h[2]; u16x8 v8; };

// ------------- bf16 GEMM core, 64x64 tile, BK=64, swapped epilogue ----------
__device__ __forceinline__ void gemm_core(
    const u16* __restrict__ A, int lda,
    const u16* __restrict__ Bt, int K,
    const float* __restrict__ bias,
    u16* __restrict__ C, int ldc, int act)
{
    __shared__ u16 As[64][72];
    __shared__ u16 Bs[64][72];
    const int tid  = threadIdx.x;
    const int wave = tid >> 6, lane = tid & 63;
    const int wr = wave >> 1, wc = wave & 1;
    const int l16 = lane & 15, kg = lane >> 4, kb = kg * 8;
    const int m0 = blockIdx.x * 64, n0 = blockIdx.y * 64;
    const int srow = tid >> 2, scol = (tid & 3) * 16;

    f32x4 acc[2][2];   // [n-frag][m-frag]
#pragma unroll
    for (int j = 0; j < 2; j++)
#pragma unroll
        for (int i = 0; i < 2; i++) { f32x4 z = {0.f,0.f,0.f,0.f}; acc[j][i] = z; }

    const u16* ap = A + (size_t)(m0 + srow) * lda + scol;
    const u16* bp = Bt + (size_t)(n0 + srow) * K + scol;
    u16x8 ua0 = *(const u16x8*)ap;
    u16x8 ua1 = *(const u16x8*)(ap + 8);
    u16x8 ub0 = *(const u16x8*)bp;
    u16x8 ub1 = *(const u16x8*)(bp + 8);

    for (int kt = 0; kt < K; kt += 64) {
        *(u16x8*)&As[srow][scol]     = ua0;
        *(u16x8*)&As[srow][scol + 8] = ua1;
        *(u16x8*)&Bs[srow][scol]     = ub0;
        *(u16x8*)&Bs[srow][scol + 8] = ub1;
        __syncthreads();
        if (kt + 64 < K) {
            ua0 = *(const u16x8*)(ap + kt + 64);
            ua1 = *(const u16x8*)(ap + kt + 72);
            ub0 = *(const u16x8*)(bp + kt + 64);
            ub1 = *(const u16x8*)(bp + kt + 72);
        }
#pragma unroll
        for (int h = 0; h < 2; h++) {
            bf16x8 af[2], bf[2];
#pragma unroll
            for (int j = 0; j < 2; j++)
                af[j] = *(const bf16x8*)&Bs[wc*32 + j*16 + l16][h*32 + kb];
#pragma unroll
            for (int i = 0; i < 2; i++)
                bf[i] = *(const bf16x8*)&As[wr*32 + i*16 + l16][h*32 + kb];
#pragma unroll
            for (int j = 0; j < 2; j++)
#pragma unroll
                for (int i = 0; i < 2; i++)
                    acc[j][i] = __builtin_amdgcn_mfma_f32_16x16x32_bf16(
                        af[j], bf[i], acc[j][i], 0,0,0);
        }
        __syncthreads();
    }
#pragma unroll
    for (int j = 0; j < 2; j++) {
        int wcol = n0 + wc*32 + j*16 + kg*4;
        f32x4 bv = *(const f32x4*)&bias[wcol];
#pragma unroll
        for (int i = 0; i < 2; i++) {
            int row = m0 + wr*32 + i*16 + l16;
            u16x4 o;
#pragma unroll
            for (int r = 0; r < 4; r++) {
                float v = acc[j][i][r] + bv[r];
                if (act == 1) v = gelu_f(v);
                o[r] = f2bf(v);
            }
            *(u16x4*)&C[(size_t)row * ldc + wcol] = o;
        }
    }
}

// ------------- bf16 GEMM core, 128x128 tile, BK=32, global_load_lds ---------
// m97-structure port: linear LDS [128][32] (async dest must be lane-linear),
// 4 waves, 4x4 frags/wave, swapped epilogue. Rows >= 3136 read in-workspace
// slack (masked at C-write). N must be a multiple of 128.
__device__ __forceinline__ void gemm_big_core(
    const u16* __restrict__ A, int lda,
    const u16* __restrict__ Bt, int K,
    const float* __restrict__ bias,
    u16* __restrict__ C, int ldc, int act)
{
    __shared__ u16 As[128*32];
    __shared__ u16 Bs[128*32];
    const int tid = threadIdx.x;
    const int wave = tid >> 6, lane = tid & 63;
    const int wr = wave >> 1, wc = wave & 1;
    const int l16 = lane & 15, kg = lane >> 4;
    const int m0 = blockIdx.x * 128, n0 = blockIdx.y * 128;

    f32x4 acc[4][4];
#pragma unroll
    for (int j = 0; j < 4; j++)
#pragma unroll
        for (int i = 0; i < 4; i++) { f32x4 z = {0.f,0.f,0.f,0.f}; acc[j][i] = z; }

    // staging: wave w covers rows [w*32, w*32+32) of both tiles, 2 calls each
    const u16* ag = A  + (size_t)(m0 + wave*32 + (lane >> 2)) * lda + (lane & 3) * 8;
    const u16* bg = Bt + (size_t)(n0 + wave*32 + (lane >> 2)) * K   + (lane & 3) * 8;
    u16* al0 = &As[(wave*32)      * 32];
    u16* al1 = &As[(wave*32 + 16) * 32];
    u16* bl0 = &Bs[(wave*32)      * 32];
    u16* bl1 = &Bs[(wave*32 + 16) * 32];

    for (int kt = 0; kt < K; kt += 32) {
        async16(ag + kt, al0);
        async16(ag + (size_t)16 * lda + kt, al1);
        async16(bg + kt, bl0);
        async16(bg + (size_t)16 * K + kt, bl1);
        __syncthreads();     // drains vmcnt (async LDS writes) + barrier
        bf16x8 af[4], bf[4];
#pragma unroll
        for (int f = 0; f < 4; f++) {
            af[f] = *(const bf16x8*)&Bs[(wc*64 + f*16 + l16)*32 + kg*8];
            bf[f] = *(const bf16x8*)&As[(wr*64 + f*16 + l16)*32 + kg*8];
        }
#pragma unroll
        for (int j = 0; j < 4; j++)
#pragma unroll
            for (int i = 0; i < 4; i++)
                acc[j][i] = __builtin_amdgcn_mfma_f32_16x16x32_bf16(
                    af[j], bf[i], acc[j][i], 0,0,0);
        __syncthreads();
    }
#pragma unroll
    for (int j = 0; j < 4; j++) {
        int wcol = n0 + wc*64 + j*16 + kg*4;
        f32x4 bv = *(const f32x4*)&bias[wcol];
#pragma unroll
        for (int i = 0; i < 4; i++) {
            int row = m0 + wr*64 + i*16 + l16;
            if (row < 3136) {
                u16x4 o;
#pragma unroll
                for (int r = 0; r < 4; r++) {
                    float v = acc[j][i][r] + bv[r];
                    if (act == 1) v = gelu_f(v);
                    o[r] = f2bf(v);
                }
                *(u16x4*)&C[(size_t)row * ldc + wcol] = o;
            }
        }
    }
}

// generic z-batched GEMM (64x64)
__global__ __launch_bounds__(256) void gemm2_kernel(
    const u16* __restrict__ A, int lda, int zA,
    const u16* __restrict__ Bt, int K, int i0, int i1, int i2, int i3, int Bsz,
    const float* __restrict__ bias, int bN,
    u16* __restrict__ C, int ldc, int zC, int act)
{
    int z = blockIdx.z;
    int iz = (z == 0) ? i0 : (z == 1) ? i1 : (z == 2) ? i2 : i3;
    gemm_core(A + (size_t)z * zA, lda,
              Bt + (size_t)iz * Bsz, K,
              bias + (size_t)iz * bN,
              C + (size_t)z * zC, ldc, act);
}

// z-batched GEMM (128x128, big grids only)
__global__ __launch_bounds__(256) void gemm_big2_kernel(
    const u16* __restrict__ A, int lda, int zA,
    const u16* __restrict__ Bt, int K, int i0, int i1, int i2, int i3, int Bsz,
    const float* __restrict__ bias, int bN,
    u16* __restrict__ C, int ldc, int zC, int act)
{
    int z = blockIdx.z;
    int iz = (z == 0) ? i0 : (z == 1) ? i1 : (z == 2) ? i2 : i3;
    gemm_big_core(A + (size_t)z * zA, lda,
                  Bt + (size_t)iz * Bsz, K,
                  bias + (size_t)iz * bN,
                  C + (size_t)z * zC, ldc, act);
}

// cat projections: z = inv*2 + ab; output [3136][768] per (inv,ab); 128^2 core
__global__ __launch_bounds__(256) void proj8_kernel(
    const u16* __restrict__ s, int b0, int b1, int b2, int b3,
    int i0, int i1, int i2, int i3,
    const u16* __restrict__ projWt, const float* __restrict__ biasc,
    u16* __restrict__ projc)
{
    int z = blockIdx.z;
    int inv = z >> 1, ab = z & 1;
    int bi = (inv == 0) ? b0 : (inv == 1) ? b1 : (inv == 2) ? b2 : b3;
    int ii = (inv == 0) ? i0 : (inv == 1) ? i1 : (inv == 2) ? i2 : i3;
    const u16* A = s + (size_t)(ab ? bi : inv) * MD;
    int widx = ii * 2 + ab;
    gemm_big_core(A, 256, projWt + (size_t)widx * 768 * 256, 256,
                  biasc + widx * 768,
                  projc + (size_t)z * 3 * MD, 768, 0);
}

__global__ __launch_bounds__(256) void pack_bias_kernel(
    const float* b0, const float* b1, const float* b2,
    const float* b3, const float* b4, const float* b5,
    float* __restrict__ biasc)
{
    int z = blockIdx.x;
    int tsr = z >> 2, i = z & 3;
    const float* barr[6] = {b0,b1,b2,b3,b4,b5};
    int ab = (tsr >= 3) ? 1 : 0;
    biasc[(i*2 + ab)*768 + (tsr % 3)*256 + threadIdx.x] = barr[tsr][i*256 + threadIdx.x];
}

// ---------------- flash attention core, 32x32x16 MFMA, 32 q-rows/wave -------
__device__ __forceinline__ void attn3_core(
    const u16* __restrict__ Qg, int ldq,
    const u16* __restrict__ Kg, int ldk,
    const u16* __restrict__ Vtg,          // [32 d][784 k] for this (b,h)
    u16* __restrict__ Og, int ldo,
    int qt, int rowbase, int qkcol, int ocol)
{
    __shared__ u16 Ks[2][64][36];
    __shared__ u16 Vts[2][32][68];
    __shared__ u16 Ps[4][32][68];
    __shared__ float Ls[4][32];

    const int tid = threadIdx.x, wave = tid >> 6, lane = tid & 63;
    const int l32 = lane & 31, hi = lane >> 5;
    const int sr = tid >> 2, sc8 = (tid & 3) * 8;     // K stage: 64r x 32c
    const int vd = tid >> 3, vk8 = (tid & 7) * 8;     // V stage: 32r x 64c
    const float QSC = 0.25503489f;        // 32^-0.5 * log2(e)

    // direct Q fragment load (pre-scaled): row = qt*128 + wave*32 + l32
    bf8_4 qf0, qf1;
    {
        int qrow = qt*128 + wave*32 + l32;
        u16x8 z8 = {0,0,0,0,0,0,0,0};
        u16x8 q0 = z8, q1 = z8;
        if (qrow < 784) {
            const u16* qp = Qg + (size_t)(rowbase + qrow) * ldq + qkcol;
            q0 = *(const u16x8*)(qp + hi*8);        // cols hi*8 .. hi*8+7
            q1 = *(const u16x8*)(qp + 16 + hi*8);   // cols 16+hi*8 ..
        }
#pragma unroll
        for (int j = 0; j < 8; j++) {
            q0[j] = f2bf(bf2f(q0[j]) * QSC);
            q1[j] = f2bf(bf2f(q1[j]) * QSC);
        }
        qf0.v8 = q0;
        qf1.v8 = q1;
    }
    {   // stage K,V tile 0 (all rows/cols valid)
        u8_4 k, v;
        k.v8 = *(const u16x8*)(Kg + (size_t)(rowbase + sr) * ldk + qkcol + sc8);
        v.v8 = *(const u16x8*)(Vtg + (size_t)vd * 784 + vk8);
        *(u16x4*)&Ks[0][sr][sc8]     = k.v4[0];
        *(u16x4*)&Ks[0][sr][sc8 + 4] = k.v4[1];
        *(u16x4*)&Vts[0][vd][vk8]     = v.v4[0];
        *(u16x4*)&Vts[0][vd][vk8 + 4] = v.v4[1];
    }
    __syncthreads();

    f32x16 oacc;
#pragma unroll
    for (int i = 0; i < 16; i++) oacc[i] = 0.f;
    float lsum = 0.f;

    u16x8 kr, vr;
    for (int t = 0; t < 13; ++t) {
        const int cur = t & 1;
        if (t < 12) {   // prefetch next tile into regs
            u16x8 z8 = {0,0,0,0,0,0,0,0}; kr = z8; vr = z8;
            int krow = (t+1)*64 + sr;
            if (krow < 784)
                kr = *(const u16x8*)(Kg + (size_t)(rowbase + krow) * ldk + qkcol + sc8);
            int kc = (t+1)*64 + vk8;
            if (kc + 7 < 784)
                vr = *(const u16x8*)(Vtg + (size_t)vd * 784 + kc);
        }
        const int kvalid = (t == 12) ? 16 : 64;
        // S^T (two 32k blocks): C row = k-local, col = q = l32
#pragma unroll
        for (int kb2 = 0; kb2 < 2; kb2++) {
            f32x16 sacc;
#pragma unroll
            for (int i = 0; i < 16; i++) sacc[i] = 0.f;
            bf8_4 kf0, kf1;
            kf0.h[0] = *(const u16x4*)&Ks[cur][kb2*32 + l32][hi*8];
            kf0.h[1] = *(const u16x4*)&Ks[cur][kb2*32 + l32][hi*8 + 4];
            kf1.h[0] = *(const u16x4*)&Ks[cur][kb2*32 + l32][16 + hi*8];
            kf1.h[1] = *(const u16x4*)&Ks[cur][kb2*32 + l32][16 + hi*8 + 4];
            sacc = __builtin_amdgcn_mfma_f32_32x32x16_bf16(kf0.f, qf0.f, sacc, 0,0,0);
            sacc = __builtin_amdgcn_mfma_f32_32x32x16_bf16(kf1.f, qf1.f, sacc, 0,0,0);
#pragma unroll
            for (int g = 0; g < 4; g++) {
                int k0 = kb2*32 + 8*g + 4*hi;
                union { unsigned u[2]; u16x4 v; } pk;
                if (k0 < kvalid) {
                    float p0 = exp2_hw(sacc[4*g+0]);
                    float p1 = exp2_hw(sacc[4*g+1]);
                    float p2 = exp2_hw(sacc[4*g+2]);
                    float p3 = exp2_hw(sacc[4*g+3]);
                    lsum += (p0 + p1) + (p2 + p3);
                    pk.u[0] = cvt_pk_bf16(p0, p1);
                    pk.u[1] = cvt_pk_bf16(p2, p3);
                } else { pk.u[0] = 0; pk.u[1] = 0; }
                *(u16x4*)&Ps[wave][l32][k0] = pk.v;
            }
        }
        // PV: O[q][d] += P[q][k] V[k][d], 4 k-frags of 16
#pragma unroll
        for (int kf2 = 0; kf2 < 4; kf2++) {
            bf8_4 pf, vf;
            pf.h[0] = *(const u16x4*)&Ps[wave][l32][kf2*16 + hi*8];
            pf.h[1] = *(const u16x4*)&Ps[wave][l32][kf2*16 + hi*8 + 4];
            vf.h[0] = *(const u16x4*)&Vts[cur][l32][kf2*16 + hi*8];
            vf.h[1] = *(const u16x4*)&Vts[cur][l32][kf2*16 + hi*8 + 4];
            oacc = __builtin_amdgcn_mfma_f32_32x32x16_bf16(pf.f, vf.f, oacc, 0,0,0);
        }
        __syncthreads();
        if (t < 12) {
            u8_4 k, v; k.v8 = kr; v.v8 = vr;
            *(u16x4*)&Ks[cur^1][sr][sc8]     = k.v4[0];
            *(u16x4*)&Ks[cur^1][sr][sc8 + 4] = k.v4[1];
            *(u16x4*)&Vts[cur^1][vd][vk8]     = v.v4[0];
            *(u16x4*)&Vts[cur^1][vd][vk8 + 4] = v.v4[1];
        }
        __syncthreads();
    }
    // total l per q (lane l32 and l32+32 hold the two halves)
    float lt = lsum + __shfl_xor(lsum, 32);
    if (hi == 0) Ls[wave][l32] = lt;
    f32x4 lv[4];
#pragma unroll
    for (int g = 0; g < 4; g++) lv[g] = *(const f32x4*)&Ls[wave][8*g + 4*hi];
    // O store: reg 4g+j -> row j+8g+4hi, col d = l32
#pragma unroll
    for (int g = 0; g < 4; g++)
#pragma unroll
        for (int j = 0; j < 4; j++) {
            int row = qt*128 + wave*32 + 8*g + 4*hi + j;
            if (row < 784)
                Og[(size_t)(rowbase + row) * ldo + ocol + l32] =
                    f2bf(oacc[4*g+j] * __builtin_amdgcn_rcpf(lv[g][j]));
        }
}

// group-of-4 attention: 1792 blocks; z = inv*2 + dir (Q side = dir, K/V = dir^1)
__global__ __launch_bounds__(256) void attn_pair_kernel(
    const u16* __restrict__ projc, const u16* __restrict__ vt,
    u16* __restrict__ fusedin)
{
    int id = blockIdx.x;
    int wg = (id & 7) * 224 + (id >> 3);      // 1792/8 = 224
    int qt = wg % 7, bh = (wg / 7) & 31, z = wg / 224;
    int inv = z >> 1, dir = z & 1;
    const u16* Q  = projc + (size_t)z * 3 * MD;
    const u16* K  = projc + (size_t)(z ^ 1) * 3 * MD + 256;
    const u16* Vt = vt + (size_t)z * MD + (size_t)bh * 32 * 784;
    u16* O = fusedin + (size_t)inv * 2 * MD;
    int bb = bh >> 3, hh = bh & 7;
    attn3_core(Q, 768, K, 768, Vt, O, 512, qt, bb*784, hh*32, dir*256 + hh*32);
}

__global__ __launch_bounds__(256) void attn_mha_kernel(
    const u16* __restrict__ qkv, const u16* __restrict__ vtmha,
    u16* __restrict__ outp)
{
    int id = blockIdx.x;
    int wg = (id & 7) * 28 + (id >> 3);       // 224/8 = 28
    int qt = wg % 7, bh = wg / 7;
    int bb = bh >> 3, hh = bh & 7;
    const u16* Vt = vtmha + (size_t)bh * 32 * 784;
    attn3_core(qkv, 768, qkv + 256, 768, Vt, outp, 256, qt, bb*784, hh*32, hh*32);
}

// ---------------- LayerNorm (bf16 io): out = [prev +] os*(LN(res + tg*x)) ---
__global__ __launch_bounds__(256) void ln_kernel(
    const u16* __restrict__ x, int zx,
    const u16* __restrict__ res, int zres,
    const float* __restrict__ gamma, int i0, int i1, int i2, int i3,
    const float* __restrict__ g, const float* __restrict__ beta, int gN,
    u16* __restrict__ out, int zout,
    float outscale, int accum, int D)
{
    int z = blockIdx.y;
    int iz = (z == 0) ? i0 : (z == 1) ? i1 : (z == 2) ? i2 : i3;
    const u16* xb = x + (size_t)z * zx;
    const u16* rb = res ? res + (size_t)z * zres : (const u16*)nullptr;
    u16* ob = out + (size_t)z * zout;
    const float* gg = g + iz * gN;
    const float* bb = beta + iz * gN;
    int wave = threadIdx.x >> 6, lane = threadIdx.x & 63;
    size_t row = (size_t)blockIdx.x * 4 + wave;
    float tg = gamma ? tanhf(gamma[iz]) : 1.0f;
    const u16* xr = xb + row * D;
    const u16* rr = rb ? rb + row * D : (const u16*)nullptr;
    float vals[16];
    int nch = D >> 8;
    float s = 0.f, s2 = 0.f;
    for (int c = 0; c < nch; c++) {
        int col = c * 256 + lane * 4;
        u16x4 v = *(const u16x4*)(xr + col);
#pragma unroll
        for (int j = 0; j < 4; j++) {
            float a = tg * bf2f(v[j]);
            if (rr) a += bf2f(rr[col + j]);
            vals[c*4 + j] = a;
            s += a; s2 += a * a;
        }
    }
    for (int off = 1; off < 64; off <<= 1) {
        s  += __shfl_xor(s, off);
        s2 += __shfl_xor(s2, off);
    }
    float inv = 1.0f / D;
    float mean = s * inv;
    float var = s2 * inv - mean * mean;
    float rstd = rsqrtf(var + 1e-5f);
    for (int c = 0; c < nch; c++) {
        int col = c * 256 + lane * 4;
#pragma unroll
        for (int j = 0; j < 4; j++) {
            float o = (vals[c*4 + j] - mean) * rstd * gg[col + j] + bb[col + j];
            o *= outscale;
            if (accum) o += bf2f(ob[row*D + col + j]);
            ob[row*D + col + j] = f2bf(o);
        }
    }
}

// ---------------- layout kernels --------------------------------------------
__device__ __forceinline__ void transpose_body(const float* in, u16* out, int K, int N)
{
    __shared__ float t[32][33];
    int tx = threadIdx.x, ty = threadIdx.y;   // (32,8)
#pragma unroll
    for (int j = 0; j < 4; j++)
        t[ty + j*8][tx] = in[(size_t)(blockIdx.y*32 + ty + j*8) * N + blockIdx.x*32 + tx];
    __syncthreads();
#pragma unroll
    for (int j = 0; j < 4; j++)
        out[(size_t)(blockIdx.x*32 + ty + j*8) * K + blockIdx.y*32 + tx] =
            f2bf(t[tx][ty + j*8]);
}

__global__ __launch_bounds__(256) void transpose_w(const float* __restrict__ in,
                                                   u16* __restrict__ out, int K, int N)
{
    int z = blockIdx.z;
    transpose_body(in + (size_t)z * K * N, out + (size_t)z * K * N, K, N);
}

// proj weights into cat layout: [i][ab][768 n][256 k]
__global__ __launch_bounds__(256) void transpose_w6(
    const float* w0, const float* w1, const float* w2,
    const float* w3, const float* w4, const float* w5,
    u16* __restrict__ out)
{
    int z = blockIdx.z;           // 0..23: tsr = z/4, i = z%4
    int tsr = z >> 2, i = z & 3;
    const float* ws[6] = {w0,w1,w2,w3,w4,w5};
    int ab = (tsr >= 3) ? 1 : 0;
    u16* ob = out + (size_t)((i*2 + ab)*3 + (tsr % 3)) * 65536;
    transpose_body(ws[tsr] + (size_t)i * 65536, ob, 256, 256);
}

// transpose V (cols 512..767 of a 768-wide qkv buffer) -> [z][bh*32+d][784]
__global__ __launch_bounds__(256) void vtrans_kernel(
    const u16* __restrict__ base, int mode,
    u16* __restrict__ outbase)
{
    __shared__ u16 t[64][44];
    int z = blockIdx.z;
    size_t off = (mode ? (size_t)0 : (size_t)(z ^ 1) * 3 * MD) + 512;
    const u16* in = base + off;
    u16* out = outbase + (size_t)z * MD;
    int kt = blockIdx.x, bh = blockIdx.y;
    int bb = bh >> 3, hh = bh & 7;
    int tid = threadIdx.x;
    {
        int r = tid >> 2, c8 = (tid & 3) * 8;
        int krow = kt*64 + r;
        u16x8 u = {0,0,0,0,0,0,0,0};
        if (krow < 784)
            u = *(const u16x8*)(in + (size_t)(bb*784 + krow) * 768 + hh*32 + c8);
        *(u16x8*)&t[r][c8] = u;
    }
    __syncthreads();
    int d = tid >> 3, k8 = (tid & 7) * 8;
    if (kt*64 + k8 + 7 < 784) {
        u16x8 u;
#pragma unroll
        for (int j = 0; j < 8; j++) u[j] = t[k8 + j][d];
        *(u16x8*)&out[(size_t)(bh*32 + d) * 784 + kt*64 + k8] = u;
    }
}

// f[B,256,28,28] fp32 -> s[fi][b*784+hw][d] bf16
__global__ __launch_bounds__(256) void to_seq_kernel(
    const float* f0, const float* f1, const float* f2, const float* f3,
    u16* __restrict__ sbase)
{
    __shared__ float t[16][17];
    int z = blockIdx.z;
    int fi = z & 3, b = z >> 2;
    const float* fs[4] = {f0,f1,f2,f3};
    const float* f = fs[fi] + (size_t)b * 256 * 784;
    u16* s = sbase + (size_t)fi * MD + (size_t)b * 784 * 256;
    int tx = threadIdx.x, ty = threadIdx.y;  // (16,16)
    t[ty][tx] = f[(size_t)(blockIdx.y*16 + ty) * 784 + blockIdx.x*16 + tx];
    __syncthreads();
    s[(size_t)(blockIdx.x*16 + ty) * 256 + blockIdx.y*16 + tx] = f2bf(t[tx][ty]);
}

// y[b*784+hw][d] bf16 -> out[b][d][h][w] fp32
__global__ __launch_bounds__(256) void from_seq_kernel(const u16* __restrict__ y,
                                                       float* __restrict__ out)
{
    __shared__ float t[16][17];
    int b = blockIdx.z;
    const u16* yb = y + (size_t)b * 784 * 256;
    float* ob = out + (size_t)b * 256 * 784;
    int tx = threadIdx.x, ty = threadIdx.y;
    t[ty][tx] = bf2f(yb[(size_t)(blockIdx.x*16 + ty) * 256 + blockIdx.y*16 + tx]);
    __syncthreads();
    ob[(size_t)(blockIdx.y*16 + ty) * 784 + blockIdx.x*16 + tx] = t[tx][ty];
}

// ---------------- host orchestration ----------------------------------------
extern "C" void kernel_launch(void* const* d_in, const int* in_sizes, int n_in,
                              void* d_out, int out_size, void* d_ws, size_t ws_size,
                              hipStream_t stream)
{
    (void)in_sizes; (void)n_in; (void)out_size; (void)ws_size;
    const float* f0 = (const float*)d_in[0];
    const float* f1 = (const float*)d_in[1];
    const float* f2 = (const float*)d_in[2];
    const float* f3 = (const float*)d_in[3];
    const float* Wq_a = (const float*)d_in[4];
    const float* Wk_a = (const float*)d_in[5];
    const float* Wv_a = (const float*)d_in[6];
    const float* Wq_b = (const float*)d_in[7];
    const float* Wk_b = (const float*)d_in[8];
    const float* Wv_b = (const float*)d_in[9];
    const float* bq_a = (const float*)d_in[10];
    const float* bk_a = (const float*)d_in[11];
    const float* bv_a = (const float*)d_in[12];
    const float* bq_b = (const float*)d_in[13];
    const float* bk_b = (const float*)d_in[14];
    const float* bv_b = (const float*)d_in[15];
    const float* gamma = (const float*)d_in[16];
    const float* gamma_ffn = (const float*)d_in[17];
    const float* Wfuse = (const float*)d_in[18];
    const float* bfuse = (const float*)d_in[19];
    const float* W1 = (const float*)d_in[20];
    const float* b1 = (const float*)d_in[21];
    const float* W2 = (const float*)d_in[22];
    const float* b2 = (const float*)d_in[23];
    const float* ln1_g = (const float*)d_in[24];
    const float* ln1_b = (const float*)d_in[25];
    const float* ln2_g = (const float*)d_in[26];
    const float* ln2_b = (const float*)d_in[27];
    const float* fp_ln_g = (const float*)d_in[28];
    const float* fp_ln_b = (const float*)d_in[29];
    const float* fp_W = (const float*)d_in[30];
    const float* fp_b = (const float*)d_in[31];
    const float* ff_ln_g = (const float*)d_in[32];
    const float* ff_ln_b = (const float*)d_in[33];
    const float* ff_W = (const float*)d_in[34];
    const float* ff_b = (const float*)d_in[35];
    const float* mha_Wqkv = (const float*)d_in[36];
    const float* mha_bqkv = (const float*)d_in[37];
    const float* mha_Wo = (const float*)d_in[38];
    const float* mha_bo = (const float*)d_in[39];
    const float* norm_g = (const float*)d_in[40];
    const float* norm_b = (const float*)d_in[41];

    u16* W = (u16*)d_ws;
    u16* projWt = W;                          // 24*65536 = 1572864
    u16* fuseWt = projWt + 1572864;           // 524288
    u16* W1t    = fuseWt + 524288;            // 1048576
    u16* W2t    = W1t + 1048576;              // 1048576
    u16* fpWt   = W2t + 1048576;              // 65536
    u16* ffWt   = fpWt + 65536;               // 262144
    u16* qkvWt  = ffWt + 262144;              // 196608
    u16* WoWt   = qkvWt + 196608;             // 65536
    float* biasc = (float*)(WoWt + 65536);    // 6144 floats
    u16* act    = (u16*)(biasc + 6144);

    u16* s     = act;               // 4 MD
    u16* e     = act + 4*MD;        // 4 MD
    u16* projc = act + 8*MD;        // 24 MD
    u16* vt    = act + 32*MD;       // 8 MD
    u16* fin   = act + 40*MD;       // 8 MD   (peak: 48 MD)
    // overlays (projc/vt dead at time of use)
    u16* ffh  = projc;              // 16 MD
    u16* fb   = projc + 16*MD;      // 4 MD
    u16* xa1  = projc + 20*MD;      // 4 MD
    u16* ffb  = vt;                 // 4 MD

    // input layout + weight pre-transpose
    to_seq_kernel<<<dim3(49,16,16), dim3(16,16), 0, stream>>>(f0,f1,f2,f3, s);
    transpose_w6<<<dim3(8,8,24), dim3(32,8), 0, stream>>>(Wq_a,Wk_a,Wv_a,Wq_b,Wk_b,Wv_b, projWt);
    pack_bias_kernel<<<24, 256, 0, stream>>>(bq_a,bk_a,bv_a,bq_b,bk_b,bv_b, biasc);
    transpose_w<<<dim3(8,16,4), dim3(32,8), 0, stream>>>(Wfuse, fuseWt, 512, 256);
    transpose_w<<<dim3(32,8,4), dim3(32,8), 0, stream>>>(W1, W1t, 256, 1024);
    transpose_w<<<dim3(8,32,4), dim3(32,8), 0, stream>>>(W2, W2t, 1024, 256);
    transpose_w<<<dim3(8,8,1),  dim3(32,8), 0, stream>>>(fp_W, fpWt, 256, 256);
    transpose_w<<<dim3(8,32,1), dim3(32,8), 0, stream>>>(ff_W, ffWt, 1024, 256);
    transpose_w<<<dim3(24,8,1), dim3(32,8), 0, stream>>>(mha_Wqkv, qkvWt, 256, 768);
    transpose_w<<<dim3(8,8,1),  dim3(32,8), 0, stream>>>(mha_Wo, WoWt, 256, 256);

    // two groups of 4 independent block invocations (a-side = s[inv]):
    // A = {bi0,bi2,bi4,bi6}: i={0,0,2,1}, b={1,0,1,0}, accum=0
    // B = {bi1,bi3,bi5,bi7}: i={1,2,3,3}, b={3,2,3,2}, accum=1
    const int GI[2][4] = {{0,0,2,1},{1,2,3,3}};
    const int GB[2][4] = {{1,0,1,0},{3,2,3,2}};

    for (int g = 0; g < 2; g++) {
        int i0 = GI[g][0], i1 = GI[g][1], i2 = GI[g][2], i3 = GI[g][3];
        proj8_kernel<<<dim3(25,6,8), 256, 0, stream>>>(s,
            GB[g][0], GB[g][1], GB[g][2], GB[g][3], i0, i1, i2, i3,
            projWt, biasc, projc);
        vtrans_kernel<<<dim3(13,32,8), 256, 0, stream>>>(projc, 0, vt);
        attn_pair_kernel<<<1792, 256, 0, stream>>>(projc, vt, fin);
        gemm2_kernel<<<dim3(49,4,4), 256, 0, stream>>>(fin, 512, (int)(2*MD),
            fuseWt, 512, i0, i1, i2, i3, 131072, bfuse, 256, fb, 256, (int)MD, 0);
        ln_kernel<<<dim3(784,4), 256, 0, stream>>>(fb, (int)MD,
            s, (int)MD, gamma, i0, i1, i2, i3, ln1_g, ln1_b, 256,
            xa1, (int)MD, 1.0f, 0, 256);
        gemm_big2_kernel<<<dim3(25,8,4), 256, 0, stream>>>(xa1, 256, (int)MD,
            W1t, 256, i0, i1, i2, i3, 262144, b1, 1024, ffh, 1024, (int)(4*MD), 1);
        gemm2_kernel<<<dim3(49,4,4), 256, 0, stream>>>(ffh, 1024, (int)(4*MD),
            W2t, 1024, i0, i1, i2, i3, 262144, b2, 256, ffb, 256, (int)MD, 0);
        ln_kernel<<<dim3(784,4), 256, 0, stream>>>(ffb, (int)MD,
            xa1, (int)MD, gamma_ffn, i0, i1, i2, i3, ln2_g, ln2_b, 256,
            e, (int)MD, 0.5f, g, 256);
    }

    // final fuse stage (reuse dead scratch; e live until first LN done)
    u16* ln4    = act + 8*MD;        // 4 MD
    u16* allf   = act + 12*MD;       // 4 MD  [3136][1024]
    u16* ffln   = act + 16*MD;       // 4 MD
    u16* x2     = act + 20*MD;       // 1 MD
    u16* qkv    = act + 21*MD;       // 3 MD  [3136][768]
    u16* vtmha  = act + 24*MD;       // 1 MD
    u16* attn_o = act + 25*MD;       // 1 MD
    u16* ymid   = act + 26*MD;       // 1 MD
    u16* yfin   = act + 27*MD;       // 1 MD

    ln_kernel<<<dim3(784,4), 256, 0, stream>>>(e, (int)MD,
        (const u16*)nullptr, 0, (const float*)nullptr, 0,0,0,0,
        fp_ln_g, fp_ln_b, 0, ln4, (int)MD, 1.0f, 0, 256);
    gemm2_kernel<<<dim3(49,4,4), 256, 0, stream>>>(ln4, 256, (int)MD,
        fpWt, 256, 0,0,0,0, 0, fp_b, 0, allf, 1024, 256, 1);
    ln_kernel<<<dim3(784,1), 256, 0, stream>>>(allf, 0,
        (const u16*)nullptr, 0, (const float*)nullptr, 0,0,0,0,
        ff_ln_g, ff_ln_b, 0, ffln, 0, 1.0f, 0, 1024);
    gemm2_kernel<<<dim3(49,4,1), 256, 0, stream>>>(ffln, 1024, 0,
        ffWt, 1024, 0,0,0,0, 0, ff_b, 0, x2, 256, 0, 1);
    gemm2_kernel<<<dim3(49,12,1), 256, 0, stream>>>(x2, 256, 0,
        qkvWt, 256, 0,0,0,0, 0, mha_bqkv, 0, qkv, 768, 0, 0);
    vtrans_kernel<<<dim3(13,32,1), 256, 0, stream>>>(qkv, 1, vtmha);
    attn_mha_kernel<<<224, 256, 0, stream>>>(qkv, vtmha, attn_o);
    gemm2_kernel<<<dim3(49,4,1), 256, 0, stream>>>(attn_o, 256, 0,
        WoWt, 256, 0,0,0,0, 0, mha_bo, 0, ymid, 256, 0, 0);
    ln_kernel<<<dim3(784,1), 256, 0, stream>>>(ymid, 0,
        (const u16*)nullptr, 0, (const float*)nullptr, 0,0,0,0,
        norm_g, norm_b, 0, yfin, 0, 1.0f, 0, 256);
    from_seq_kernel<<<dim3(49,16,4), dim3(16,16), 0, stream>>>(yfin, (float*)d_out);
}

// Round 13
// 438.489 us; speedup vs baseline: 1.1322x; 1.1322x over previous
//
#include <hip/hip_runtime.h>

typedef unsigned short u16;
typedef __bf16 bf16x8 __attribute__((ext_vector_type(8)));
typedef float f32x4 __attribute__((ext_vector_type(4)));
typedef float f32x16 __attribute__((ext_vector_type(16)));
typedef unsigned short u16x8 __attribute__((ext_vector_type(8)));
typedef unsigned short u16x4 __attribute__((ext_vector_type(4)));

static constexpr size_t MD = 802816;   // 3136*256 elements

__device__ __forceinline__ u16 f2bf(float f) {
    __bf16 h = (__bf16)f;
    return __builtin_bit_cast(unsigned short, h);
}
__device__ __forceinline__ float bf2f(u16 u) {
    return __uint_as_float(((unsigned)u) << 16);
}
__device__ __forceinline__ float gelu_f(float x) {
    return 0.5f * x * (1.0f + erff(x * 0.70710678118654752f));
}
// pack two f32 -> two bf16 in one u32 (low = a, high = b)
__device__ __forceinline__ unsigned cvt_pk_bf16(float a, float b) {
    unsigned r;
    asm("v_cvt_pk_bf16_f32 %0, %1, %2" : "=v"(r) : "v"(a), "v"(b));
    return r;
}
// raw 2^x via the ISA instruction (v_exp_f32 -> D = 2^S0).
// NOTE: __builtin_amdgcn_exp2f gave WRONG results (R8/R9); inline asm pins it.
__device__ __forceinline__ float exp2_hw(float x) {
    float r;
    asm("v_exp_f32 %0, %1" : "=v"(r) : "v"(x));
    return r;
}
union u8_4 { u16x8 v8; u16x4 v4[2]; };
union bf8_4 { bf16x8 f; u16x4 h[2]; u16x8 v8; };

// ------------- bf16 GEMM core, 64x64 tile, BK=64, swapped epilogue ----------
// C-tile staged through LDS (reusing As) so global stores are 32B/lane
// contiguous (4 lanes = full 128B row) — removes the 2x write amplification
// measured in R12 (WRITE_SIZE 50.7MB vs 25.6MB ideal with scattered 8B stores).
__device__ __forceinline__ void gemm_core(
    const u16* __restrict__ A, int lda,
    const u16* __restrict__ Bt, int K,
    const float* __restrict__ bias,
    u16* __restrict__ C, int ldc, int act)
{
    __shared__ u16 As[64][72];
    __shared__ u16 Bs[64][72];
    const int tid  = threadIdx.x;
    const int wave = tid >> 6, lane = tid & 63;
    const int wr = wave >> 1, wc = wave & 1;
    const int l16 = lane & 15, kg = lane >> 4, kb = kg * 8;
    const int m0 = blockIdx.x * 64, n0 = blockIdx.y * 64;
    const int srow = tid >> 2, scol = (tid & 3) * 16;

    f32x4 acc[2][2];   // [n-frag][m-frag]
#pragma unroll
    for (int j = 0; j < 2; j++)
#pragma unroll
        for (int i = 0; i < 2; i++) { f32x4 z = {0.f,0.f,0.f,0.f}; acc[j][i] = z; }

    const u16* ap = A + (size_t)(m0 + srow) * lda + scol;
    const u16* bp = Bt + (size_t)(n0 + srow) * K + scol;
    u16x8 ua0 = *(const u16x8*)ap;
    u16x8 ua1 = *(const u16x8*)(ap + 8);
    u16x8 ub0 = *(const u16x8*)bp;
    u16x8 ub1 = *(const u16x8*)(bp + 8);

    for (int kt = 0; kt < K; kt += 64) {
        *(u16x8*)&As[srow][scol]     = ua0;
        *(u16x8*)&As[srow][scol + 8] = ua1;
        *(u16x8*)&Bs[srow][scol]     = ub0;
        *(u16x8*)&Bs[srow][scol + 8] = ub1;
        __syncthreads();
        if (kt + 64 < K) {
            ua0 = *(const u16x8*)(ap + kt + 64);
            ua1 = *(const u16x8*)(ap + kt + 72);
            ub0 = *(const u16x8*)(bp + kt + 64);
            ub1 = *(const u16x8*)(bp + kt + 72);
        }
#pragma unroll
        for (int h = 0; h < 2; h++) {
            bf16x8 af[2], bf[2];
#pragma unroll
            for (int j = 0; j < 2; j++)
                af[j] = *(const bf16x8*)&Bs[wc*32 + j*16 + l16][h*32 + kb];
#pragma unroll
            for (int i = 0; i < 2; i++)
                bf[i] = *(const bf16x8*)&As[wr*32 + i*16 + l16][h*32 + kb];
#pragma unroll
            for (int j = 0; j < 2; j++)
#pragma unroll
                for (int i = 0; i < 2; i++)
                    acc[j][i] = __builtin_amdgcn_mfma_f32_16x16x32_bf16(
                        af[j], bf[i], acc[j][i], 0,0,0);
        }
        __syncthreads();
    }
    // stage C quadrants into As (each wave owns rows wr*32+.., cols wc*32+..)
#pragma unroll
    for (int j = 0; j < 2; j++) {
        int lcol = wc*32 + j*16 + kg*4;
        f32x4 bv = *(const f32x4*)&bias[n0 + lcol];
#pragma unroll
        for (int i = 0; i < 2; i++) {
            int lrow = wr*32 + i*16 + l16;
            u16x4 o;
#pragma unroll
            for (int r = 0; r < 4; r++) {
                float v = acc[j][i][r] + bv[r];
                if (act == 1) v = gelu_f(v);
                o[r] = f2bf(v);
            }
            *(u16x4*)&As[lrow][lcol] = o;
        }
    }
    __syncthreads();
    {   // coalesced write: 4 threads per row x 32B = full 128B row
        int crow = tid >> 2, cc = (tid & 3) * 16;
        u16x8 c0 = *(const u16x8*)&As[crow][cc];
        u16x8 c1 = *(const u16x8*)&As[crow][cc + 8];
        u16* cp = &C[(size_t)(m0 + crow) * ldc + n0 + cc];
        *(u16x8*)cp = c0;
        *(u16x8*)(cp + 8) = c1;
    }
}

// generic z-batched GEMM (64x64)
__global__ __launch_bounds__(256) void gemm2_kernel(
    const u16* __restrict__ A, int lda, int zA,
    const u16* __restrict__ Bt, int K, int i0, int i1, int i2, int i3, int Bsz,
    const float* __restrict__ bias, int bN,
    u16* __restrict__ C, int ldc, int zC, int act)
{
    int z = blockIdx.z;
    int iz = (z == 0) ? i0 : (z == 1) ? i1 : (z == 2) ? i2 : i3;
    gemm_core(A + (size_t)z * zA, lda,
              Bt + (size_t)iz * Bsz, K,
              bias + (size_t)iz * bN,
              C + (size_t)z * zC, ldc, act);
}

// cat projections: z = inv*2 + ab; output [3136][768] (q|k|v) per (inv,ab)
__global__ __launch_bounds__(256) void proj8_kernel(
    const u16* __restrict__ s, int b0, int b1, int b2, int b3,
    int i0, int i1, int i2, int i3,
    const u16* __restrict__ projWt, const float* __restrict__ biasc,
    u16* __restrict__ projc)
{
    int z = blockIdx.z;
    int inv = z >> 1, ab = z & 1;
    int bi = (inv == 0) ? b0 : (inv == 1) ? b1 : (inv == 2) ? b2 : b3;
    int ii = (inv == 0) ? i0 : (inv == 1) ? i1 : (inv == 2) ? i2 : i3;
    const u16* A = s + (size_t)(ab ? bi : inv) * MD;
    int widx = ii * 2 + ab;
    gemm_core(A, 256, projWt + (size_t)widx * 768 * 256, 256,
              biasc + widx * 768,
              projc + (size_t)z * 3 * MD, 768, 0);
}

__global__ __launch_bounds__(256) void pack_bias_kernel(
    const float* b0, const float* b1, const float* b2,
    const float* b3, const float* b4, const float* b5,
    float* __restrict__ biasc)
{
    int z = blockIdx.x;
    int tsr = z >> 2, i = z & 3;
    const float* barr[6] = {b0,b1,b2,b3,b4,b5};
    int ab = (tsr >= 3) ? 1 : 0;
    biasc[(i*2 + ab)*768 + (tsr % 3)*256 + threadIdx.x] = barr[tsr][i*256 + threadIdx.x];
}

// ---------------- flash attention core, 32x32x16 MFMA, 32 q-rows/wave -------
__device__ __forceinline__ void attn3_core(
    const u16* __restrict__ Qg, int ldq,
    const u16* __restrict__ Kg, int ldk,
    const u16* __restrict__ Vtg,          // [32 d][784 k] for this (b,h)
    u16* __restrict__ Og, int ldo,
    int qt, int rowbase, int qkcol, int ocol)
{
    __shared__ u16 Ks[2][64][36];
    __shared__ u16 Vts[2][32][68];
    __shared__ u16 Ps[4][32][68];
    __shared__ float Ls[4][32];

    const int tid = threadIdx.x, wave = tid >> 6, lane = tid & 63;
    const int l32 = lane & 31, hi = lane >> 5;
    const int sr = tid >> 2, sc8 = (tid & 3) * 8;     // K stage: 64r x 32c
    const int vd = tid >> 3, vk8 = (tid & 7) * 8;     // V stage: 32r x 64c
    const float QSC = 0.25503489f;        // 32^-0.5 * log2(e)

    // direct Q fragment load (pre-scaled): row = qt*128 + wave*32 + l32
    bf8_4 qf0, qf1;
    {
        int qrow = qt*128 + wave*32 + l32;
        u16x8 z8 = {0,0,0,0,0,0,0,0};
        u16x8 q0 = z8, q1 = z8;
        if (qrow < 784) {
            const u16* qp = Qg + (size_t)(rowbase + qrow) * ldq + qkcol;
            q0 = *(const u16x8*)(qp + hi*8);        // cols hi*8 .. hi*8+7
            q1 = *(const u16x8*)(qp + 16 + hi*8);   // cols 16+hi*8 ..
        }
#pragma unroll
        for (int j = 0; j < 8; j++) {
            q0[j] = f2bf(bf2f(q0[j]) * QSC);
            q1[j] = f2bf(bf2f(q1[j]) * QSC);
        }
        qf0.v8 = q0;
        qf1.v8 = q1;
    }
    {   // stage K,V tile 0 (all rows/cols valid)
        u8_4 k, v;
        k.v8 = *(const u16x8*)(Kg + (size_t)(rowbase + sr) * ldk + qkcol + sc8);
        v.v8 = *(const u16x8*)(Vtg + (size_t)vd * 784 + vk8);
        *(u16x4*)&Ks[0][sr][sc8]     = k.v4[0];
        *(u16x4*)&Ks[0][sr][sc8 + 4] = k.v4[1];
        *(u16x4*)&Vts[0][vd][vk8]     = v.v4[0];
        *(u16x4*)&Vts[0][vd][vk8 + 4] = v.v4[1];
    }
    __syncthreads();

    f32x16 oacc;
#pragma unroll
    for (int i = 0; i < 16; i++) oacc[i] = 0.f;
    float lsum = 0.f;

    u16x8 kr, vr;
    for (int t = 0; t < 13; ++t) {
        const int cur = t & 1;
        if (t < 12) {   // prefetch next tile into regs
            u16x8 z8 = {0,0,0,0,0,0,0,0}; kr = z8; vr = z8;
            int krow = (t+1)*64 + sr;
            if (krow < 784)
                kr = *(const u16x8*)(Kg + (size_t)(rowbase + krow) * ldk + qkcol + sc8);
            int kc = (t+1)*64 + vk8;
            if (kc + 7 < 784)
                vr = *(const u16x8*)(Vtg + (size_t)vd * 784 + kc);
        }
        const int kvalid = (t == 12) ? 16 : 64;
        // S^T (two 32k blocks): C row = k-local, col = q = l32
#pragma unroll
        for (int kb2 = 0; kb2 < 2; kb2++) {
            f32x16 sacc;
#pragma unroll
            for (int i = 0; i < 16; i++) sacc[i] = 0.f;
            bf8_4 kf0, kf1;
            kf0.h[0] = *(const u16x4*)&Ks[cur][kb2*32 + l32][hi*8];
            kf0.h[1] = *(const u16x4*)&Ks[cur][kb2*32 + l32][hi*8 + 4];
            kf1.h[0] = *(const u16x4*)&Ks[cur][kb2*32 + l32][16 + hi*8];
            kf1.h[1] = *(const u16x4*)&Ks[cur][kb2*32 + l32][16 + hi*8 + 4];
            sacc = __builtin_amdgcn_mfma_f32_32x32x16_bf16(kf0.f, qf0.f, sacc, 0,0,0);
            sacc = __builtin_amdgcn_mfma_f32_32x32x16_bf16(kf1.f, qf1.f, sacc, 0,0,0);
#pragma unroll
            for (int g = 0; g < 4; g++) {
                int k0 = kb2*32 + 8*g + 4*hi;
                union { unsigned u[2]; u16x4 v; } pk;
                if (k0 < kvalid) {
                    float p0 = exp2_hw(sacc[4*g+0]);
                    float p1 = exp2_hw(sacc[4*g+1]);
                    float p2 = exp2_hw(sacc[4*g+2]);
                    float p3 = exp2_hw(sacc[4*g+3]);
                    lsum += (p0 + p1) + (p2 + p3);
                    pk.u[0] = cvt_pk_bf16(p0, p1);
                    pk.u[1] = cvt_pk_bf16(p2, p3);
                } else { pk.u[0] = 0; pk.u[1] = 0; }
                *(u16x4*)&Ps[wave][l32][k0] = pk.v;
            }
        }
        // PV: O[q][d] += P[q][k] V[k][d], 4 k-frags of 16
#pragma unroll
        for (int kf2 = 0; kf2 < 4; kf2++) {
            bf8_4 pf, vf;
            pf.h[0] = *(const u16x4*)&Ps[wave][l32][kf2*16 + hi*8];
            pf.h[1] = *(const u16x4*)&Ps[wave][l32][kf2*16 + hi*8 + 4];
            vf.h[0] = *(const u16x4*)&Vts[cur][l32][kf2*16 + hi*8];
            vf.h[1] = *(const u16x4*)&Vts[cur][l32][kf2*16 + hi*8 + 4];
            oacc = __builtin_amdgcn_mfma_f32_32x32x16_bf16(pf.f, vf.f, oacc, 0,0,0);
        }
        __syncthreads();
        if (t < 12) {
            u8_4 k, v; k.v8 = kr; v.v8 = vr;
            *(u16x4*)&Ks[cur^1][sr][sc8]     = k.v4[0];
            *(u16x4*)&Ks[cur^1][sr][sc8 + 4] = k.v4[1];
            *(u16x4*)&Vts[cur^1][vd][vk8]     = v.v4[0];
            *(u16x4*)&Vts[cur^1][vd][vk8 + 4] = v.v4[1];
        }
        __syncthreads();
    }
    // total l per q (lane l32 and l32+32 hold the two halves)
    float lt = lsum + __shfl_xor(lsum, 32);
    if (hi == 0) Ls[wave][l32] = lt;
    f32x4 lv[4];
#pragma unroll
    for (int g = 0; g < 4; g++) lv[g] = *(const f32x4*)&Ls[wave][8*g + 4*hi];
    // O store: reg 4g+j -> row j+8g+4hi, col d = l32
#pragma unroll
    for (int g = 0; g < 4; g++)
#pragma unroll
        for (int j = 0; j < 4; j++) {
            int row = qt*128 + wave*32 + 8*g + 4*hi + j;
            if (row < 784)
                Og[(size_t)(rowbase + row) * ldo + ocol + l32] =
                    f2bf(oacc[4*g+j] * __builtin_amdgcn_rcpf(lv[g][j]));
        }
}

// group-of-4 attention: 1792 blocks; z = inv*2 + dir (Q side = dir, K/V = dir^1)
__global__ __launch_bounds__(256) void attn_pair_kernel(
    const u16* __restrict__ projc, const u16* __restrict__ vt,
    u16* __restrict__ fusedin)
{
    int id = blockIdx.x;
    int wg = (id & 7) * 224 + (id >> 3);      // 1792/8 = 224
    int qt = wg % 7, bh = (wg / 7) & 31, z = wg / 224;
    int inv = z >> 1, dir = z & 1;
    const u16* Q  = projc + (size_t)z * 3 * MD;
    const u16* K  = projc + (size_t)(z ^ 1) * 3 * MD + 256;
    const u16* Vt = vt + (size_t)z * MD + (size_t)bh * 32 * 784;
    u16* O = fusedin + (size_t)inv * 2 * MD;
    int bb = bh >> 3, hh = bh & 7;
    attn3_core(Q, 768, K, 768, Vt, O, 512, qt, bb*784, hh*32, dir*256 + hh*32);
}

__global__ __launch_bounds__(256) void attn_mha_kernel(
    const u16* __restrict__ qkv, const u16* __restrict__ vtmha,
    u16* __restrict__ outp)
{
    int id = blockIdx.x;
    int wg = (id & 7) * 28 + (id >> 3);       // 224/8 = 28
    int qt = wg % 7, bh = wg / 7;
    int bb = bh >> 3, hh = bh & 7;
    const u16* Vt = vtmha + (size_t)bh * 32 * 784;
    attn3_core(qkv, 768, qkv + 256, 768, Vt, outp, 256, qt, bb*784, hh*32, hh*32);
}

// ---------------- LayerNorm (bf16 io): out = [prev +] os*(LN(res + tg*x)) ---
__global__ __launch_bounds__(256) void ln_kernel(
    const u16* __restrict__ x, int zx,
    const u16* __restrict__ res, int zres,
    const float* __restrict__ gamma, int i0, int i1, int i2, int i3,
    const float* __restrict__ g, const float* __restrict__ beta, int gN,
    u16* __restrict__ out, int zout,
    float outscale, int accum, int D)
{
    int z = blockIdx.y;
    int iz = (z == 0) ? i0 : (z == 1) ? i1 : (z == 2) ? i2 : i3;
    const u16* xb = x + (size_t)z * zx;
    const u16* rb = res ? res + (size_t)z * zres : (const u16*)nullptr;
    u16* ob = out + (size_t)z * zout;
    const float* gg = g + iz * gN;
    const float* bb = beta + iz * gN;
    int wave = threadIdx.x >> 6, lane = threadIdx.x & 63;
    size_t row = (size_t)blockIdx.x * 4 + wave;
    float tg = gamma ? tanhf(gamma[iz]) : 1.0f;
    const u16* xr = xb + row * D;
    const u16* rr = rb ? rb + row * D : (const u16*)nullptr;
    float vals[16];
    int nch = D >> 8;
    float s = 0.f, s2 = 0.f;
    for (int c = 0; c < nch; c++) {
        int col = c * 256 + lane * 4;
        u16x4 v = *(const u16x4*)(xr + col);
#pragma unroll
        for (int j = 0; j < 4; j++) {
            float a = tg * bf2f(v[j]);
            if (rr) a += bf2f(rr[col + j]);
            vals[c*4 + j] = a;
            s += a; s2 += a * a;
        }
    }
    for (int off = 1; off < 64; off <<= 1) {
        s  += __shfl_xor(s, off);
        s2 += __shfl_xor(s2, off);
    }
    float inv = 1.0f / D;
    float mean = s * inv;
    float var = s2 * inv - mean * mean;
    float rstd = rsqrtf(var + 1e-5f);
    for (int c = 0; c < nch; c++) {
        int col = c * 256 + lane * 4;
#pragma unroll
        for (int j = 0; j < 4; j++) {
            float o = (vals[c*4 + j] - mean) * rstd * gg[col + j] + bb[col + j];
            o *= outscale;
            if (accum) o += bf2f(ob[row*D + col + j]);
            ob[row*D + col + j] = f2bf(o);
        }
    }
}

// ---------------- layout kernels --------------------------------------------
__device__ __forceinline__ void transpose_body(const float* in, u16* out, int K, int N)
{
    __shared__ float t[32][33];
    int tx = threadIdx.x, ty = threadIdx.y;   // (32,8)
#pragma unroll
    for (int j = 0; j < 4; j++)
        t[ty + j*8][tx] = in[(size_t)(blockIdx.y*32 + ty + j*8) * N + blockIdx.x*32 + tx];
    __syncthreads();
#pragma unroll
    for (int j = 0; j < 4; j++)
        out[(size_t)(blockIdx.x*32 + ty + j*8) * K + blockIdx.y*32 + tx] =
            f2bf(t[tx][ty + j*8]);
}

__global__ __launch_bounds__(256) void transpose_w(const float* __restrict__ in,
                                                   u16* __restrict__ out, int K, int N)
{
    int z = blockIdx.z;
    transpose_body(in + (size_t)z * K * N, out + (size_t)z * K * N, K, N);
}

// proj weights into cat layout: [i][ab][768 n][256 k]
__global__ __launch_bounds__(256) void transpose_w6(
    const float* w0, const float* w1, const float* w2,
    const float* w3, const float* w4, const float* w5,
    u16* __restrict__ out)
{
    int z = blockIdx.z;           // 0..23: tsr = z/4, i = z%4
    int tsr = z >> 2, i = z & 3;
    const float* ws[6] = {w0,w1,w2,w3,w4,w5};
    int ab = (tsr >= 3) ? 1 : 0;
    u16* ob = out + (size_t)((i*2 + ab)*3 + (tsr % 3)) * 65536;
    transpose_body(ws[tsr] + (size_t)i * 65536, ob, 256, 256);
}

// transpose V (cols 512..767 of a 768-wide qkv buffer) -> [z][bh*32+d][784]
__global__ __launch_bounds__(256) void vtrans_kernel(
    const u16* __restrict__ base, int mode,
    u16* __restrict__ outbase)
{
    __shared__ u16 t[64][44];
    int z = blockIdx.z;
    size_t off = (mode ? (size_t)0 : (size_t)(z ^ 1) * 3 * MD) + 512;
    const u16* in = base + off;
    u16* out = outbase + (size_t)z * MD;
    int kt = blockIdx.x, bh = blockIdx.y;
    int bb = bh >> 3, hh = bh & 7;
    int tid = threadIdx.x;
    {
        int r = tid >> 2, c8 = (tid & 3) * 8;
        int krow = kt*64 + r;
        u16x8 u = {0,0,0,0,0,0,0,0};
        if (krow < 784)
            u = *(const u16x8*)(in + (size_t)(bb*784 + krow) * 768 + hh*32 + c8);
        *(u16x8*)&t[r][c8] = u;
    }
    __syncthreads();
    int d = tid >> 3, k8 = (tid & 7) * 8;
    if (kt*64 + k8 + 7 < 784) {
        u16x8 u;
#pragma unroll
        for (int j = 0; j < 8; j++) u[j] = t[k8 + j][d];
        *(u16x8*)&out[(size_t)(bh*32 + d) * 784 + kt*64 + k8] = u;
    }
}

// f[B,256,28,28] fp32 -> s[fi][b*784+hw][d] bf16
__global__ __launch_bounds__(256) void to_seq_kernel(
    const float* f0, const float* f1, const float* f2, const float* f3,
    u16* __restrict__ sbase)
{
    __shared__ float t[16][17];
    int z = blockIdx.z;
    int fi = z & 3, b = z >> 2;
    const float* fs[4] = {f0,f1,f2,f3};
    const float* f = fs[fi] + (size_t)b * 256 * 784;
    u16* s = sbase + (size_t)fi * MD + (size_t)b * 784 * 256;
    int tx = threadIdx.x, ty = threadIdx.y;  // (16,16)
    t[ty][tx] = f[(size_t)(blockIdx.y*16 + ty) * 784 + blockIdx.x*16 + tx];
    __syncthreads();
    s[(size_t)(blockIdx.x*16 + ty) * 256 + blockIdx.y*16 + tx] = f2bf(t[tx][ty]);
}

// y[b*784+hw][d] bf16 -> out[b][d][h][w] fp32
__global__ __launch_bounds__(256) void from_seq_kernel(const u16* __restrict__ y,
                                                       float* __restrict__ out)
{
    __shared__ float t[16][17];
    int b = blockIdx.z;
    const u16* yb = y + (size_t)b * 784 * 256;
    float* ob = out + (size_t)b * 256 * 784;
    int tx = threadIdx.x, ty = threadIdx.y;
    t[ty][tx] = bf2f(yb[(size_t)(blockIdx.x*16 + ty) * 256 + blockIdx.y*16 + tx]);
    __syncthreads();
    ob[(size_t)(blockIdx.y*16 + ty) * 784 + blockIdx.x*16 + tx] = t[tx][ty];
}

// ---------------- host orchestration ----------------------------------------
extern "C" void kernel_launch(void* const* d_in, const int* in_sizes, int n_in,
                              void* d_out, int out_size, void* d_ws, size_t ws_size,
                              hipStream_t stream)
{
    (void)in_sizes; (void)n_in; (void)out_size; (void)ws_size;
    const float* f0 = (const float*)d_in[0];
    const float* f1 = (const float*)d_in[1];
    const float* f2 = (const float*)d_in[2];
    const float* f3 = (const float*)d_in[3];
    const float* Wq_a = (const float*)d_in[4];
    const float* Wk_a = (const float*)d_in[5];
    const float* Wv_a = (const float*)d_in[6];
    const float* Wq_b = (const float*)d_in[7];
    const float* Wk_b = (const float*)d_in[8];
    const float* Wv_b = (const float*)d_in[9];
    const float* bq_a = (const float*)d_in[10];
    const float* bk_a = (const float*)d_in[11];
    const float* bv_a = (const float*)d_in[12];
    const float* bq_b = (const float*)d_in[13];
    const float* bk_b = (const float*)d_in[14];
    const float* bv_b = (const float*)d_in[15];
    const float* gamma = (const float*)d_in[16];
    const float* gamma_ffn = (const float*)d_in[17];
    const float* Wfuse = (const float*)d_in[18];
    const float* bfuse = (const float*)d_in[19];
    const float* W1 = (const float*)d_in[20];
    const float* b1 = (const float*)d_in[21];
    const float* W2 = (const float*)d_in[22];
    const float* b2 = (const float*)d_in[23];
    const float* ln1_g = (const float*)d_in[24];
    const float* ln1_b = (const float*)d_in[25];
    const float* ln2_g = (const float*)d_in[26];
    const float* ln2_b = (const float*)d_in[27];
    const float* fp_ln_g = (const float*)d_in[28];
    const float* fp_ln_b = (const float*)d_in[29];
    const float* fp_W = (const float*)d_in[30];
    const float* fp_b = (const float*)d_in[31];
    const float* ff_ln_g = (const float*)d_in[32];
    const float* ff_ln_b = (const float*)d_in[33];
    const float* ff_W = (const float*)d_in[34];
    const float* ff_b = (const float*)d_in[35];
    const float* mha_Wqkv = (const float*)d_in[36];
    const float* mha_bqkv = (const float*)d_in[37];
    const float* mha_Wo = (const float*)d_in[38];
    const float* mha_bo = (const float*)d_in[39];
    const float* norm_g = (const float*)d_in[40];
    const float* norm_b = (const float*)d_in[41];

    u16* W = (u16*)d_ws;
    u16* projWt = W;                          // 24*65536 = 1572864
    u16* fuseWt = projWt + 1572864;           // 524288
    u16* W1t    = fuseWt + 524288;            // 1048576
    u16* W2t    = W1t + 1048576;              // 1048576
    u16* fpWt   = W2t + 1048576;              // 65536
    u16* ffWt   = fpWt + 65536;               // 262144
    u16* qkvWt  = ffWt + 262144;              // 196608
    u16* WoWt   = qkvWt + 196608;             // 65536
    float* biasc = (float*)(WoWt + 65536);    // 6144 floats
    u16* act    = (u16*)(biasc + 6144);

    u16* s     = act;               // 4 MD
    u16* e     = act + 4*MD;        // 4 MD
    u16* projc = act + 8*MD;        // 24 MD
    u16* vt    = act + 32*MD;       // 8 MD
    u16* fin   = act + 40*MD;       // 8 MD   (peak: 48 MD)
    // overlays (projc/vt dead at time of use)
    u16* ffh  = projc;              // 16 MD
    u16* fb   = projc + 16*MD;      // 4 MD
    u16* xa1  = projc + 20*MD;      // 4 MD
    u16* ffb  = vt;                 // 4 MD

    // input layout + weight pre-transpose
    to_seq_kernel<<<dim3(49,16,16), dim3(16,16), 0, stream>>>(f0,f1,f2,f3, s);
    transpose_w6<<<dim3(8,8,24), dim3(32,8), 0, stream>>>(Wq_a,Wk_a,Wv_a,Wq_b,Wk_b,Wv_b, projWt);
    pack_bias_kernel<<<24, 256, 0, stream>>>(bq_a,bk_a,bv_a,bq_b,bk_b,bv_b, biasc);
    transpose_w<<<dim3(8,16,4), dim3(32,8), 0, stream>>>(Wfuse, fuseWt, 512, 256);
    transpose_w<<<dim3(32,8,4), dim3(32,8), 0, stream>>>(W1, W1t, 256, 1024);
    transpose_w<<<dim3(8,32,4), dim3(32,8), 0, stream>>>(W2, W2t, 1024, 256);
    transpose_w<<<dim3(8,8,1),  dim3(32,8), 0, stream>>>(fp_W, fpWt, 256, 256);
    transpose_w<<<dim3(8,32,1), dim3(32,8), 0, stream>>>(ff_W, ffWt, 1024, 256);
    transpose_w<<<dim3(24,8,1), dim3(32,8), 0, stream>>>(mha_Wqkv, qkvWt, 256, 768);
    transpose_w<<<dim3(8,8,1),  dim3(32,8), 0, stream>>>(mha_Wo, WoWt, 256, 256);

    // two groups of 4 independent block invocations (a-side = s[inv]):
    // A = {bi0,bi2,bi4,bi6}: i={0,0,2,1}, b={1,0,1,0}, accum=0
    // B = {bi1,bi3,bi5,bi7}: i={1,2,3,3}, b={3,2,3,2}, accum=1
    const int GI[2][4] = {{0,0,2,1},{1,2,3,3}};
    const int GB[2][4] = {{1,0,1,0},{3,2,3,2}};

    for (int g = 0; g < 2; g++) {
        int i0 = GI[g][0], i1 = GI[g][1], i2 = GI[g][2], i3 = GI[g][3];
        proj8_kernel<<<dim3(49,12,8), 256, 0, stream>>>(s,
            GB[g][0], GB[g][1], GB[g][2], GB[g][3], i0, i1, i2, i3,
            projWt, biasc, projc);
        vtrans_kernel<<<dim3(13,32,8), 256, 0, stream>>>(projc, 0, vt);
        attn_pair_kernel<<<1792, 256, 0, stream>>>(projc, vt, fin);
        gemm2_kernel<<<dim3(49,4,4), 256, 0, stream>>>(fin, 512, (int)(2*MD),
            fuseWt, 512, i0, i1, i2, i3, 131072, bfuse, 256, fb, 256, (int)MD, 0);
        ln_kernel<<<dim3(784,4), 256, 0, stream>>>(fb, (int)MD,
            s, (int)MD, gamma, i0, i1, i2, i3, ln1_g, ln1_b, 256,
            xa1, (int)MD, 1.0f, 0, 256);
        gemm2_kernel<<<dim3(49,16,4), 256, 0, stream>>>(xa1, 256, (int)MD,
            W1t, 256, i0, i1, i2, i3, 262144, b1, 1024, ffh, 1024, (int)(4*MD), 1);
        gemm2_kernel<<<dim3(49,4,4), 256, 0, stream>>>(ffh, 1024, (int)(4*MD),
            W2t, 1024, i0, i1, i2, i3, 262144, b2, 256, ffb, 256, (int)MD, 0);
        ln_kernel<<<dim3(784,4), 256, 0, stream>>>(ffb, (int)MD,
            xa1, (int)MD, gamma_ffn, i0, i1, i2, i3, ln2_g, ln2_b, 256,
            e, (int)MD, 0.5f, g, 256);
    }

    // final fuse stage (reuse dead scratch; e live until first LN done)
    u16* ln4    = act + 8*MD;        // 4 MD
    u16* allf   = act + 12*MD;       // 4 MD  [3136][1024]
    u16* ffln   = act + 16*MD;       // 4 MD
    u16* x2     = act + 20*MD;       // 1 MD
    u16* qkv    = act + 21*MD;       // 3 MD  [3136][768]
    u16* vtmha  = act + 24*MD;       // 1 MD
    u16* attn_o = act + 25*MD;       // 1 MD
    u16* ymid   = act + 26*MD;       // 1 MD
    u16* yfin   = act + 27*MD;       // 1 MD

    ln_kernel<<<dim3(784,4), 256, 0, stream>>>(e, (int)MD,
        (const u16*)nullptr, 0, (const float*)nullptr, 0,0,0,0,
        fp_ln_g, fp_ln_b, 0, ln4, (int)MD, 1.0f, 0, 256);
    gemm2_kernel<<<dim3(49,4,4), 256, 0, stream>>>(ln4, 256, (int)MD,
        fpWt, 256, 0,0,0,0, 0, fp_b, 0, allf, 1024, 256, 1);
    ln_kernel<<<dim3(784,1), 256, 0, stream>>>(allf, 0,
        (const u16*)nullptr, 0, (const float*)nullptr, 0,0,0,0,
        ff_ln_g, ff_ln_b, 0, ffln, 0, 1.0f, 0, 1024);
    gemm2_kernel<<<dim3(49,4,1), 256, 0, stream>>>(ffln, 1024, 0,
        ffWt, 1024, 0,0,0,0, 0, ff_b, 0, x2, 256, 0, 1);
    gemm2_kernel<<<dim3(49,12,1), 256, 0, stream>>>(x2, 256, 0,
        qkvWt, 256, 0,0,0,0, 0, mha_bqkv, 0, qkv, 768, 0, 0);
    vtrans_kernel<<<dim3(13,32,1), 256, 0, stream>>>(qkv, 1, vtmha);
    attn_mha_kernel<<<224, 256, 0, stream>>>(qkv, vtmha, attn_o);
    gemm2_kernel<<<dim3(49,4,1), 256, 0, stream>>>(attn_o, 256, 0,
        WoWt, 256, 0,0,0,0, 0, mha_bo, 0, ymid, 256, 0, 0);
    ln_kernel<<<dim3(784,1), 256, 0, stream>>>(ymid, 0,
        (const u16*)nullptr, 0, (const float*)nullptr, 0,0,0,0,
        norm_g, norm_b, 0, yfin, 0, 1.0f, 0, 256);
    from_seq_kernel<<<dim3(49,16,4), dim3(16,16), 0, stream>>>(yfin, (float*)d_out);
}

// Round 14
// 425.643 us; speedup vs baseline: 1.1664x; 1.0302x over previous
//
#include <hip/hip_runtime.h>

typedef unsigned short u16;
typedef __bf16 bf16x8 __attribute__((ext_vector_type(8)));
typedef float f32x4 __attribute__((ext_vector_type(4)));
typedef float f32x16 __attribute__((ext_vector_type(16)));
typedef unsigned short u16x8 __attribute__((ext_vector_type(8)));
typedef unsigned short u16x4 __attribute__((ext_vector_type(4)));

static constexpr size_t MD = 802816;   // 3136*256 elements

__device__ __forceinline__ u16 f2bf(float f) {
    __bf16 h = (__bf16)f;
    return __builtin_bit_cast(unsigned short, h);
}
__device__ __forceinline__ float bf2f(u16 u) {
    return __uint_as_float(((unsigned)u) << 16);
}
__device__ __forceinline__ float gelu_f(float x) {
    return 0.5f * x * (1.0f + erff(x * 0.70710678118654752f));
}
// pack two f32 -> two bf16 in one u32 (low = a, high = b)
__device__ __forceinline__ unsigned cvt_pk_bf16(float a, float b) {
    unsigned r;
    asm("v_cvt_pk_bf16_f32 %0, %1, %2" : "=v"(r) : "v"(a), "v"(b));
    return r;
}
// raw 2^x via the ISA instruction (v_exp_f32 -> D = 2^S0).
// NOTE: __builtin_amdgcn_exp2f gave WRONG results (R8/R9); inline asm pins it.
__device__ __forceinline__ float exp2_hw(float x) {
    float r;
    asm("v_exp_f32 %0, %1" : "=v"(r) : "v"(x));
    return r;
}
// bijective XCD swizzle (m204 form): blocks with the same hw XCD (id%8) get a
// CONTIGUOUS logical range -> operand panels stay resident in that XCD's L2.
__device__ __forceinline__ int xcd_swz(int id, int nwg) {
    int q = nwg >> 3, r = nwg & 7;
    int xcd = id & 7, idx = id >> 3;
    return (xcd < r) ? (xcd * (q + 1) + idx) : (r * (q + 1) + (xcd - r) * q + idx);
}
union u8_4 { u16x8 v8; u16x4 v4[2]; };
union bf8_4 { bf16x8 f; u16x4 h[2]; u16x8 v8; };

// ------------- bf16 GEMM core, 64x64 tile, BK=64, swapped epilogue ----------
// C staged via LDS -> 32B/lane contiguous stores (R13: removed 2x write amp).
__device__ __forceinline__ void gemm_core(
    const u16* __restrict__ A, int lda,
    const u16* __restrict__ Bt, int K,
    const float* __restrict__ bias,
    u16* __restrict__ C, int ldc, int act, int m0, int n0)
{
    __shared__ u16 As[64][72];
    __shared__ u16 Bs[64][72];
    const int tid  = threadIdx.x;
    const int wave = tid >> 6, lane = tid & 63;
    const int wr = wave >> 1, wc = wave & 1;
    const int l16 = lane & 15, kg = lane >> 4, kb = kg * 8;
    const int srow = tid >> 2, scol = (tid & 3) * 16;

    f32x4 acc[2][2];   // [n-frag][m-frag]
#pragma unroll
    for (int j = 0; j < 2; j++)
#pragma unroll
        for (int i = 0; i < 2; i++) { f32x4 z = {0.f,0.f,0.f,0.f}; acc[j][i] = z; }

    const u16* ap = A + (size_t)(m0 + srow) * lda + scol;
    const u16* bp = Bt + (size_t)(n0 + srow) * K + scol;
    u16x8 ua0 = *(const u16x8*)ap;
    u16x8 ua1 = *(const u16x8*)(ap + 8);
    u16x8 ub0 = *(const u16x8*)bp;
    u16x8 ub1 = *(const u16x8*)(bp + 8);

    for (int kt = 0; kt < K; kt += 64) {
        *(u16x8*)&As[srow][scol]     = ua0;
        *(u16x8*)&As[srow][scol + 8] = ua1;
        *(u16x8*)&Bs[srow][scol]     = ub0;
        *(u16x8*)&Bs[srow][scol + 8] = ub1;
        __syncthreads();
        if (kt + 64 < K) {
            ua0 = *(const u16x8*)(ap + kt + 64);
            ua1 = *(const u16x8*)(ap + kt + 72);
            ub0 = *(const u16x8*)(bp + kt + 64);
            ub1 = *(const u16x8*)(bp + kt + 72);
        }
#pragma unroll
        for (int h = 0; h < 2; h++) {
            bf16x8 af[2], bf[2];
#pragma unroll
            for (int j = 0; j < 2; j++)
                af[j] = *(const bf16x8*)&Bs[wc*32 + j*16 + l16][h*32 + kb];
#pragma unroll
            for (int i = 0; i < 2; i++)
                bf[i] = *(const bf16x8*)&As[wr*32 + i*16 + l16][h*32 + kb];
#pragma unroll
            for (int j = 0; j < 2; j++)
#pragma unroll
                for (int i = 0; i < 2; i++)
                    acc[j][i] = __builtin_amdgcn_mfma_f32_16x16x32_bf16(
                        af[j], bf[i], acc[j][i], 0,0,0);
        }
        __syncthreads();
    }
    // stage C quadrants into As (each wave owns rows wr*32+.., cols wc*32+..)
#pragma unroll
    for (int j = 0; j < 2; j++) {
        int lcol = wc*32 + j*16 + kg*4;
        f32x4 bv = *(const f32x4*)&bias[n0 + lcol];
#pragma unroll
        for (int i = 0; i < 2; i++) {
            int lrow = wr*32 + i*16 + l16;
            u16x4 o;
#pragma unroll
            for (int r = 0; r < 4; r++) {
                float v = acc[j][i][r] + bv[r];
                if (act == 1) v = gelu_f(v);
                o[r] = f2bf(v);
            }
            *(u16x4*)&As[lrow][lcol] = o;
        }
    }
    __syncthreads();
    {   // coalesced write: 4 threads per row x 32B = full 128B row
        int crow = tid >> 2, cc = (tid & 3) * 16;
        u16x8 c0 = *(const u16x8*)&As[crow][cc];
        u16x8 c1 = *(const u16x8*)&As[crow][cc + 8];
        u16* cp = &C[(size_t)(m0 + crow) * ldc + n0 + cc];
        *(u16x8*)cp = c0;
        *(u16x8*)(cp + 8) = c1;
    }
}

// generic z-batched GEMM (64x64), 1D grid, XCD-swizzled, n fastest
__global__ __launch_bounds__(256) void gemm2_kernel(
    const u16* __restrict__ A, int lda, int zA,
    const u16* __restrict__ Bt, int K, int i0, int i1, int i2, int i3, int Bsz,
    const float* __restrict__ bias, int bN,
    u16* __restrict__ C, int ldc, int zC, int act, int nN, int nwg)
{
    int wg = xcd_swz(blockIdx.x, nwg);
    int n = wg % nN, rest = wg / nN;
    int m = rest % 49, z = rest / 49;
    int iz = (z == 0) ? i0 : (z == 1) ? i1 : (z == 2) ? i2 : i3;
    gemm_core(A + (size_t)z * zA, lda,
              Bt + (size_t)iz * Bsz, K,
              bias + (size_t)iz * bN,
              C + (size_t)z * zC, ldc, act, m * 64, n * 64);
}

// cat projections: z = inv*2 + ab; output [3136][768]; 1D grid, swizzled
__global__ __launch_bounds__(256) void proj8_kernel(
    const u16* __restrict__ s, int b0, int b1, int b2, int b3,
    int i0, int i1, int i2, int i3,
    const u16* __restrict__ projWt, const float* __restrict__ biasc,
    u16* __restrict__ projc)
{
    int wg = xcd_swz(blockIdx.x, 4704);       // 49*12*8
    int n = wg % 12, rest = wg / 12;
    int m = rest % 49, z = rest / 49;
    int inv = z >> 1, ab = z & 1;
    int bi = (inv == 0) ? b0 : (inv == 1) ? b1 : (inv == 2) ? b2 : b3;
    int ii = (inv == 0) ? i0 : (inv == 1) ? i1 : (inv == 2) ? i2 : i3;
    const u16* Aact = s + (size_t)(ab ? bi : inv) * MD;
    int widx = ii * 2 + ab;
    gemm_core(Aact, 256, projWt + (size_t)widx * 768 * 256, 256,
              biasc + widx * 768,
              projc + (size_t)z * 3 * MD, 768, 0, m * 64, n * 64);
}

__global__ __launch_bounds__(256) void pack_bias_kernel(
    const float* b0, const float* b1, const float* b2,
    const float* b3, const float* b4, const float* b5,
    float* __restrict__ biasc)
{
    int z = blockIdx.x;
    int tsr = z >> 2, i = z & 3;
    const float* barr[6] = {b0,b1,b2,b3,b4,b5};
    int ab = (tsr >= 3) ? 1 : 0;
    biasc[(i*2 + ab)*768 + (tsr % 3)*256 + threadIdx.x] = barr[tsr][i*256 + threadIdx.x];
}

// ---------------- flash attention core, 32x32x16 MFMA, 32 q-rows/wave -------
__device__ __forceinline__ void attn3_core(
    const u16* __restrict__ Qg, int ldq,
    const u16* __restrict__ Kg, int ldk,
    const u16* __restrict__ Vtg,          // [32 d][784 k] for this (b,h)
    u16* __restrict__ Og, int ldo,
    int qt, int rowbase, int qkcol, int ocol)
{
    __shared__ u16 Ks[2][64][36];
    __shared__ u16 Vts[2][32][68];
    __shared__ u16 Ps[4][32][68];
    __shared__ float Ls[4][32];

    const int tid = threadIdx.x, wave = tid >> 6, lane = tid & 63;
    const int l32 = lane & 31, hi = lane >> 5;
    const int sr = tid >> 2, sc8 = (tid & 3) * 8;     // K stage: 64r x 32c
    const int vd = tid >> 3, vk8 = (tid & 7) * 8;     // V stage: 32r x 64c
    const float QSC = 0.25503489f;        // 32^-0.5 * log2(e)

    // direct Q fragment load (pre-scaled): row = qt*128 + wave*32 + l32
    bf8_4 qf0, qf1;
    {
        int qrow = qt*128 + wave*32 + l32;
        u16x8 z8 = {0,0,0,0,0,0,0,0};
        u16x8 q0 = z8, q1 = z8;
        if (qrow < 784) {
            const u16* qp = Qg + (size_t)(rowbase + qrow) * ldq + qkcol;
            q0 = *(const u16x8*)(qp + hi*8);        // cols hi*8 .. hi*8+7
            q1 = *(const u16x8*)(qp + 16 + hi*8);   // cols 16+hi*8 ..
        }
#pragma unroll
        for (int j = 0; j < 8; j++) {
            q0[j] = f2bf(bf2f(q0[j]) * QSC);
            q1[j] = f2bf(bf2f(q1[j]) * QSC);
        }
        qf0.v8 = q0;
        qf1.v8 = q1;
    }
    {   // stage K,V tile 0 (all rows/cols valid)
        u8_4 k, v;
        k.v8 = *(const u16x8*)(Kg + (size_t)(rowbase + sr) * ldk + qkcol + sc8);
        v.v8 = *(const u16x8*)(Vtg + (size_t)vd * 784 + vk8);
        *(u16x4*)&Ks[0][sr][sc8]     = k.v4[0];
        *(u16x4*)&Ks[0][sr][sc8 + 4] = k.v4[1];
        *(u16x4*)&Vts[0][vd][vk8]     = v.v4[0];
        *(u16x4*)&Vts[0][vd][vk8 + 4] = v.v4[1];
    }
    __syncthreads();

    f32x16 oacc;
#pragma unroll
    for (int i = 0; i < 16; i++) oacc[i] = 0.f;
    float lsum = 0.f;

    u16x8 kr, vr;
    for (int t = 0; t < 13; ++t) {
        const int cur = t & 1;
        if (t < 12) {   // prefetch next tile into regs
            u16x8 z8 = {0,0,0,0,0,0,0,0}; kr = z8; vr = z8;
            int krow = (t+1)*64 + sr;
            if (krow < 784)
                kr = *(const u16x8*)(Kg + (size_t)(rowbase + krow) * ldk + qkcol + sc8);
            int kc = (t+1)*64 + vk8;
            if (kc + 7 < 784)
                vr = *(const u16x8*)(Vtg + (size_t)vd * 784 + kc);
        }
        const int kvalid = (t == 12) ? 16 : 64;
        // S^T (two 32k blocks): C row = k-local, col = q = l32
#pragma unroll
        for (int kb2 = 0; kb2 < 2; kb2++) {
            f32x16 sacc;
#pragma unroll
            for (int i = 0; i < 16; i++) sacc[i] = 0.f;
            bf8_4 kf0, kf1;
            kf0.h[0] = *(const u16x4*)&Ks[cur][kb2*32 + l32][hi*8];
            kf0.h[1] = *(const u16x4*)&Ks[cur][kb2*32 + l32][hi*8 + 4];
            kf1.h[0] = *(const u16x4*)&Ks[cur][kb2*32 + l32][16 + hi*8];
            kf1.h[1] = *(const u16x4*)&Ks[cur][kb2*32 + l32][16 + hi*8 + 4];
            sacc = __builtin_amdgcn_mfma_f32_32x32x16_bf16(kf0.f, qf0.f, sacc, 0,0,0);
            sacc = __builtin_amdgcn_mfma_f32_32x32x16_bf16(kf1.f, qf1.f, sacc, 0,0,0);
#pragma unroll
            for (int g = 0; g < 4; g++) {
                int k0 = kb2*32 + 8*g + 4*hi;
                union { unsigned u[2]; u16x4 v; } pk;
                if (k0 < kvalid) {
                    float p0 = exp2_hw(sacc[4*g+0]);
                    float p1 = exp2_hw(sacc[4*g+1]);
                    float p2 = exp2_hw(sacc[4*g+2]);
                    float p3 = exp2_hw(sacc[4*g+3]);
                    lsum += (p0 + p1) + (p2 + p3);
                    pk.u[0] = cvt_pk_bf16(p0, p1);
                    pk.u[1] = cvt_pk_bf16(p2, p3);
                } else { pk.u[0] = 0; pk.u[1] = 0; }
                *(u16x4*)&Ps[wave][l32][k0] = pk.v;
            }
        }
        // PV: O[q][d] += P[q][k] V[k][d], 4 k-frags of 16
#pragma unroll
        for (int kf2 = 0; kf2 < 4; kf2++) {
            bf8_4 pf, vf;
            pf.h[0] = *(const u16x4*)&Ps[wave][l32][kf2*16 + hi*8];
            pf.h[1] = *(const u16x4*)&Ps[wave][l32][kf2*16 + hi*8 + 4];
            vf.h[0] = *(const u16x4*)&Vts[cur][l32][kf2*16 + hi*8];
            vf.h[1] = *(const u16x4*)&Vts[cur][l32][kf2*16 + hi*8 + 4];
            oacc = __builtin_amdgcn_mfma_f32_32x32x16_bf16(pf.f, vf.f, oacc, 0,0,0);
        }
        __syncthreads();
        if (t < 12) {
            u8_4 k, v; k.v8 = kr; v.v8 = vr;
            *(u16x4*)&Ks[cur^1][sr][sc8]     = k.v4[0];
            *(u16x4*)&Ks[cur^1][sr][sc8 + 4] = k.v4[1];
            *(u16x4*)&Vts[cur^1][vd][vk8]     = v.v4[0];
            *(u16x4*)&Vts[cur^1][vd][vk8 + 4] = v.v4[1];
        }
        __syncthreads();
    }
    // total l per q (lane l32 and l32+32 hold the two halves)
    float lt = lsum + __shfl_xor(lsum, 32);
    if (hi == 0) Ls[wave][l32] = lt;
    f32x4 lv[4];
#pragma unroll
    for (int g = 0; g < 4; g++) lv[g] = *(const f32x4*)&Ls[wave][8*g + 4*hi];
    // O store: reg 4g+j -> row j+8g+4hi, col d = l32
#pragma unroll
    for (int g = 0; g < 4; g++)
#pragma unroll
        for (int j = 0; j < 4; j++) {
            int row = qt*128 + wave*32 + 8*g + 4*hi + j;
            if (row < 784)
                Og[(size_t)(rowbase + row) * ldo + ocol + l32] =
                    f2bf(oacc[4*g+j] * __builtin_amdgcn_rcpf(lv[g][j]));
        }
}

// group-of-4 attention: 1792 blocks; z = inv*2 + dir (Q side = dir, K/V = dir^1)
__global__ __launch_bounds__(256) void attn_pair_kernel(
    const u16* __restrict__ projc, const u16* __restrict__ vt,
    u16* __restrict__ fusedin)
{
    int id = blockIdx.x;
    int wg = (id & 7) * 224 + (id >> 3);      // 1792/8 = 224
    int qt = wg % 7, bh = (wg / 7) & 31, z = wg / 224;
    int inv = z >> 1, dir = z & 1;
    const u16* Q  = projc + (size_t)z * 3 * MD;
    const u16* K  = projc + (size_t)(z ^ 1) * 3 * MD + 256;
    const u16* Vt = vt + (size_t)z * MD + (size_t)bh * 32 * 784;
    u16* O = fusedin + (size_t)inv * 2 * MD;
    int bb = bh >> 3, hh = bh & 7;
    attn3_core(Q, 768, K, 768, Vt, O, 512, qt, bb*784, hh*32, dir*256 + hh*32);
}

__global__ __launch_bounds__(256) void attn_mha_kernel(
    const u16* __restrict__ qkv, const u16* __restrict__ vtmha,
    u16* __restrict__ outp)
{
    int id = blockIdx.x;
    int wg = (id & 7) * 28 + (id >> 3);       // 224/8 = 28
    int qt = wg % 7, bh = wg / 7;
    int bb = bh >> 3, hh = bh & 7;
    const u16* Vt = vtmha + (size_t)bh * 32 * 784;
    attn3_core(qkv, 768, qkv + 256, 768, Vt, outp, 256, qt, bb*784, hh*32, hh*32);
}

// ---------------- LayerNorm (bf16 io): out = [prev +] os*(LN(res + tg*x)) ---
__global__ __launch_bounds__(256) void ln_kernel(
    const u16* __restrict__ x, int zx,
    const u16* __restrict__ res, int zres,
    const float* __restrict__ gamma, int i0, int i1, int i2, int i3,
    const float* __restrict__ g, const float* __restrict__ beta, int gN,
    u16* __restrict__ out, int zout,
    float outscale, int accum, int D)
{
    int z = blockIdx.y;
    int iz = (z == 0) ? i0 : (z == 1) ? i1 : (z == 2) ? i2 : i3;
    const u16* xb = x + (size_t)z * zx;
    const u16* rb = res ? res + (size_t)z * zres : (const u16*)nullptr;
    u16* ob = out + (size_t)z * zout;
    const float* gg = g + iz * gN;
    const float* bb = beta + iz * gN;
    int wave = threadIdx.x >> 6, lane = threadIdx.x & 63;
    size_t row = (size_t)blockIdx.x * 4 + wave;
    float tg = gamma ? tanhf(gamma[iz]) : 1.0f;
    const u16* xr = xb + row * D;
    const u16* rr = rb ? rb + row * D : (const u16*)nullptr;
    float vals[16];
    int nch = D >> 8;
    float s = 0.f, s2 = 0.f;
    for (int c = 0; c < nch; c++) {
        int col = c * 256 + lane * 4;
        u16x4 v = *(const u16x4*)(xr + col);
#pragma unroll
        for (int j = 0; j < 4; j++) {
            float a = tg * bf2f(v[j]);
            if (rr) a += bf2f(rr[col + j]);
            vals[c*4 + j] = a;
            s += a; s2 += a * a;
        }
    }
    for (int off = 1; off < 64; off <<= 1) {
        s  += __shfl_xor(s, off);
        s2 += __shfl_xor(s2, off);
    }
    float inv = 1.0f / D;
    float mean = s * inv;
    float var = s2 * inv - mean * mean;
    float rstd = rsqrtf(var + 1e-5f);
    for (int c = 0; c < nch; c++) {
        int col = c * 256 + lane * 4;
#pragma unroll
        for (int j = 0; j < 4; j++) {
            float o = (vals[c*4 + j] - mean) * rstd * gg[col + j] + bb[col + j];
            o *= outscale;
            if (accum) o += bf2f(ob[row*D + col + j]);
            ob[row*D + col + j] = f2bf(o);
        }
    }
}

// ---------------- layout kernels --------------------------------------------
__device__ __forceinline__ void transpose_body(const float* in, u16* out, int K, int N)
{
    __shared__ float t[32][33];
    int tx = threadIdx.x, ty = threadIdx.y;   // (32,8)
#pragma unroll
    for (int j = 0; j < 4; j++)
        t[ty + j*8][tx] = in[(size_t)(blockIdx.y*32 + ty + j*8) * N + blockIdx.x*32 + tx];
    __syncthreads();
#pragma unroll
    for (int j = 0; j < 4; j++)
        out[(size_t)(blockIdx.x*32 + ty + j*8) * K + blockIdx.y*32 + tx] =
            f2bf(t[tx][ty + j*8]);
}

__global__ __launch_bounds__(256) void transpose_w(const float* __restrict__ in,
                                                   u16* __restrict__ out, int K, int N)
{
    int z = blockIdx.z;
    transpose_body(in + (size_t)z * K * N, out + (size_t)z * K * N, K, N);
}

// proj weights into cat layout: [i][ab][768 n][256 k]
__global__ __launch_bounds__(256) void transpose_w6(
    const float* w0, const float* w1, const float* w2,
    const float* w3, const float* w4, const float* w5,
    u16* __restrict__ out)
{
    int z = blockIdx.z;           // 0..23: tsr = z/4, i = z%4
    int tsr = z >> 2, i = z & 3;
    const float* ws[6] = {w0,w1,w2,w3,w4,w5};
    int ab = (tsr >= 3) ? 1 : 0;
    u16* ob = out + (size_t)((i*2 + ab)*3 + (tsr % 3)) * 65536;
    transpose_body(ws[tsr] + (size_t)i * 65536, ob, 256, 256);
}

// transpose V (cols 512..767 of a 768-wide qkv buffer) -> [z][bh*32+d][784]
__global__ __launch_bounds__(256) void vtrans_kernel(
    const u16* __restrict__ base, int mode,
    u16* __restrict__ outbase)
{
    __shared__ u16 t[64][44];
    int z = blockIdx.z;
    size_t off = (mode ? (size_t)0 : (size_t)(z ^ 1) * 3 * MD) + 512;
    const u16* in = base + off;
    u16* out = outbase + (size_t)z * MD;
    int kt = blockIdx.x, bh = blockIdx.y;
    int bb = bh >> 3, hh = bh & 7;
    int tid = threadIdx.x;
    {
        int r = tid >> 2, c8 = (tid & 3) * 8;
        int krow = kt*64 + r;
        u16x8 u = {0,0,0,0,0,0,0,0};
        if (krow < 784)
            u = *(const u16x8*)(in + (size_t)(bb*784 + krow) * 768 + hh*32 + c8);
        *(u16x8*)&t[r][c8] = u;
    }
    __syncthreads();
    int d = tid >> 3, k8 = (tid & 7) * 8;
    if (kt*64 + k8 + 7 < 784) {
        u16x8 u;
#pragma unroll
        for (int j = 0; j < 8; j++) u[j] = t[k8 + j][d];
        *(u16x8*)&out[(size_t)(bh*32 + d) * 784 + kt*64 + k8] = u;
    }
}

// f[B,256,28,28] fp32 -> s[fi][b*784+hw][d] bf16
__global__ __launch_bounds__(256) void to_seq_kernel(
    const float* f0, const float* f1, const float* f2, const float* f3,
    u16* __restrict__ sbase)
{
    __shared__ float t[16][17];
    int z = blockIdx.z;
    int fi = z & 3, b = z >> 2;
    const float* fs[4] = {f0,f1,f2,f3};
    const float* f = fs[fi] + (size_t)b * 256 * 784;
    u16* s = sbase + (size_t)fi * MD + (size_t)b * 784 * 256;
    int tx = threadIdx.x, ty = threadIdx.y;  // (16,16)
    t[ty][tx] = f[(size_t)(blockIdx.y*16 + ty) * 784 + blockIdx.x*16 + tx];
    __syncthreads();
    s[(size_t)(blockIdx.x*16 + ty) * 256 + blockIdx.y*16 + tx] = f2bf(t[tx][ty]);
}

// y[b*784+hw][d] bf16 -> out[b][d][h][w] fp32
__global__ __launch_bounds__(256) void from_seq_kernel(const u16* __restrict__ y,
                                                       float* __restrict__ out)
{
    __shared__ float t[16][17];
    int b = blockIdx.z;
    const u16* yb = y + (size_t)b * 784 * 256;
    float* ob = out + (size_t)b * 256 * 784;
    int tx = threadIdx.x, ty = threadIdx.y;
    t[ty][tx] = bf2f(yb[(size_t)(blockIdx.x*16 + ty) * 256 + blockIdx.y*16 + tx]);
    __syncthreads();
    ob[(size_t)(blockIdx.y*16 + ty) * 784 + blockIdx.x*16 + tx] = t[tx][ty];
}

// ---------------- host orchestration ----------------------------------------
extern "C" void kernel_launch(void* const* d_in, const int* in_sizes, int n_in,
                              void* d_out, int out_size, void* d_ws, size_t ws_size,
                              hipStream_t stream)
{
    (void)in_sizes; (void)n_in; (void)out_size; (void)ws_size;
    const float* f0 = (const float*)d_in[0];
    const float* f1 = (const float*)d_in[1];
    const float* f2 = (const float*)d_in[2];
    const float* f3 = (const float*)d_in[3];
    const float* Wq_a = (const float*)d_in[4];
    const float* Wk_a = (const float*)d_in[5];
    const float* Wv_a = (const float*)d_in[6];
    const float* Wq_b = (const float*)d_in[7];
    const float* Wk_b = (const float*)d_in[8];
    const float* Wv_b = (const float*)d_in[9];
    const float* bq_a = (const float*)d_in[10];
    const float* bk_a = (const float*)d_in[11];
    const float* bv_a = (const float*)d_in[12];
    const float* bq_b = (const float*)d_in[13];
    const float* bk_b = (const float*)d_in[14];
    const float* bv_b = (const float*)d_in[15];
    const float* gamma = (const float*)d_in[16];
    const float* gamma_ffn = (const float*)d_in[17];
    const float* Wfuse = (const float*)d_in[18];
    const float* bfuse = (const float*)d_in[19];
    const float* W1 = (const float*)d_in[20];
    const float* b1 = (const float*)d_in[21];
    const float* W2 = (const float*)d_in[22];
    const float* b2 = (const float*)d_in[23];
    const float* ln1_g = (const float*)d_in[24];
    const float* ln1_b = (const float*)d_in[25];
    const float* ln2_g = (const float*)d_in[26];
    const float* ln2_b = (const float*)d_in[27];
    const float* fp_ln_g = (const float*)d_in[28];
    const float* fp_ln_b = (const float*)d_in[29];
    const float* fp_W = (const float*)d_in[30];
    const float* fp_b = (const float*)d_in[31];
    const float* ff_ln_g = (const float*)d_in[32];
    const float* ff_ln_b = (const float*)d_in[33];
    const float* ff_W = (const float*)d_in[34];
    const float* ff_b = (const float*)d_in[35];
    const float* mha_Wqkv = (const float*)d_in[36];
    const float* mha_bqkv = (const float*)d_in[37];
    const float* mha_Wo = (const float*)d_in[38];
    const float* mha_bo = (const float*)d_in[39];
    const float* norm_g = (const float*)d_in[40];
    const float* norm_b = (const float*)d_in[41];

    u16* W = (u16*)d_ws;
    u16* projWt = W;                          // 24*65536 = 1572864
    u16* fuseWt = projWt + 1572864;           // 524288
    u16* W1t    = fuseWt + 524288;            // 1048576
    u16* W2t    = W1t + 1048576;              // 1048576
    u16* fpWt   = W2t + 1048576;              // 65536
    u16* ffWt   = fpWt + 65536;               // 262144
    u16* qkvWt  = ffWt + 262144;              // 196608
    u16* WoWt   = qkvWt + 196608;             // 65536
    float* biasc = (float*)(WoWt + 65536);    // 6144 floats
    u16* act    = (u16*)(biasc + 6144);

    u16* s     = act;               // 4 MD
    u16* e     = act + 4*MD;        // 4 MD
    u16* projc = act + 8*MD;        // 24 MD
    u16* vt    = act + 32*MD;       // 8 MD
    u16* fin   = act + 40*MD;       // 8 MD   (peak: 48 MD)
    // overlays (projc/vt dead at time of use)
    u16* ffh  = projc;              // 16 MD
    u16* fb   = projc + 16*MD;      // 4 MD
    u16* xa1  = projc + 20*MD;      // 4 MD
    u16* ffb  = vt;                 // 4 MD

    // input layout + weight pre-transpose
    to_seq_kernel<<<dim3(49,16,16), dim3(16,16), 0, stream>>>(f0,f1,f2,f3, s);
    transpose_w6<<<dim3(8,8,24), dim3(32,8), 0, stream>>>(Wq_a,Wk_a,Wv_a,Wq_b,Wk_b,Wv_b, projWt);
    pack_bias_kernel<<<24, 256, 0, stream>>>(bq_a,bk_a,bv_a,bq_b,bk_b,bv_b, biasc);
    transpose_w<<<dim3(8,16,4), dim3(32,8), 0, stream>>>(Wfuse, fuseWt, 512, 256);
    transpose_w<<<dim3(32,8,4), dim3(32,8), 0, stream>>>(W1, W1t, 256, 1024);
    transpose_w<<<dim3(8,32,4), dim3(32,8), 0, stream>>>(W2, W2t, 1024, 256);
    transpose_w<<<dim3(8,8,1),  dim3(32,8), 0, stream>>>(fp_W, fpWt, 256, 256);
    transpose_w<<<dim3(8,32,1), dim3(32,8), 0, stream>>>(ff_W, ffWt, 1024, 256);
    transpose_w<<<dim3(24,8,1), dim3(32,8), 0, stream>>>(mha_Wqkv, qkvWt, 256, 768);
    transpose_w<<<dim3(8,8,1),  dim3(32,8), 0, stream>>>(mha_Wo, WoWt, 256, 256);

    // two groups of 4 independent block invocations (a-side = s[inv]):
    // A = {bi0,bi2,bi4,bi6}: i={0,0,2,1}, b={1,0,1,0}, accum=0
    // B = {bi1,bi3,bi5,bi7}: i={1,2,3,3}, b={3,2,3,2}, accum=1
    const int GI[2][4] = {{0,0,2,1},{1,2,3,3}};
    const int GB[2][4] = {{1,0,1,0},{3,2,3,2}};

    for (int g = 0; g < 2; g++) {
        int i0 = GI[g][0], i1 = GI[g][1], i2 = GI[g][2], i3 = GI[g][3];
        proj8_kernel<<<4704, 256, 0, stream>>>(s,
            GB[g][0], GB[g][1], GB[g][2], GB[g][3], i0, i1, i2, i3,
            projWt, biasc, projc);
        vtrans_kernel<<<dim3(13,32,8), 256, 0, stream>>>(projc, 0, vt);
        attn_pair_kernel<<<1792, 256, 0, stream>>>(projc, vt, fin);
        gemm2_kernel<<<784, 256, 0, stream>>>(fin, 512, (int)(2*MD),
            fuseWt, 512, i0, i1, i2, i3, 131072, bfuse, 256, fb, 256, (int)MD, 0, 4, 784);
        ln_kernel<<<dim3(784,4), 256, 0, stream>>>(fb, (int)MD,
            s, (int)MD, gamma, i0, i1, i2, i3, ln1_g, ln1_b, 256,
            xa1, (int)MD, 1.0f, 0, 256);
        gemm2_kernel<<<3136, 256, 0, stream>>>(xa1, 256, (int)MD,
            W1t, 256, i0, i1, i2, i3, 262144, b1, 1024, ffh, 1024, (int)(4*MD), 1, 16, 3136);
        gemm2_kernel<<<784, 256, 0, stream>>>(ffh, 1024, (int)(4*MD),
            W2t, 1024, i0, i1, i2, i3, 262144, b2, 256, ffb, 256, (int)MD, 0, 4, 784);
        ln_kernel<<<dim3(784,4), 256, 0, stream>>>(ffb, (int)MD,
            xa1, (int)MD, gamma_ffn, i0, i1, i2, i3, ln2_g, ln2_b, 256,
            e, (int)MD, 0.5f, g, 256);
    }

    // final fuse stage (reuse dead scratch; e live until first LN done)
    u16* ln4    = act + 8*MD;        // 4 MD
    u16* allf   = act + 12*MD;       // 4 MD  [3136][1024]
    u16* ffln   = act + 16*MD;       // 4 MD
    u16* x2     = act + 20*MD;       // 1 MD
    u16* qkv    = act + 21*MD;       // 3 MD  [3136][768]
    u16* vtmha  = act + 24*MD;       // 1 MD
    u16* attn_o = act + 25*MD;       // 1 MD
    u16* ymid   = act + 26*MD;       // 1 MD
    u16* yfin   = act + 27*MD;       // 1 MD

    ln_kernel<<<dim3(784,4), 256, 0, stream>>>(e, (int)MD,
        (const u16*)nullptr, 0, (const float*)nullptr, 0,0,0,0,
        fp_ln_g, fp_ln_b, 0, ln4, (int)MD, 1.0f, 0, 256);
    gemm2_kernel<<<784, 256, 0, stream>>>(ln4, 256, (int)MD,
        fpWt, 256, 0,0,0,0, 0, fp_b, 0, allf, 1024, 256, 1, 4, 784);
    ln_kernel<<<dim3(784,1), 256, 0, stream>>>(allf, 0,
        (const u16*)nullptr, 0, (const float*)nullptr, 0,0,0,0,
        ff_ln_g, ff_ln_b, 0, ffln, 0, 1.0f, 0, 1024);
    gemm2_kernel<<<196, 256, 0, stream>>>(ffln, 1024, 0,
        ffWt, 1024, 0,0,0,0, 0, ff_b, 0, x2, 256, 0, 1, 4, 196);
    gemm2_kernel<<<588, 256, 0, stream>>>(x2, 256, 0,
        qkvWt, 256, 0,0,0,0, 0, mha_bqkv, 0, qkv, 768, 0, 0, 12, 588);
    vtrans_kernel<<<dim3(13,32,1), 256, 0, stream>>>(qkv, 1, vtmha);
    attn_mha_kernel<<<224, 256, 0, stream>>>(qkv, vtmha, attn_o);
    gemm2_kernel<<<196, 256, 0, stream>>>(attn_o, 256, 0,
        WoWt, 256, 0,0,0,0, 0, mha_bo, 0, ymid, 256, 0, 0, 4, 196);
    ln_kernel<<<dim3(784,1), 256, 0, stream>>>(ymid, 0,
        (const u16*)nullptr, 0, (const float*)nullptr, 0,0,0,0,
        norm_g, norm_b, 0, yfin, 0, 1.0f, 0, 256);
    from_seq_kernel<<<dim3(49,16,4), dim3(16,16), 0, stream>>>(yfin, (float*)d_out);
}

// Round 15
// 377.124 us; speedup vs baseline: 1.3164x; 1.1287x over previous
//
#include <hip/hip_runtime.h>

typedef unsigned short u16;
typedef __bf16 bf16x8 __attribute__((ext_vector_type(8)));
typedef float f32x4 __attribute__((ext_vector_type(4)));
typedef float f32x16 __attribute__((ext_vector_type(16)));
typedef unsigned short u16x8 __attribute__((ext_vector_type(8)));
typedef unsigned short u16x4 __attribute__((ext_vector_type(4)));

static constexpr size_t MD = 802816;   // 3136*256 elements

__device__ __forceinline__ u16 f2bf(float f) {
    __bf16 h = (__bf16)f;
    return __builtin_bit_cast(unsigned short, h);
}
__device__ __forceinline__ float bf2f(u16 u) {
    return __uint_as_float(((unsigned)u) << 16);
}
__device__ __forceinline__ float gelu_f(float x) {
    return 0.5f * x * (1.0f + erff(x * 0.70710678118654752f));
}
// pack two f32 -> two bf16 in one u32 (low = a, high = b)
__device__ __forceinline__ unsigned cvt_pk_bf16(float a, float b) {
    unsigned r;
    asm("v_cvt_pk_bf16_f32 %0, %1, %2" : "=v"(r) : "v"(a), "v"(b));
    return r;
}
// raw 2^x via the ISA instruction (v_exp_f32 -> D = 2^S0).
// NOTE: __builtin_amdgcn_exp2f gave WRONG results (R8/R9); inline asm pins it.
__device__ __forceinline__ float exp2_hw(float x) {
    float r;
    asm("v_exp_f32 %0, %1" : "=v"(r) : "v"(x));
    return r;
}
// bijective XCD swizzle (m204 form): blocks with the same hw XCD (id%8) get a
// CONTIGUOUS logical range -> operand panels stay resident in that XCD's L2.
__device__ __forceinline__ int xcd_swz(int id, int nwg) {
    int q = nwg >> 3, r = nwg & 7;
    int xcd = id & 7, idx = id >> 3;
    return (xcd < r) ? (xcd * (q + 1) + idx) : (r * (q + 1) + (xcd - r) * q + idx);
}
union u8_4 { u16x8 v8; u16x4 v4[2]; };
union bf8_4 { bf16x8 f; u16x4 h[2]; u16x8 v8; };

// ------------- bf16 GEMM core, 64x64 tile, BK=64, swapped epilogue ----------
// C staged via LDS -> 32B/lane contiguous stores (R13: removed 2x write amp).
__device__ __forceinline__ void gemm_core(
    const u16* __restrict__ A, int lda,
    const u16* __restrict__ Bt, int K,
    const float* __restrict__ bias,
    u16* __restrict__ C, int ldc, int act, int m0, int n0)
{
    __shared__ u16 As[64][72];
    __shared__ u16 Bs[64][72];
    const int tid  = threadIdx.x;
    const int wave = tid >> 6, lane = tid & 63;
    const int wr = wave >> 1, wc = wave & 1;
    const int l16 = lane & 15, kg = lane >> 4, kb = kg * 8;
    const int srow = tid >> 2, scol = (tid & 3) * 16;

    f32x4 acc[2][2];   // [n-frag][m-frag]
#pragma unroll
    for (int j = 0; j < 2; j++)
#pragma unroll
        for (int i = 0; i < 2; i++) { f32x4 z = {0.f,0.f,0.f,0.f}; acc[j][i] = z; }

    const u16* ap = A + (size_t)(m0 + srow) * lda + scol;
    const u16* bp = Bt + (size_t)(n0 + srow) * K + scol;
    u16x8 ua0 = *(const u16x8*)ap;
    u16x8 ua1 = *(const u16x8*)(ap + 8);
    u16x8 ub0 = *(const u16x8*)bp;
    u16x8 ub1 = *(const u16x8*)(bp + 8);

    for (int kt = 0; kt < K; kt += 64) {
        *(u16x8*)&As[srow][scol]     = ua0;
        *(u16x8*)&As[srow][scol + 8] = ua1;
        *(u16x8*)&Bs[srow][scol]     = ub0;
        *(u16x8*)&Bs[srow][scol + 8] = ub1;
        __syncthreads();
        if (kt + 64 < K) {
            ua0 = *(const u16x8*)(ap + kt + 64);
            ua1 = *(const u16x8*)(ap + kt + 72);
            ub0 = *(const u16x8*)(bp + kt + 64);
            ub1 = *(const u16x8*)(bp + kt + 72);
        }
#pragma unroll
        for (int h = 0; h < 2; h++) {
            bf16x8 af[2], bf[2];
#pragma unroll
            for (int j = 0; j < 2; j++)
                af[j] = *(const bf16x8*)&Bs[wc*32 + j*16 + l16][h*32 + kb];
#pragma unroll
            for (int i = 0; i < 2; i++)
                bf[i] = *(const bf16x8*)&As[wr*32 + i*16 + l16][h*32 + kb];
#pragma unroll
            for (int j = 0; j < 2; j++)
#pragma unroll
                for (int i = 0; i < 2; i++)
                    acc[j][i] = __builtin_amdgcn_mfma_f32_16x16x32_bf16(
                        af[j], bf[i], acc[j][i], 0,0,0);
        }
        __syncthreads();
    }
    // stage C quadrants into As (each wave owns rows wr*32+.., cols wc*32+..)
#pragma unroll
    for (int j = 0; j < 2; j++) {
        int lcol = wc*32 + j*16 + kg*4;
        f32x4 bv = *(const f32x4*)&bias[n0 + lcol];
#pragma unroll
        for (int i = 0; i < 2; i++) {
            int lrow = wr*32 + i*16 + l16;
            u16x4 o;
#pragma unroll
            for (int r = 0; r < 4; r++) {
                float v = acc[j][i][r] + bv[r];
                if (act == 1) v = gelu_f(v);
                o[r] = f2bf(v);
            }
            *(u16x4*)&As[lrow][lcol] = o;
        }
    }
    __syncthreads();
    {   // coalesced write: 4 threads per row x 32B = full 128B row
        int crow = tid >> 2, cc = (tid & 3) * 16;
        u16x8 c0 = *(const u16x8*)&As[crow][cc];
        u16x8 c1 = *(const u16x8*)&As[crow][cc + 8];
        u16* cp = &C[(size_t)(m0 + crow) * ldc + n0 + cc];
        *(u16x8*)cp = c0;
        *(u16x8*)(cp + 8) = c1;
    }
}

// generic z-batched GEMM (64x64), 1D grid, XCD-swizzled, n fastest
__global__ __launch_bounds__(256) void gemm2_kernel(
    const u16* __restrict__ A, int lda, int zA,
    const u16* __restrict__ Bt, int K, int i0, int i1, int i2, int i3, int Bsz,
    const float* __restrict__ bias, int bN,
    u16* __restrict__ C, int ldc, int zC, int act, int nN, int nwg)
{
    int wg = xcd_swz(blockIdx.x, nwg);
    int n = wg % nN, rest = wg / nN;
    int m = rest % 49, z = rest / 49;
    int iz = (z == 0) ? i0 : (z == 1) ? i1 : (z == 2) ? i2 : i3;
    gemm_core(A + (size_t)z * zA, lda,
              Bt + (size_t)iz * Bsz, K,
              bias + (size_t)iz * bN,
              C + (size_t)z * zC, ldc, act, m * 64, n * 64);
}

// cat projections: z = inv*2 + ab; output [3136][768]; 1D grid, swizzled
__global__ __launch_bounds__(256) void proj8_kernel(
    const u16* __restrict__ s, int b0, int b1, int b2, int b3,
    int i0, int i1, int i2, int i3,
    const u16* __restrict__ projWt, const float* __restrict__ biasc,
    u16* __restrict__ projc)
{
    int wg = xcd_swz(blockIdx.x, 4704);       // 49*12*8
    int n = wg % 12, rest = wg / 12;
    int m = rest % 49, z = rest / 49;
    int inv = z >> 1, ab = z & 1;
    int bi = (inv == 0) ? b0 : (inv == 1) ? b1 : (inv == 2) ? b2 : b3;
    int ii = (inv == 0) ? i0 : (inv == 1) ? i1 : (inv == 2) ? i2 : i3;
    const u16* Aact = s + (size_t)(ab ? bi : inv) * MD;
    int widx = ii * 2 + ab;
    gemm_core(Aact, 256, projWt + (size_t)widx * 768 * 256, 256,
              biasc + widx * 768,
              projc + (size_t)z * 3 * MD, 768, 0, m * 64, n * 64);
}

__global__ __launch_bounds__(256) void pack_bias_kernel(
    const float* b0, const float* b1, const float* b2,
    const float* b3, const float* b4, const float* b5,
    float* __restrict__ biasc)
{
    int z = blockIdx.x;
    int tsr = z >> 2, i = z & 3;
    const float* barr[6] = {b0,b1,b2,b3,b4,b5};
    int ab = (tsr >= 3) ? 1 : 0;
    biasc[(i*2 + ab)*768 + (tsr % 3)*256 + threadIdx.x] = barr[tsr][i*256 + threadIdx.x];
}

// ---------------- flash attention core, 32x32x16 MFMA, 32 q-rows/wave -------
// ONE barrier per KV tile: writes at iter t go to buffer cur^1 whose last
// readers (iter t-1) were all released by the end-of-(t-1) barrier.
__device__ __forceinline__ void attn3_core(
    const u16* __restrict__ Qg, int ldq,
    const u16* __restrict__ Kg, int ldk,
    const u16* __restrict__ Vtg,          // [32 d][784 k] for this (b,h)
    u16* __restrict__ Og, int ldo,
    int qt, int rowbase, int qkcol, int ocol)
{
    __shared__ u16 Ks[2][64][36];
    __shared__ u16 Vts[2][32][68];
    __shared__ u16 Ps[4][32][68];
    __shared__ float Ls[4][32];

    const int tid = threadIdx.x, wave = tid >> 6, lane = tid & 63;
    const int l32 = lane & 31, hi = lane >> 5;
    const int sr = tid >> 2, sc8 = (tid & 3) * 8;     // K stage: 64r x 32c
    const int vd = tid >> 3, vk8 = (tid & 7) * 8;     // V stage: 32r x 64c
    const float QSC = 0.25503489f;        // 32^-0.5 * log2(e)

    // direct Q fragment load (pre-scaled): row = qt*128 + wave*32 + l32
    bf8_4 qf0, qf1;
    {
        int qrow = qt*128 + wave*32 + l32;
        u16x8 z8 = {0,0,0,0,0,0,0,0};
        u16x8 q0 = z8, q1 = z8;
        if (qrow < 784) {
            const u16* qp = Qg + (size_t)(rowbase + qrow) * ldq + qkcol;
            q0 = *(const u16x8*)(qp + hi*8);        // cols hi*8 .. hi*8+7
            q1 = *(const u16x8*)(qp + 16 + hi*8);   // cols 16+hi*8 ..
        }
#pragma unroll
        for (int j = 0; j < 8; j++) {
            q0[j] = f2bf(bf2f(q0[j]) * QSC);
            q1[j] = f2bf(bf2f(q1[j]) * QSC);
        }
        qf0.v8 = q0;
        qf1.v8 = q1;
    }
    {   // stage K,V tile 0 (all rows/cols valid)
        u8_4 k, v;
        k.v8 = *(const u16x8*)(Kg + (size_t)(rowbase + sr) * ldk + qkcol + sc8);
        v.v8 = *(const u16x8*)(Vtg + (size_t)vd * 784 + vk8);
        *(u16x4*)&Ks[0][sr][sc8]     = k.v4[0];
        *(u16x4*)&Ks[0][sr][sc8 + 4] = k.v4[1];
        *(u16x4*)&Vts[0][vd][vk8]     = v.v4[0];
        *(u16x4*)&Vts[0][vd][vk8 + 4] = v.v4[1];
    }
    __syncthreads();

    f32x16 oacc;
#pragma unroll
    for (int i = 0; i < 16; i++) oacc[i] = 0.f;
    float lsum = 0.f;

    u16x8 kr, vr;
    for (int t = 0; t < 13; ++t) {
        const int cur = t & 1;
        if (t < 12) {   // prefetch next tile into regs
            u16x8 z8 = {0,0,0,0,0,0,0,0}; kr = z8; vr = z8;
            int krow = (t+1)*64 + sr;
            if (krow < 784)
                kr = *(const u16x8*)(Kg + (size_t)(rowbase + krow) * ldk + qkcol + sc8);
            int kc = (t+1)*64 + vk8;
            if (kc + 7 < 784)
                vr = *(const u16x8*)(Vtg + (size_t)vd * 784 + kc);
        }
        const int kvalid = (t == 12) ? 16 : 64;
        // S^T (two 32k blocks): C row = k-local, col = q = l32
#pragma unroll
        for (int kb2 = 0; kb2 < 2; kb2++) {
            f32x16 sacc;
#pragma unroll
            for (int i = 0; i < 16; i++) sacc[i] = 0.f;
            bf8_4 kf0, kf1;
            kf0.h[0] = *(const u16x4*)&Ks[cur][kb2*32 + l32][hi*8];
            kf0.h[1] = *(const u16x4*)&Ks[cur][kb2*32 + l32][hi*8 + 4];
            kf1.h[0] = *(const u16x4*)&Ks[cur][kb2*32 + l32][16 + hi*8];
            kf1.h[1] = *(const u16x4*)&Ks[cur][kb2*32 + l32][16 + hi*8 + 4];
            sacc = __builtin_amdgcn_mfma_f32_32x32x16_bf16(kf0.f, qf0.f, sacc, 0,0,0);
            sacc = __builtin_amdgcn_mfma_f32_32x32x16_bf16(kf1.f, qf1.f, sacc, 0,0,0);
#pragma unroll
            for (int g = 0; g < 4; g++) {
                int k0 = kb2*32 + 8*g + 4*hi;
                union { unsigned u[2]; u16x4 v; } pk;
                if (k0 < kvalid) {
                    float p0 = exp2_hw(sacc[4*g+0]);
                    float p1 = exp2_hw(sacc[4*g+1]);
                    float p2 = exp2_hw(sacc[4*g+2]);
                    float p3 = exp2_hw(sacc[4*g+3]);
                    lsum += (p0 + p1) + (p2 + p3);
                    pk.u[0] = cvt_pk_bf16(p0, p1);
                    pk.u[1] = cvt_pk_bf16(p2, p3);
                } else { pk.u[0] = 0; pk.u[1] = 0; }
                *(u16x4*)&Ps[wave][l32][k0] = pk.v;
            }
        }
        // PV: O[q][d] += P[q][k] V[k][d], 4 k-frags of 16
#pragma unroll
        for (int kf2 = 0; kf2 < 4; kf2++) {
            bf8_4 pf, vf;
            pf.h[0] = *(const u16x4*)&Ps[wave][l32][kf2*16 + hi*8];
            pf.h[1] = *(const u16x4*)&Ps[wave][l32][kf2*16 + hi*8 + 4];
            vf.h[0] = *(const u16x4*)&Vts[cur][l32][kf2*16 + hi*8];
            vf.h[1] = *(const u16x4*)&Vts[cur][l32][kf2*16 + hi*8 + 4];
            oacc = __builtin_amdgcn_mfma_f32_32x32x16_bf16(pf.f, vf.f, oacc, 0,0,0);
        }
        if (t < 12) {
            // write next tile to buffer cur^1: its last readers (iter t-1)
            // were released by the barrier at the end of iter t-1 -> safe
            // without an extra barrier here.
            u8_4 k, v; k.v8 = kr; v.v8 = vr;
            *(u16x4*)&Ks[cur^1][sr][sc8]     = k.v4[0];
            *(u16x4*)&Ks[cur^1][sr][sc8 + 4] = k.v4[1];
            *(u16x4*)&Vts[cur^1][vd][vk8]     = v.v4[0];
            *(u16x4*)&Vts[cur^1][vd][vk8 + 4] = v.v4[1];
            __syncthreads();
        }
    }
    // total l per q (lane l32 and l32+32 hold the two halves)
    float lt = lsum + __shfl_xor(lsum, 32);
    if (hi == 0) Ls[wave][l32] = lt;
    f32x4 lv[4];
#pragma unroll
    for (int g = 0; g < 4; g++) lv[g] = *(const f32x4*)&Ls[wave][8*g + 4*hi];
    // O store: reg 4g+j -> row j+8g+4hi, col d = l32
#pragma unroll
    for (int g = 0; g < 4; g++)
#pragma unroll
        for (int j = 0; j < 4; j++) {
            int row = qt*128 + wave*32 + 8*g + 4*hi + j;
            if (row < 784)
                Og[(size_t)(rowbase + row) * ldo + ocol + l32] =
                    f2bf(oacc[4*g+j] * __builtin_amdgcn_rcpf(lv[g][j]));
        }
}

// group-of-4 attention: 1792 blocks; z = inv*2 + dir (Q side = dir, K/V = dir^1)
__global__ __launch_bounds__(256) void attn_pair_kernel(
    const u16* __restrict__ projc, const u16* __restrict__ vt,
    u16* __restrict__ fusedin)
{
    int id = blockIdx.x;
    int wg = (id & 7) * 224 + (id >> 3);      // 1792/8 = 224
    int qt = wg % 7, bh = (wg / 7) & 31, z = wg / 224;
    int inv = z >> 1, dir = z & 1;
    const u16* Q  = projc + (size_t)z * 3 * MD;
    const u16* K  = projc + (size_t)(z ^ 1) * 3 * MD + 256;
    const u16* Vt = vt + (size_t)z * MD + (size_t)bh * 32 * 784;
    u16* O = fusedin + (size_t)inv * 2 * MD;
    int bb = bh >> 3, hh = bh & 7;
    attn3_core(Q, 768, K, 768, Vt, O, 512, qt, bb*784, hh*32, dir*256 + hh*32);
}

__global__ __launch_bounds__(256) void attn_mha_kernel(
    const u16* __restrict__ qkv, const u16* __restrict__ vtmha,
    u16* __restrict__ outp)
{
    int id = blockIdx.x;
    int wg = (id & 7) * 28 + (id >> 3);       // 224/8 = 28
    int qt = wg % 7, bh = wg / 7;
    int bb = bh >> 3, hh = bh & 7;
    const u16* Vt = vtmha + (size_t)bh * 32 * 784;
    attn3_core(qkv, 768, qkv + 256, 768, Vt, outp, 256, qt, bb*784, hh*32, hh*32);
}

// ---------------- LayerNorm (bf16 io): out = [prev +] os*(LN(res + tg*x)) ---
// 2 rows per wave (32 lanes x u16x8 = 256 cols); grid (392, z)
__global__ __launch_bounds__(256) void ln_kernel(
    const u16* __restrict__ x, int zx,
    const u16* __restrict__ res, int zres,
    const float* __restrict__ gamma, int i0, int i1, int i2, int i3,
    const float* __restrict__ g, const float* __restrict__ beta, int gN,
    u16* __restrict__ out, int zout,
    float outscale, int accum, int D)
{
    int z = blockIdx.y;
    int iz = (z == 0) ? i0 : (z == 1) ? i1 : (z == 2) ? i2 : i3;
    const u16* xb = x + (size_t)z * zx;
    const u16* rb = res ? res + (size_t)z * zres : (const u16*)nullptr;
    u16* ob = out + (size_t)z * zout;
    const float* gg = g + iz * gN;
    const float* bb = beta + iz * gN;
    int wave = threadIdx.x >> 6, lane = threadIdx.x & 63;
    int half = lane >> 5, l32 = lane & 31;
    size_t row = (size_t)blockIdx.x * 8 + wave * 2 + half;
    float tg = gamma ? tanhf(gamma[iz]) : 1.0f;
    const u16* xr = xb + row * D;
    const u16* rr = rb ? rb + row * D : (const u16*)nullptr;
    float vals[32];
    int nch = D >> 8;
    float s = 0.f, s2 = 0.f;
    for (int c = 0; c < nch; c++) {
        int col = c * 256 + l32 * 8;
        u16x8 v = *(const u16x8*)(xr + col);
        u16x8 r8 = {0,0,0,0,0,0,0,0};
        if (rr) r8 = *(const u16x8*)(rr + col);
#pragma unroll
        for (int j = 0; j < 8; j++) {
            float a = tg * bf2f(v[j]) + bf2f(r8[j]);
            vals[c*8 + j] = a;
            s += a; s2 += a * a;
        }
    }
#pragma unroll
    for (int off = 1; off < 32; off <<= 1) {
        s  += __shfl_xor(s, off);
        s2 += __shfl_xor(s2, off);
    }
    float inv = 1.0f / D;
    float mean = s * inv;
    float var = s2 * inv - mean * mean;
    float rstd = rsqrtf(var + 1e-5f);
    for (int c = 0; c < nch; c++) {
        int col = c * 256 + l32 * 8;
        u16x8 prev = {0,0,0,0,0,0,0,0};
        if (accum) prev = *(const u16x8*)(ob + row*D + col);
        u16x8 o8;
#pragma unroll
        for (int j = 0; j < 8; j++) {
            float o = (vals[c*8 + j] - mean) * rstd * gg[col + j] + bb[col + j];
            o *= outscale;
            if (accum) o += bf2f(prev[j]);
            o8[j] = f2bf(o);
        }
        *(u16x8*)(ob + row*D + col) = o8;
    }
}

// ---------------- layout kernels --------------------------------------------
__device__ __forceinline__ void transpose_body(const float* in, u16* out, int K, int N)
{
    __shared__ float t[32][33];
    int tx = threadIdx.x, ty = threadIdx.y;   // (32,8)
#pragma unroll
    for (int j = 0; j < 4; j++)
        t[ty + j*8][tx] = in[(size_t)(blockIdx.y*32 + ty + j*8) * N + blockIdx.x*32 + tx];
    __syncthreads();
#pragma unroll
    for (int j = 0; j < 4; j++)
        out[(size_t)(blockIdx.x*32 + ty + j*8) * K + blockIdx.y*32 + tx] =
            f2bf(t[tx][ty + j*8]);
}

__global__ __launch_bounds__(256) void transpose_w(const float* __restrict__ in,
                                                   u16* __restrict__ out, int K, int N)
{
    int z = blockIdx.z;
    transpose_body(in + (size_t)z * K * N, out + (size_t)z * K * N, K, N);
}

// proj weights into cat layout: [i][ab][768 n][256 k]
__global__ __launch_bounds__(256) void transpose_w6(
    const float* w0, const float* w1, const float* w2,
    const float* w3, const float* w4, const float* w5,
    u16* __restrict__ out)
{
    int z = blockIdx.z;           // 0..23: tsr = z/4, i = z%4
    int tsr = z >> 2, i = z & 3;
    const float* ws[6] = {w0,w1,w2,w3,w4,w5};
    int ab = (tsr >= 3) ? 1 : 0;
    u16* ob = out + (size_t)((i*2 + ab)*3 + (tsr % 3)) * 65536;
    transpose_body(ws[tsr] + (size_t)i * 65536, ob, 256, 256);
}

// transpose V (cols 512..767 of a 768-wide qkv buffer) -> [z][bh*32+d][784]
__global__ __launch_bounds__(256) void vtrans_kernel(
    const u16* __restrict__ base, int mode,
    u16* __restrict__ outbase)
{
    __shared__ u16 t[64][44];
    int z = blockIdx.z;
    size_t off = (mode ? (size_t)0 : (size_t)(z ^ 1) * 3 * MD) + 512;
    const u16* in = base + off;
    u16* out = outbase + (size_t)z * MD;
    int kt = blockIdx.x, bh = blockIdx.y;
    int bb = bh >> 3, hh = bh & 7;
    int tid = threadIdx.x;
    {
        int r = tid >> 2, c8 = (tid & 3) * 8;
        int krow = kt*64 + r;
        u16x8 u = {0,0,0,0,0,0,0,0};
        if (krow < 784)
            u = *(const u16x8*)(in + (size_t)(bb*784 + krow) * 768 + hh*32 + c8);
        *(u16x8*)&t[r][c8] = u;
    }
    __syncthreads();
    int d = tid >> 3, k8 = (tid & 7) * 8;
    if (kt*64 + k8 + 7 < 784) {
        u16x8 u;
#pragma unroll
        for (int j = 0; j < 8; j++) u[j] = t[k8 + j][d];
        *(u16x8*)&out[(size_t)(bh*32 + d) * 784 + kt*64 + k8] = u;
    }
}

// f[B,256,28,28] fp32 -> s[fi][b*784+hw][d] bf16
__global__ __launch_bounds__(256) void to_seq_kernel(
    const float* f0, const float* f1, const float* f2, const float* f3,
    u16* __restrict__ sbase)
{
    __shared__ float t[16][17];
    int z = blockIdx.z;
    int fi = z & 3, b = z >> 2;
    const float* fs[4] = {f0,f1,f2,f3};
    const float* f = fs[fi] + (size_t)b * 256 * 784;
    u16* s = sbase + (size_t)fi * MD + (size_t)b * 784 * 256;
    int tx = threadIdx.x, ty = threadIdx.y;  // (16,16)
    t[ty][tx] = f[(size_t)(blockIdx.y*16 + ty) * 784 + blockIdx.x*16 + tx];
    __syncthreads();
    s[(size_t)(blockIdx.x*16 + ty) * 256 + blockIdx.y*16 + tx] = f2bf(t[tx][ty]);
}

// y[b*784+hw][d] bf16 -> out[b][d][h][w] fp32
__global__ __launch_bounds__(256) void from_seq_kernel(const u16* __restrict__ y,
                                                       float* __restrict__ out)
{
    __shared__ float t[16][17];
    int b = blockIdx.z;
    const u16* yb = y + (size_t)b * 784 * 256;
    float* ob = out + (size_t)b * 256 * 784;
    int tx = threadIdx.x, ty = threadIdx.y;
    t[ty][tx] = bf2f(yb[(size_t)(blockIdx.x*16 + ty) * 256 + blockIdx.y*16 + tx]);
    __syncthreads();
    ob[(size_t)(blockIdx.y*16 + ty) * 784 + blockIdx.x*16 + tx] = t[tx][ty];
}

// ---------------- host orchestration ----------------------------------------
extern "C" void kernel_launch(void* const* d_in, const int* in_sizes, int n_in,
                              void* d_out, int out_size, void* d_ws, size_t ws_size,
                              hipStream_t stream)
{
    (void)in_sizes; (void)n_in; (void)out_size; (void)ws_size;
    const float* f0 = (const float*)d_in[0];
    const float* f1 = (const float*)d_in[1];
    const float* f2 = (const float*)d_in[2];
    const float* f3 = (const float*)d_in[3];
    const float* Wq_a = (const float*)d_in[4];
    const float* Wk_a = (const float*)d_in[5];
    const float* Wv_a = (const float*)d_in[6];
    const float* Wq_b = (const float*)d_in[7];
    const float* Wk_b = (const float*)d_in[8];
    const float* Wv_b = (const float*)d_in[9];
    const float* bq_a = (const float*)d_in[10];
    const float* bk_a = (const float*)d_in[11];
    const float* bv_a = (const float*)d_in[12];
    const float* bq_b = (const float*)d_in[13];
    const float* bk_b = (const float*)d_in[14];
    const float* bv_b = (const float*)d_in[15];
    const float* gamma = (const float*)d_in[16];
    const float* gamma_ffn = (const float*)d_in[17];
    const float* Wfuse = (const float*)d_in[18];
    const float* bfuse = (const float*)d_in[19];
    const float* W1 = (const float*)d_in[20];
    const float* b1 = (const float*)d_in[21];
    const float* W2 = (const float*)d_in[22];
    const float* b2 = (const float*)d_in[23];
    const float* ln1_g = (const float*)d_in[24];
    const float* ln1_b = (const float*)d_in[25];
    const float* ln2_g = (const float*)d_in[26];
    const float* ln2_b = (const float*)d_in[27];
    const float* fp_ln_g = (const float*)d_in[28];
    const float* fp_ln_b = (const float*)d_in[29];
    const float* fp_W = (const float*)d_in[30];
    const float* fp_b = (const float*)d_in[31];
    const float* ff_ln_g = (const float*)d_in[32];
    const float* ff_ln_b = (const float*)d_in[33];
    const float* ff_W = (const float*)d_in[34];
    const float* ff_b = (const float*)d_in[35];
    const float* mha_Wqkv = (const float*)d_in[36];
    const float* mha_bqkv = (const float*)d_in[37];
    const float* mha_Wo = (const float*)d_in[38];
    const float* mha_bo = (const float*)d_in[39];
    const float* norm_g = (const float*)d_in[40];
    const float* norm_b = (const float*)d_in[41];

    u16* W = (u16*)d_ws;
    u16* projWt = W;                          // 24*65536 = 1572864
    u16* fuseWt = projWt + 1572864;           // 524288
    u16* W1t    = fuseWt + 524288;            // 1048576
    u16* W2t    = W1t + 1048576;              // 1048576
    u16* fpWt   = W2t + 1048576;              // 65536
    u16* ffWt   = fpWt + 65536;               // 262144
    u16* qkvWt  = ffWt + 262144;              // 196608
    u16* WoWt   = qkvWt + 196608;             // 65536
    float* biasc = (float*)(WoWt + 65536);    // 6144 floats
    u16* act    = (u16*)(biasc + 6144);

    u16* s     = act;               // 4 MD
    u16* e     = act + 4*MD;        // 4 MD
    u16* projc = act + 8*MD;        // 24 MD
    u16* vt    = act + 32*MD;       // 8 MD
    u16* fin   = act + 40*MD;       // 8 MD   (peak: 48 MD)
    // overlays (projc/vt dead at time of use)
    u16* ffh  = projc;              // 16 MD
    u16* fb   = projc + 16*MD;      // 4 MD
    u16* xa1  = projc + 20*MD;      // 4 MD
    u16* ffb  = vt;                 // 4 MD

    // input layout + weight pre-transpose
    to_seq_kernel<<<dim3(49,16,16), dim3(16,16), 0, stream>>>(f0,f1,f2,f3, s);
    transpose_w6<<<dim3(8,8,24), dim3(32,8), 0, stream>>>(Wq_a,Wk_a,Wv_a,Wq_b,Wk_b,Wv_b, projWt);
    pack_bias_kernel<<<24, 256, 0, stream>>>(bq_a,bk_a,bv_a,bq_b,bk_b,bv_b, biasc);
    transpose_w<<<dim3(8,16,4), dim3(32,8), 0, stream>>>(Wfuse, fuseWt, 512, 256);
    transpose_w<<<dim3(32,8,4), dim3(32,8), 0, stream>>>(W1, W1t, 256, 1024);
    transpose_w<<<dim3(8,32,4), dim3(32,8), 0, stream>>>(W2, W2t, 1024, 256);
    transpose_w<<<dim3(8,8,1),  dim3(32,8), 0, stream>>>(fp_W, fpWt, 256, 256);
    transpose_w<<<dim3(8,32,1), dim3(32,8), 0, stream>>>(ff_W, ffWt, 1024, 256);
    transpose_w<<<dim3(24,8,1), dim3(32,8), 0, stream>>>(mha_Wqkv, qkvWt, 256, 768);
    transpose_w<<<dim3(8,8,1),  dim3(32,8), 0, stream>>>(mha_Wo, WoWt, 256, 256);

    // two groups of 4 independent block invocations (a-side = s[inv]):
    // A = {bi0,bi2,bi4,bi6}: i={0,0,2,1}, b={1,0,1,0}, accum=0
    // B = {bi1,bi3,bi5,bi7}: i={1,2,3,3}, b={3,2,3,2}, accum=1
    const int GI[2][4] = {{0,0,2,1},{1,2,3,3}};
    const int GB[2][4] = {{1,0,1,0},{3,2,3,2}};

    for (int g = 0; g < 2; g++) {
        int i0 = GI[g][0], i1 = GI[g][1], i2 = GI[g][2], i3 = GI[g][3];
        proj8_kernel<<<4704, 256, 0, stream>>>(s,
            GB[g][0], GB[g][1], GB[g][2], GB[g][3], i0, i1, i2, i3,
            projWt, biasc, projc);
        vtrans_kernel<<<dim3(13,32,8), 256, 0, stream>>>(projc, 0, vt);
        attn_pair_kernel<<<1792, 256, 0, stream>>>(projc, vt, fin);
        gemm2_kernel<<<784, 256, 0, stream>>>(fin, 512, (int)(2*MD),
            fuseWt, 512, i0, i1, i2, i3, 131072, bfuse, 256, fb, 256, (int)MD, 0, 4, 784);
        ln_kernel<<<dim3(392,4), 256, 0, stream>>>(fb, (int)MD,
            s, (int)MD, gamma, i0, i1, i2, i3, ln1_g, ln1_b, 256,
            xa1, (int)MD, 1.0f, 0, 256);
        gemm2_kernel<<<3136, 256, 0, stream>>>(xa1, 256, (int)MD,
            W1t, 256, i0, i1, i2, i3, 262144, b1, 1024, ffh, 1024, (int)(4*MD), 1, 16, 3136);
        gemm2_kernel<<<784, 256, 0, stream>>>(ffh, 1024, (int)(4*MD),
            W2t, 1024, i0, i1, i2, i3, 262144, b2, 256, ffb, 256, (int)MD, 0, 4, 784);
        ln_kernel<<<dim3(392,4), 256, 0, stream>>>(ffb, (int)MD,
            xa1, (int)MD, gamma_ffn, i0, i1, i2, i3, ln2_g, ln2_b, 256,
            e, (int)MD, 0.5f, g, 256);
    }

    // final fuse stage (reuse dead scratch; e live until first LN done)
    u16* ln4    = act + 8*MD;        // 4 MD
    u16* allf   = act + 12*MD;       // 4 MD  [3136][1024]
    u16* ffln   = act + 16*MD;       // 4 MD
    u16* x2     = act + 20*MD;       // 1 MD
    u16* qkv    = act + 21*MD;       // 3 MD  [3136][768]
    u16* vtmha  = act + 24*MD;       // 1 MD
    u16* attn_o = act + 25*MD;       // 1 MD
    u16* ymid   = act + 26*MD;       // 1 MD
    u16* yfin   = act + 27*MD;       // 1 MD

    ln_kernel<<<dim3(392,4), 256, 0, stream>>>(e, (int)MD,
        (const u16*)nullptr, 0, (const float*)nullptr, 0,0,0,0,
        fp_ln_g, fp_ln_b, 0, ln4, (int)MD, 1.0f, 0, 256);
    gemm2_kernel<<<784, 256, 0, stream>>>(ln4, 256, (int)MD,
        fpWt, 256, 0,0,0,0, 0, fp_b, 0, allf, 1024, 256, 1, 4, 784);
    ln_kernel<<<dim3(392,1), 256, 0, stream>>>(allf, 0,
        (const u16*)nullptr, 0, (const float*)nullptr, 0,0,0,0,
        ff_ln_g, ff_ln_b, 0, ffln, 0, 1.0f, 0, 1024);
    gemm2_kernel<<<196, 256, 0, stream>>>(ffln, 1024, 0,
        ffWt, 1024, 0,0,0,0, 0, ff_b, 0, x2, 256, 0, 1, 4, 196);
    gemm2_kernel<<<588, 256, 0, stream>>>(x2, 256, 0,
        qkvWt, 256, 0,0,0,0, 0, mha_bqkv, 0, qkv, 768, 0, 0, 12, 588);
    vtrans_kernel<<<dim3(13,32,1), 256, 0, stream>>>(qkv, 1, vtmha);
    attn_mha_kernel<<<224, 256, 0, stream>>>(qkv, vtmha, attn_o);
    gemm2_kernel<<<196, 256, 0, stream>>>(attn_o, 256, 0,
        WoWt, 256, 0,0,0,0, 0, mha_bo, 0, ymid, 256, 0, 0, 4, 196);
    ln_kernel<<<dim3(392,1), 256, 0, stream>>>(ymid, 0,
        (const u16*)nullptr, 0, (const float*)nullptr, 0,0,0,0,
        norm_g, norm_b, 0, yfin, 0, 1.0f, 0, 256);
    from_seq_kernel<<<dim3(49,16,4), dim3(16,16), 0, stream>>>(yfin, (float*)d_out);
}

// Round 16
// 366.052 us; speedup vs baseline: 1.3562x; 1.0302x over previous
//
#include <hip/hip_runtime.h>

typedef unsigned short u16;
typedef __bf16 bf16x8 __attribute__((ext_vector_type(8)));
typedef float f32x4 __attribute__((ext_vector_type(4)));
typedef float f32x16 __attribute__((ext_vector_type(16)));
typedef unsigned short u16x8 __attribute__((ext_vector_type(8)));
typedef unsigned short u16x4 __attribute__((ext_vector_type(4)));

static constexpr size_t MD = 802816;   // 3136*256 elements

__device__ __forceinline__ u16 f2bf(float f) {
    __bf16 h = (__bf16)f;
    return __builtin_bit_cast(unsigned short, h);
}
__device__ __forceinline__ float bf2f(u16 u) {
    return __uint_as_float(((unsigned)u) << 16);
}
__device__ __forceinline__ float gelu_f(float x) {
    return 0.5f * x * (1.0f + erff(x * 0.70710678118654752f));
}
// pack two f32 -> two bf16 in one u32 (low = a, high = b)
__device__ __forceinline__ unsigned cvt_pk_bf16(float a, float b) {
    unsigned r;
    asm("v_cvt_pk_bf16_f32 %0, %1, %2" : "=v"(r) : "v"(a), "v"(b));
    return r;
}
// raw 2^x via the ISA instruction (v_exp_f32 -> D = 2^S0).
// NOTE: __builtin_amdgcn_exp2f gave WRONG results (R8/R9); inline asm pins it.
__device__ __forceinline__ float exp2_hw(float x) {
    float r;
    asm("v_exp_f32 %0, %1" : "=v"(r) : "v"(x));
    return r;
}
// bijective XCD swizzle (m204 form)
__device__ __forceinline__ int xcd_swz(int id, int nwg) {
    int q = nwg >> 3, r = nwg & 7;
    int xcd = id & 7, idx = id >> 3;
    return (xcd < r) ? (xcd * (q + 1) + idx) : (r * (q + 1) + (xcd - r) * q + idx);
}
union u8_4 { u16x8 v8; u16x4 v4[2]; };
union bf8_4 { bf16x8 f; u16x4 h[2]; u16x8 v8; };

// ------------- bf16 GEMM core, 64x64 tile, BK=64, swapped epilogue ----------
// C staged via LDS -> 32B/lane contiguous stores. If VT != null and this is a
// V-tile (n0 >= 512), the tile is written TRANSPOSED to VT ([bh*32+d][784])
// instead of C — eliminates the separate vtrans pass (V only read via vt).
__device__ __forceinline__ void gemm_core(
    const u16* __restrict__ A, int lda,
    const u16* __restrict__ Bt, int K,
    const float* __restrict__ bias,
    u16* __restrict__ C, int ldc, int act, int m0, int n0,
    u16* __restrict__ VT)
{
    __shared__ u16 As[64][72];
    __shared__ u16 Bs[64][72];
    const int tid  = threadIdx.x;
    const int wave = tid >> 6, lane = tid & 63;
    const int wr = wave >> 1, wc = wave & 1;
    const int l16 = lane & 15, kg = lane >> 4, kb = kg * 8;
    const int srow = tid >> 2, scol = (tid & 3) * 16;

    f32x4 acc[2][2];   // [n-frag][m-frag]
#pragma unroll
    for (int j = 0; j < 2; j++)
#pragma unroll
        for (int i = 0; i < 2; i++) { f32x4 z = {0.f,0.f,0.f,0.f}; acc[j][i] = z; }

    const u16* ap = A + (size_t)(m0 + srow) * lda + scol;
    const u16* bp = Bt + (size_t)(n0 + srow) * K + scol;
    u16x8 ua0 = *(const u16x8*)ap;
    u16x8 ua1 = *(const u16x8*)(ap + 8);
    u16x8 ub0 = *(const u16x8*)bp;
    u16x8 ub1 = *(const u16x8*)(bp + 8);

    for (int kt = 0; kt < K; kt += 64) {
        *(u16x8*)&As[srow][scol]     = ua0;
        *(u16x8*)&As[srow][scol + 8] = ua1;
        *(u16x8*)&Bs[srow][scol]     = ub0;
        *(u16x8*)&Bs[srow][scol + 8] = ub1;
        __syncthreads();
        if (kt + 64 < K) {
            ua0 = *(const u16x8*)(ap + kt + 64);
            ua1 = *(const u16x8*)(ap + kt + 72);
            ub0 = *(const u16x8*)(bp + kt + 64);
            ub1 = *(const u16x8*)(bp + kt + 72);
        }
#pragma unroll
        for (int h = 0; h < 2; h++) {
            bf16x8 af[2], bf[2];
#pragma unroll
            for (int j = 0; j < 2; j++)
                af[j] = *(const bf16x8*)&Bs[wc*32 + j*16 + l16][h*32 + kb];
#pragma unroll
            for (int i = 0; i < 2; i++)
                bf[i] = *(const bf16x8*)&As[wr*32 + i*16 + l16][h*32 + kb];
#pragma unroll
            for (int j = 0; j < 2; j++)
#pragma unroll
                for (int i = 0; i < 2; i++)
                    acc[j][i] = __builtin_amdgcn_mfma_f32_16x16x32_bf16(
                        af[j], bf[i], acc[j][i], 0,0,0);
        }
        __syncthreads();
    }
    // stage C quadrants into As (each wave owns rows wr*32+.., cols wc*32+..)
#pragma unroll
    for (int j = 0; j < 2; j++) {
        int lcol = wc*32 + j*16 + kg*4;
        f32x4 bv = *(const f32x4*)&bias[n0 + lcol];
#pragma unroll
        for (int i = 0; i < 2; i++) {
            int lrow = wr*32 + i*16 + l16;
            u16x4 o;
#pragma unroll
            for (int r = 0; r < 4; r++) {
                float v = acc[j][i][r] + bv[r];
                if (act == 1) v = gelu_f(v);
                o[r] = f2bf(v);
            }
            *(u16x4*)&As[lrow][lcol] = o;
        }
    }
    __syncthreads();
    if (VT && n0 >= 512) {
        // transposed write: col c of the tile -> vt row (bb*8+hh)*32+d,
        // 16 contiguous k per thread (784 = 49*16 -> chunk never straddles bb)
        int c = tid & 63, chunk = tid >> 6;
        int dg = n0 - 512 + c;                 // 0..255
        int hh2 = dg >> 5, dd = dg & 31;
        int grow = m0 + chunk*16;
        int bb2 = grow / 784, kk0 = grow - bb2 * 784;
        u16x8 a, b;
#pragma unroll
        for (int j = 0; j < 8; j++) a[j] = As[chunk*16 + j][c];
#pragma unroll
        for (int j = 0; j < 8; j++) b[j] = As[chunk*16 + 8 + j][c];
        u16* vp = VT + ((size_t)(bb2*8 + hh2)*32 + dd)*784 + kk0;
        *(u16x8*)vp = a;
        *(u16x8*)(vp + 8) = b;
    } else {
        // coalesced write: 4 threads per row x 32B = full 128B row
        int crow = tid >> 2, cc = (tid & 3) * 16;
        u16x8 c0 = *(const u16x8*)&As[crow][cc];
        u16x8 c1 = *(const u16x8*)&As[crow][cc + 8];
        u16* cp = &C[(size_t)(m0 + crow) * ldc + n0 + cc];
        *(u16x8*)cp = c0;
        *(u16x8*)(cp + 8) = c1;
    }
}

// generic z-batched GEMM (64x64), 1D grid, XCD-swizzled, n fastest
__global__ __launch_bounds__(256) void gemm2_kernel(
    const u16* __restrict__ A, int lda, int zA,
    const u16* __restrict__ Bt, int K, int i0, int i1, int i2, int i3, int Bsz,
    const float* __restrict__ bias, int bN,
    u16* __restrict__ C, int ldc, int zC, int act, int nN, int nwg)
{
    int wg = xcd_swz(blockIdx.x, nwg);
    int n = wg % nN, rest = wg / nN;
    int m = rest % 49, z = rest / 49;
    int iz = (z == 0) ? i0 : (z == 1) ? i1 : (z == 2) ? i2 : i3;
    gemm_core(A + (size_t)z * zA, lda,
              Bt + (size_t)iz * Bsz, K,
              bias + (size_t)iz * bN,
              C + (size_t)z * zC, ldc, act, m * 64, n * 64, nullptr);
}

// cat projections: z = inv*2 + ab; output [3136][768]; V-tiles go transposed
// into vt[z^1] (attention z reads V of side z^1)
__global__ __launch_bounds__(256) void proj8_kernel(
    const u16* __restrict__ s, int b0, int b1, int b2, int b3,
    int i0, int i1, int i2, int i3,
    const u16* __restrict__ projWt, const float* __restrict__ biasc,
    u16* __restrict__ projc, u16* __restrict__ vt)
{
    int wg = xcd_swz(blockIdx.x, 4704);       // 49*12*8
    int n = wg % 12, rest = wg / 12;
    int m = rest % 49, z = rest / 49;
    int inv = z >> 1, ab = z & 1;
    int bi = (inv == 0) ? b0 : (inv == 1) ? b1 : (inv == 2) ? b2 : b3;
    int ii = (inv == 0) ? i0 : (inv == 1) ? i1 : (inv == 2) ? i2 : i3;
    const u16* Aact = s + (size_t)(ab ? bi : inv) * MD;
    int widx = ii * 2 + ab;
    gemm_core(Aact, 256, projWt + (size_t)widx * 768 * 256, 256,
              biasc + widx * 768,
              projc + (size_t)z * 3 * MD, 768, 0, m * 64, n * 64,
              vt + (size_t)(z ^ 1) * MD);
}

__global__ __launch_bounds__(256) void pack_bias_kernel(
    const float* b0, const float* b1, const float* b2,
    const float* b3, const float* b4, const float* b5,
    float* __restrict__ biasc)
{
    int z = blockIdx.x;
    int tsr = z >> 2, i = z & 3;
    const float* barr[6] = {b0,b1,b2,b3,b4,b5};
    int ab = (tsr >= 3) ? 1 : 0;
    biasc[(i*2 + ab)*768 + (tsr % 3)*256 + threadIdx.x] = barr[tsr][i*256 + threadIdx.x];
}

// ---------------- flash attention core, 32x32x16 MFMA, 32 q-rows/wave -------
// ONE barrier per KV tile (write to cur^1 is safe: its readers were released
// by the previous end-of-iteration barrier).
__device__ __forceinline__ void attn3_core(
    const u16* __restrict__ Qg, int ldq,
    const u16* __restrict__ Kg, int ldk,
    const u16* __restrict__ Vtg,          // [32 d][784 k] for this (b,h)
    u16* __restrict__ Og, int ldo,
    int qt, int rowbase, int qkcol, int ocol)
{
    __shared__ u16 Ks[2][64][36];
    __shared__ u16 Vts[2][32][68];
    __shared__ u16 Ps[4][32][68];
    __shared__ float Ls[4][32];

    const int tid = threadIdx.x, wave = tid >> 6, lane = tid & 63;
    const int l32 = lane & 31, hi = lane >> 5;
    const int sr = tid >> 2, sc8 = (tid & 3) * 8;     // K stage: 64r x 32c
    const int vd = tid >> 3, vk8 = (tid & 7) * 8;     // V stage: 32r x 64c
    const float QSC = 0.25503489f;        // 32^-0.5 * log2(e)

    // direct Q fragment load (pre-scaled): row = qt*128 + wave*32 + l32
    bf8_4 qf0, qf1;
    {
        int qrow = qt*128 + wave*32 + l32;
        u16x8 z8 = {0,0,0,0,0,0,0,0};
        u16x8 q0 = z8, q1 = z8;
        if (qrow < 784) {
            const u16* qp = Qg + (size_t)(rowbase + qrow) * ldq + qkcol;
            q0 = *(const u16x8*)(qp + hi*8);        // cols hi*8 .. hi*8+7
            q1 = *(const u16x8*)(qp + 16 + hi*8);   // cols 16+hi*8 ..
        }
#pragma unroll
        for (int j = 0; j < 8; j++) {
            q0[j] = f2bf(bf2f(q0[j]) * QSC);
            q1[j] = f2bf(bf2f(q1[j]) * QSC);
        }
        qf0.v8 = q0;
        qf1.v8 = q1;
    }
    {   // stage K,V tile 0 (all rows/cols valid)
        u8_4 k, v;
        k.v8 = *(const u16x8*)(Kg + (size_t)(rowbase + sr) * ldk + qkcol + sc8);
        v.v8 = *(const u16x8*)(Vtg + (size_t)vd * 784 + vk8);
        *(u16x4*)&Ks[0][sr][sc8]     = k.v4[0];
        *(u16x4*)&Ks[0][sr][sc8 + 4] = k.v4[1];
        *(u16x4*)&Vts[0][vd][vk8]     = v.v4[0];
        *(u16x4*)&Vts[0][vd][vk8 + 4] = v.v4[1];
    }
    __syncthreads();

    f32x16 oacc;
#pragma unroll
    for (int i = 0; i < 16; i++) oacc[i] = 0.f;
    float lsum = 0.f;

    u16x8 kr, vr;
    for (int t = 0; t < 13; ++t) {
        const int cur = t & 1;
        if (t < 12) {   // prefetch next tile into regs
            u16x8 z8 = {0,0,0,0,0,0,0,0}; kr = z8; vr = z8;
            int krow = (t+1)*64 + sr;
            if (krow < 784)
                kr = *(const u16x8*)(Kg + (size_t)(rowbase + krow) * ldk + qkcol + sc8);
            int kc = (t+1)*64 + vk8;
            if (kc + 7 < 784)
                vr = *(const u16x8*)(Vtg + (size_t)vd * 784 + kc);
        }
        const int kvalid = (t == 12) ? 16 : 64;
        // S^T (two 32k blocks): C row = k-local, col = q = l32
#pragma unroll
        for (int kb2 = 0; kb2 < 2; kb2++) {
            f32x16 sacc;
#pragma unroll
            for (int i = 0; i < 16; i++) sacc[i] = 0.f;
            bf8_4 kf0, kf1;
            kf0.h[0] = *(const u16x4*)&Ks[cur][kb2*32 + l32][hi*8];
            kf0.h[1] = *(const u16x4*)&Ks[cur][kb2*32 + l32][hi*8 + 4];
            kf1.h[0] = *(const u16x4*)&Ks[cur][kb2*32 + l32][16 + hi*8];
            kf1.h[1] = *(const u16x4*)&Ks[cur][kb2*32 + l32][16 + hi*8 + 4];
            sacc = __builtin_amdgcn_mfma_f32_32x32x16_bf16(kf0.f, qf0.f, sacc, 0,0,0);
            sacc = __builtin_amdgcn_mfma_f32_32x32x16_bf16(kf1.f, qf1.f, sacc, 0,0,0);
#pragma unroll
            for (int g = 0; g < 4; g++) {
                int k0 = kb2*32 + 8*g + 4*hi;
                union { unsigned u[2]; u16x4 v; } pk;
                if (k0 < kvalid) {
                    float p0 = exp2_hw(sacc[4*g+0]);
                    float p1 = exp2_hw(sacc[4*g+1]);
                    float p2 = exp2_hw(sacc[4*g+2]);
                    float p3 = exp2_hw(sacc[4*g+3]);
                    lsum += (p0 + p1) + (p2 + p3);
                    pk.u[0] = cvt_pk_bf16(p0, p1);
                    pk.u[1] = cvt_pk_bf16(p2, p3);
                } else { pk.u[0] = 0; pk.u[1] = 0; }
                *(u16x4*)&Ps[wave][l32][k0] = pk.v;
            }
        }
        // PV: O[q][d] += P[q][k] V[k][d], 4 k-frags of 16
#pragma unroll
        for (int kf2 = 0; kf2 < 4; kf2++) {
            bf8_4 pf, vf;
            pf.h[0] = *(const u16x4*)&Ps[wave][l32][kf2*16 + hi*8];
            pf.h[1] = *(const u16x4*)&Ps[wave][l32][kf2*16 + hi*8 + 4];
            vf.h[0] = *(const u16x4*)&Vts[cur][l32][kf2*16 + hi*8];
            vf.h[1] = *(const u16x4*)&Vts[cur][l32][kf2*16 + hi*8 + 4];
            oacc = __builtin_amdgcn_mfma_f32_32x32x16_bf16(pf.f, vf.f, oacc, 0,0,0);
        }
        if (t < 12) {
            u8_4 k, v; k.v8 = kr; v.v8 = vr;
            *(u16x4*)&Ks[cur^1][sr][sc8]     = k.v4[0];
            *(u16x4*)&Ks[cur^1][sr][sc8 + 4] = k.v4[1];
            *(u16x4*)&Vts[cur^1][vd][vk8]     = v.v4[0];
            *(u16x4*)&Vts[cur^1][vd][vk8 + 4] = v.v4[1];
            __syncthreads();
        }
    }
    // total l per q (lane l32 and l32+32 hold the two halves)
    float lt = lsum + __shfl_xor(lsum, 32);
    if (hi == 0) Ls[wave][l32] = lt;
    f32x4 lv[4];
#pragma unroll
    for (int g = 0; g < 4; g++) lv[g] = *(const f32x4*)&Ls[wave][8*g + 4*hi];
    // O store: reg 4g+j -> row j+8g+4hi, col d = l32
#pragma unroll
    for (int g = 0; g < 4; g++)
#pragma unroll
        for (int j = 0; j < 4; j++) {
            int row = qt*128 + wave*32 + 8*g + 4*hi + j;
            if (row < 784)
                Og[(size_t)(rowbase + row) * ldo + ocol + l32] =
                    f2bf(oacc[4*g+j] * __builtin_amdgcn_rcpf(lv[g][j]));
        }
}

// group-of-4 attention: 1792 blocks; z = inv*2 + dir (Q side = dir, K/V = dir^1)
__global__ __launch_bounds__(256) void attn_pair_kernel(
    const u16* __restrict__ projc, const u16* __restrict__ vt,
    u16* __restrict__ fusedin)
{
    int id = blockIdx.x;
    int wg = (id & 7) * 224 + (id >> 3);      // 1792/8 = 224
    int qt = wg % 7, bh = (wg / 7) & 31, z = wg / 224;
    int inv = z >> 1, dir = z & 1;
    const u16* Q  = projc + (size_t)z * 3 * MD;
    const u16* K  = projc + (size_t)(z ^ 1) * 3 * MD + 256;
    const u16* Vt = vt + (size_t)z * MD + (size_t)bh * 32 * 784;
    u16* O = fusedin + (size_t)inv * 2 * MD;
    int bb = bh >> 3, hh = bh & 7;
    attn3_core(Q, 768, K, 768, Vt, O, 512, qt, bb*784, hh*32, dir*256 + hh*32);
}

__global__ __launch_bounds__(256) void attn_mha_kernel(
    const u16* __restrict__ qkv, const u16* __restrict__ vtmha,
    u16* __restrict__ outp)
{
    int id = blockIdx.x;
    int wg = (id & 7) * 28 + (id >> 3);       // 224/8 = 28
    int qt = wg % 7, bh = wg / 7;
    int bb = bh >> 3, hh = bh & 7;
    const u16* Vt = vtmha + (size_t)bh * 32 * 784;
    attn3_core(qkv, 768, qkv + 256, 768, Vt, outp, 256, qt, bb*784, hh*32, hh*32);
}

// ---------------- LayerNorm (bf16 io): out = [prev +] os*(LN(res + tg*x)) ---
// 2 rows per wave (32 lanes x u16x8 = 256 cols); grid (392, z)
__global__ __launch_bounds__(256) void ln_kernel(
    const u16* __restrict__ x, int zx,
    const u16* __restrict__ res, int zres,
    const float* __restrict__ gamma, int i0, int i1, int i2, int i3,
    const float* __restrict__ g, const float* __restrict__ beta, int gN,
    u16* __restrict__ out, int zout,
    float outscale, int accum, int D)
{
    int z = blockIdx.y;
    int iz = (z == 0) ? i0 : (z == 1) ? i1 : (z == 2) ? i2 : i3;
    const u16* xb = x + (size_t)z * zx;
    const u16* rb = res ? res + (size_t)z * zres : (const u16*)nullptr;
    u16* ob = out + (size_t)z * zout;
    const float* gg = g + iz * gN;
    const float* bb = beta + iz * gN;
    int wave = threadIdx.x >> 6, lane = threadIdx.x & 63;
    int half = lane >> 5, l32 = lane & 31;
    size_t row = (size_t)blockIdx.x * 8 + wave * 2 + half;
    float tg = gamma ? tanhf(gamma[iz]) : 1.0f;
    const u16* xr = xb + row * D;
    const u16* rr = rb ? rb + row * D : (const u16*)nullptr;
    float vals[32];
    int nch = D >> 8;
    float s = 0.f, s2 = 0.f;
    for (int c = 0; c < nch; c++) {
        int col = c * 256 + l32 * 8;
        u16x8 v = *(const u16x8*)(xr + col);
        u16x8 r8 = {0,0,0,0,0,0,0,0};
        if (rr) r8 = *(const u16x8*)(rr + col);
#pragma unroll
        for (int j = 0; j < 8; j++) {
            float a = tg * bf2f(v[j]) + bf2f(r8[j]);
            vals[c*8 + j] = a;
            s += a; s2 += a * a;
        }
    }
#pragma unroll
    for (int off = 1; off < 32; off <<= 1) {
        s  += __shfl_xor(s, off);
        s2 += __shfl_xor(s2, off);
    }
    float inv = 1.0f / D;
    float mean = s * inv;
    float var = s2 * inv - mean * mean;
    float rstd = rsqrtf(var + 1e-5f);
    for (int c = 0; c < nch; c++) {
        int col = c * 256 + l32 * 8;
        u16x8 prev = {0,0,0,0,0,0,0,0};
        if (accum) prev = *(const u16x8*)(ob + row*D + col);
        u16x8 o8;
#pragma unroll
        for (int j = 0; j < 8; j++) {
            float o = (vals[c*8 + j] - mean) * rstd * gg[col + j] + bb[col + j];
            o *= outscale;
            if (accum) o += bf2f(prev[j]);
            o8[j] = f2bf(o);
        }
        *(u16x8*)(ob + row*D + col) = o8;
    }
}

// ---------------- layout kernels --------------------------------------------
__device__ __forceinline__ void transpose_body(const float* in, u16* out, int K, int N)
{
    __shared__ float t[32][33];
    int tx = threadIdx.x, ty = threadIdx.y;   // (32,8)
#pragma unroll
    for (int j = 0; j < 4; j++)
        t[ty + j*8][tx] = in[(size_t)(blockIdx.y*32 + ty + j*8) * N + blockIdx.x*32 + tx];
    __syncthreads();
#pragma unroll
    for (int j = 0; j < 4; j++)
        out[(size_t)(blockIdx.x*32 + ty + j*8) * K + blockIdx.y*32 + tx] =
            f2bf(t[tx][ty + j*8]);
}

__global__ __launch_bounds__(256) void transpose_w(const float* __restrict__ in,
                                                   u16* __restrict__ out, int K, int N)
{
    int z = blockIdx.z;
    transpose_body(in + (size_t)z * K * N, out + (size_t)z * K * N, K, N);
}

// proj weights into cat layout: [i][ab][768 n][256 k]
__global__ __launch_bounds__(256) void transpose_w6(
    const float* w0, const float* w1, const float* w2,
    const float* w3, const float* w4, const float* w5,
    u16* __restrict__ out)
{
    int z = blockIdx.z;           // 0..23: tsr = z/4, i = z%4
    int tsr = z >> 2, i = z & 3;
    const float* ws[6] = {w0,w1,w2,w3,w4,w5};
    int ab = (tsr >= 3) ? 1 : 0;
    u16* ob = out + (size_t)((i*2 + ab)*3 + (tsr % 3)) * 65536;
    transpose_body(ws[tsr] + (size_t)i * 65536, ob, 256, 256);
}

// transpose V (cols 512..767 of a 768-wide qkv buffer) -> [bh*32+d][784]
__global__ __launch_bounds__(256) void vtrans_kernel(
    const u16* __restrict__ base,
    u16* __restrict__ out)
{
    __shared__ u16 t[64][44];
    const u16* in = base + 512;
    int kt = blockIdx.x, bh = blockIdx.y;
    int bb = bh >> 3, hh = bh & 7;
    int tid = threadIdx.x;
    {
        int r = tid >> 2, c8 = (tid & 3) * 8;
        int krow = kt*64 + r;
        u16x8 u = {0,0,0,0,0,0,0,0};
        if (krow < 784)
            u = *(const u16x8*)(in + (size_t)(bb*784 + krow) * 768 + hh*32 + c8);
        *(u16x8*)&t[r][c8] = u;
    }
    __syncthreads();
    int d = tid >> 3, k8 = (tid & 7) * 8;
    if (kt*64 + k8 + 7 < 784) {
        u16x8 u;
#pragma unroll
        for (int j = 0; j < 8; j++) u[j] = t[k8 + j][d];
        *(u16x8*)&out[(size_t)(bh*32 + d) * 784 + kt*64 + k8] = u;
    }
}

// f[B,256,28,28] fp32 -> s[fi][b*784+hw][d] bf16
__global__ __launch_bounds__(256) void to_seq_kernel(
    const float* f0, const float* f1, const float* f2, const float* f3,
    u16* __restrict__ sbase)
{
    __shared__ float t[16][17];
    int z = blockIdx.z;
    int fi = z & 3, b = z >> 2;
    const float* fs[4] = {f0,f1,f2,f3};
    const float* f = fs[fi] + (size_t)b * 256 * 784;
    u16* s = sbase + (size_t)fi * MD + (size_t)b * 784 * 256;
    int tx = threadIdx.x, ty = threadIdx.y;  // (16,16)
    t[ty][tx] = f[(size_t)(blockIdx.y*16 + ty) * 784 + blockIdx.x*16 + tx];
    __syncthreads();
    s[(size_t)(blockIdx.x*16 + ty) * 256 + blockIdx.y*16 + tx] = f2bf(t[tx][ty]);
}

// y[b*784+hw][d] bf16 -> out[b][d][h][w] fp32
__global__ __launch_bounds__(256) void from_seq_kernel(const u16* __restrict__ y,
                                                       float* __restrict__ out)
{
    __shared__ float t[16][17];
    int b = blockIdx.z;
    const u16* yb = y + (size_t)b * 784 * 256;
    float* ob = out + (size_t)b * 256 * 784;
    int tx = threadIdx.x, ty = threadIdx.y;
    t[ty][tx] = bf2f(yb[(size_t)(blockIdx.x*16 + ty) * 256 + blockIdx.y*16 + tx]);
    __syncthreads();
    ob[(size_t)(blockIdx.y*16 + ty) * 784 + blockIdx.x*16 + tx] = t[tx][ty];
}

// ---------------- host orchestration ----------------------------------------
extern "C" void kernel_launch(void* const* d_in, const int* in_sizes, int n_in,
                              void* d_out, int out_size, void* d_ws, size_t ws_size,
                              hipStream_t stream)
{
    (void)in_sizes; (void)n_in; (void)out_size; (void)ws_size;
    const float* f0 = (const float*)d_in[0];
    const float* f1 = (const float*)d_in[1];
    const float* f2 = (const float*)d_in[2];
    const float* f3 = (const float*)d_in[3];
    const float* Wq_a = (const float*)d_in[4];
    const float* Wk_a = (const float*)d_in[5];
    const float* Wv_a = (const float*)d_in[6];
    const float* Wq_b = (const float*)d_in[7];
    const float* Wk_b = (const float*)d_in[8];
    const float* Wv_b = (const float*)d_in[9];
    const float* bq_a = (const float*)d_in[10];
    const float* bk_a = (const float*)d_in[11];
    const float* bv_a = (const float*)d_in[12];
    const float* bq_b = (const float*)d_in[13];
    const float* bk_b = (const float*)d_in[14];
    const float* bv_b = (const float*)d_in[15];
    const float* gamma = (const float*)d_in[16];
    const float* gamma_ffn = (const float*)d_in[17];
    const float* Wfuse = (const float*)d_in[18];
    const float* bfuse = (const float*)d_in[19];
    const float* W1 = (const float*)d_in[20];
    const float* b1 = (const float*)d_in[21];
    const float* W2 = (const float*)d_in[22];
    const float* b2 = (const float*)d_in[23];
    const float* ln1_g = (const float*)d_in[24];
    const float* ln1_b = (const float*)d_in[25];
    const float* ln2_g = (const float*)d_in[26];
    const float* ln2_b = (const float*)d_in[27];
    const float* fp_ln_g = (const float*)d_in[28];
    const float* fp_ln_b = (const float*)d_in[29];
    const float* fp_W = (const float*)d_in[30];
    const float* fp_b = (const float*)d_in[31];
    const float* ff_ln_g = (const float*)d_in[32];
    const float* ff_ln_b = (const float*)d_in[33];
    const float* ff_W = (const float*)d_in[34];
    const float* ff_b = (const float*)d_in[35];
    const float* mha_Wqkv = (const float*)d_in[36];
    const float* mha_bqkv = (const float*)d_in[37];
    const float* mha_Wo = (const float*)d_in[38];
    const float* mha_bo = (const float*)d_in[39];
    const float* norm_g = (const float*)d_in[40];
    const float* norm_b = (const float*)d_in[41];

    u16* W = (u16*)d_ws;
    u16* projWt = W;                          // 24*65536 = 1572864
    u16* fuseWt = projWt + 1572864;           // 524288
    u16* W1t    = fuseWt + 524288;            // 1048576
    u16* W2t    = W1t + 1048576;              // 1048576
    u16* fpWt   = W2t + 1048576;              // 65536
    u16* ffWt   = fpWt + 65536;               // 262144
    u16* qkvWt  = ffWt + 262144;              // 196608
    u16* WoWt   = qkvWt + 196608;             // 65536
    float* biasc = (float*)(WoWt + 65536);    // 6144 floats
    u16* act    = (u16*)(biasc + 6144);

    u16* s     = act;               // 4 MD
    u16* e     = act + 4*MD;        // 4 MD
    u16* projc = act + 8*MD;        // 24 MD
    u16* vt    = act + 32*MD;       // 8 MD
    u16* fin   = act + 40*MD;       // 8 MD   (peak: 48 MD)
    // overlays (projc/vt dead at time of use)
    u16* ffh  = projc;              // 16 MD
    u16* fb   = projc + 16*MD;      // 4 MD
    u16* xa1  = projc + 20*MD;      // 4 MD
    u16* ffb  = vt;                 // 4 MD

    // input layout + weight pre-transpose
    to_seq_kernel<<<dim3(49,16,16), dim3(16,16), 0, stream>>>(f0,f1,f2,f3, s);
    transpose_w6<<<dim3(8,8,24), dim3(32,8), 0, stream>>>(Wq_a,Wk_a,Wv_a,Wq_b,Wk_b,Wv_b, projWt);
    pack_bias_kernel<<<24, 256, 0, stream>>>(bq_a,bk_a,bv_a,bq_b,bk_b,bv_b, biasc);
    transpose_w<<<dim3(8,16,4), dim3(32,8), 0, stream>>>(Wfuse, fuseWt, 512, 256);
    transpose_w<<<dim3(32,8,4), dim3(32,8), 0, stream>>>(W1, W1t, 256, 1024);
    transpose_w<<<dim3(8,32,4), dim3(32,8), 0, stream>>>(W2, W2t, 1024, 256);
    transpose_w<<<dim3(8,8,1),  dim3(32,8), 0, stream>>>(fp_W, fpWt, 256, 256);
    transpose_w<<<dim3(8,32,1), dim3(32,8), 0, stream>>>(ff_W, ffWt, 1024, 256);
    transpose_w<<<dim3(24,8,1), dim3(32,8), 0, stream>>>(mha_Wqkv, qkvWt, 256, 768);
    transpose_w<<<dim3(8,8,1),  dim3(32,8), 0, stream>>>(mha_Wo, WoWt, 256, 256);

    // two groups of 4 independent block invocations (a-side = s[inv]):
    // A = {bi0,bi2,bi4,bi6}: i={0,0,2,1}, b={1,0,1,0}, accum=0
    // B = {bi1,bi3,bi5,bi7}: i={1,2,3,3}, b={3,2,3,2}, accum=1
    const int GI[2][4] = {{0,0,2,1},{1,2,3,3}};
    const int GB[2][4] = {{1,0,1,0},{3,2,3,2}};

    for (int g = 0; g < 2; g++) {
        int i0 = GI[g][0], i1 = GI[g][1], i2 = GI[g][2], i3 = GI[g][3];
        proj8_kernel<<<4704, 256, 0, stream>>>(s,
            GB[g][0], GB[g][1], GB[g][2], GB[g][3], i0, i1, i2, i3,
            projWt, biasc, projc, vt);
        attn_pair_kernel<<<1792, 256, 0, stream>>>(projc, vt, fin);
        gemm2_kernel<<<784, 256, 0, stream>>>(fin, 512, (int)(2*MD),
            fuseWt, 512, i0, i1, i2, i3, 131072, bfuse, 256, fb, 256, (int)MD, 0, 4, 784);
        ln_kernel<<<dim3(392,4), 256, 0, stream>>>(fb, (int)MD,
            s, (int)MD, gamma, i0, i1, i2, i3, ln1_g, ln1_b, 256,
            xa1, (int)MD, 1.0f, 0, 256);
        gemm2_kernel<<<3136, 256, 0, stream>>>(xa1, 256, (int)MD,
            W1t, 256, i0, i1, i2, i3, 262144, b1, 1024, ffh, 1024, (int)(4*MD), 1, 16, 3136);
        gemm2_kernel<<<784, 256, 0, stream>>>(ffh, 1024, (int)(4*MD),
            W2t, 1024, i0, i1, i2, i3, 262144, b2, 256, ffb, 256, (int)MD, 0, 4, 784);
        ln_kernel<<<dim3(392,4), 256, 0, stream>>>(ffb, (int)MD,
            xa1, (int)MD, gamma_ffn, i0, i1, i2, i3, ln2_g, ln2_b, 256,
            e, (int)MD, 0.5f, g, 256);
    }

    // final fuse stage (reuse dead scratch; e live until first LN done)
    u16* ln4    = act + 8*MD;        // 4 MD
    u16* allf   = act + 12*MD;       // 4 MD  [3136][1024]
    u16* ffln   = act + 16*MD;       // 4 MD
    u16* x2     = act + 20*MD;       // 1 MD
    u16* qkv    = act + 21*MD;       // 3 MD  [3136][768]
    u16* vtmha  = act + 24*MD;       // 1 MD
    u16* attn_o = act + 25*MD;       // 1 MD
    u16* ymid   = act + 26*MD;       // 1 MD
    u16* yfin   = act + 27*MD;       // 1 MD

    ln_kernel<<<dim3(392,4), 256, 0, stream>>>(e, (int)MD,
        (const u16*)nullptr, 0, (const float*)nullptr, 0,0,0,0,
        fp_ln_g, fp_ln_b, 0, ln4, (int)MD, 1.0f, 0, 256);
    gemm2_kernel<<<784, 256, 0, stream>>>(ln4, 256, (int)MD,
        fpWt, 256, 0,0,0,0, 0, fp_b, 0, allf, 1024, 256, 1, 4, 784);
    ln_kernel<<<dim3(392,1), 256, 0, stream>>>(allf, 0,
        (const u16*)nullptr, 0, (const float*)nullptr, 0,0,0,0,
        ff_ln_g, ff_ln_b, 0, ffln, 0, 1.0f, 0, 1024);
    gemm2_kernel<<<196, 256, 0, stream>>>(ffln, 1024, 0,
        ffWt, 1024, 0,0,0,0, 0, ff_b, 0, x2, 256, 0, 1, 4, 196);
    gemm2_kernel<<<588, 256, 0, stream>>>(x2, 256, 0,
        qkvWt, 256, 0,0,0,0, 0, mha_bqkv, 0, qkv, 768, 0, 0, 12, 588);
    vtrans_kernel<<<dim3(13,32), 256, 0, stream>>>(qkv, vtmha);
    attn_mha_kernel<<<224, 256, 0, stream>>>(qkv, vtmha, attn_o);
    gemm2_kernel<<<196, 256, 0, stream>>>(attn_o, 256, 0,
        WoWt, 256, 0,0,0,0, 0, mha_bo, 0, ymid, 256, 0, 0, 4, 196);
    ln_kernel<<<dim3(392,1), 256, 0, stream>>>(ymid, 0,
        (const u16*)nullptr, 0, (const float*)nullptr, 0,0,0,0,
        norm_g, norm_b, 0, yfin, 0, 1.0f, 0, 256);
    from_seq_kernel<<<dim3(49,16,4), dim3(16,16), 0, stream>>>(yfin, (float*)d_out);
}

// Round 17
// 314.816 us; speedup vs baseline: 1.5770x; 1.1628x over previous
//
#include <hip/hip_runtime.h>

typedef unsigned short u16;
typedef __bf16 bf16x8 __attribute__((ext_vector_type(8)));
typedef float f32x4 __attribute__((ext_vector_type(4)));
typedef float f32x16 __attribute__((ext_vector_type(16)));
typedef unsigned short u16x8 __attribute__((ext_vector_type(8)));
typedef unsigned short u16x4 __attribute__((ext_vector_type(4)));

static constexpr size_t MD = 802816;   // 3136*256 elements

__device__ __forceinline__ u16 f2bf(float f) {
    __bf16 h = (__bf16)f;
    return __builtin_bit_cast(unsigned short, h);
}
__device__ __forceinline__ float bf2f(u16 u) {
    return __uint_as_float(((unsigned)u) << 16);
}
__device__ __forceinline__ float gelu_f(float x) {
    return 0.5f * x * (1.0f + erff(x * 0.70710678118654752f));
}
__device__ __forceinline__ unsigned cvt_pk_bf16(float a, float b) {
    unsigned r;
    asm("v_cvt_pk_bf16_f32 %0, %1, %2" : "=v"(r) : "v"(a), "v"(b));
    return r;
}
// raw 2^x (v_exp_f32). NOTE: __builtin_amdgcn_exp2f is WRONG (R8/R9).
__device__ __forceinline__ float exp2_hw(float x) {
    float r;
    asm("v_exp_f32 %0, %1" : "=v"(r) : "v"(x));
    return r;
}
// bijective XCD swizzle (m204 form)
__device__ __forceinline__ int xcd_swz(int id, int nwg) {
    int q = nwg >> 3, r = nwg & 7;
    int xcd = id & 7, idx = id >> 3;
    return (xcd < r) ? (xcd * (q + 1) + idx) : (r * (q + 1) + (xcd - r) * q + idx);
}
union u8_4 { u16x8 v8; u16x4 v4[2]; };
union bf8_4 { bf16x8 f; u16x4 h[2]; u16x8 v8; };

// ------------- bf16 GEMM core, 64x64 tile, BK=64, swapped epilogue ----------
__device__ __forceinline__ void gemm_core(
    const u16* __restrict__ A, int lda,
    const u16* __restrict__ Bt, int K,
    const float* __restrict__ bias,
    u16* __restrict__ C, int ldc, int act, int m0, int n0,
    u16* __restrict__ VT)
{
    __shared__ u16 As[64][72];
    __shared__ u16 Bs[64][72];
    const int tid  = threadIdx.x;
    const int wave = tid >> 6, lane = tid & 63;
    const int wr = wave >> 1, wc = wave & 1;
    const int l16 = lane & 15, kg = lane >> 4, kb = kg * 8;
    const int srow = tid >> 2, scol = (tid & 3) * 16;

    f32x4 acc[2][2];
#pragma unroll
    for (int j = 0; j < 2; j++)
#pragma unroll
        for (int i = 0; i < 2; i++) { f32x4 z = {0.f,0.f,0.f,0.f}; acc[j][i] = z; }

    const u16* ap = A + (size_t)(m0 + srow) * lda + scol;
    const u16* bp = Bt + (size_t)(n0 + srow) * K + scol;
    u16x8 ua0 = *(const u16x8*)ap;
    u16x8 ua1 = *(const u16x8*)(ap + 8);
    u16x8 ub0 = *(const u16x8*)bp;
    u16x8 ub1 = *(const u16x8*)(bp + 8);

    for (int kt = 0; kt < K; kt += 64) {
        *(u16x8*)&As[srow][scol]     = ua0;
        *(u16x8*)&As[srow][scol + 8] = ua1;
        *(u16x8*)&Bs[srow][scol]     = ub0;
        *(u16x8*)&Bs[srow][scol + 8] = ub1;
        __syncthreads();
        if (kt + 64 < K) {
            ua0 = *(const u16x8*)(ap + kt + 64);
            ua1 = *(const u16x8*)(ap + kt + 72);
            ub0 = *(const u16x8*)(bp + kt + 64);
            ub1 = *(const u16x8*)(bp + kt + 72);
        }
#pragma unroll
        for (int h = 0; h < 2; h++) {
            bf16x8 af[2], bf[2];
#pragma unroll
            for (int j = 0; j < 2; j++)
                af[j] = *(const bf16x8*)&Bs[wc*32 + j*16 + l16][h*32 + kb];
#pragma unroll
            for (int i = 0; i < 2; i++)
                bf[i] = *(const bf16x8*)&As[wr*32 + i*16 + l16][h*32 + kb];
#pragma unroll
            for (int j = 0; j < 2; j++)
#pragma unroll
                for (int i = 0; i < 2; i++)
                    acc[j][i] = __builtin_amdgcn_mfma_f32_16x16x32_bf16(
                        af[j], bf[i], acc[j][i], 0,0,0);
        }
        __syncthreads();
    }
#pragma unroll
    for (int j = 0; j < 2; j++) {
        int lcol = wc*32 + j*16 + kg*4;
        f32x4 bv = *(const f32x4*)&bias[n0 + lcol];
#pragma unroll
        for (int i = 0; i < 2; i++) {
            int lrow = wr*32 + i*16 + l16;
            u16x4 o;
#pragma unroll
            for (int r = 0; r < 4; r++) {
                float v = acc[j][i][r] + bv[r];
                if (act == 1) v = gelu_f(v);
                o[r] = f2bf(v);
            }
            *(u16x4*)&As[lrow][lcol] = o;
        }
    }
    __syncthreads();
    if (VT && n0 >= 512) {
        int c = tid & 63, chunk = tid >> 6;
        int dg = n0 - 512 + c;
        int hh2 = dg >> 5, dd = dg & 31;
        int grow = m0 + chunk*16;
        int bb2 = grow / 784, kk0 = grow - bb2 * 784;
        u16x8 a, b;
#pragma unroll
        for (int j = 0; j < 8; j++) a[j] = As[chunk*16 + j][c];
#pragma unroll
        for (int j = 0; j < 8; j++) b[j] = As[chunk*16 + 8 + j][c];
        u16* vp = VT + ((size_t)(bb2*8 + hh2)*32 + dd)*784 + kk0;
        *(u16x8*)vp = a;
        *(u16x8*)(vp + 8) = b;
    } else {
        int crow = tid >> 2, cc = (tid & 3) * 16;
        u16x8 c0 = *(const u16x8*)&As[crow][cc];
        u16x8 c1 = *(const u16x8*)&As[crow][cc + 8];
        u16* cp = &C[(size_t)(m0 + crow) * ldc + n0 + cc];
        *(u16x8*)cp = c0;
        *(u16x8*)(cp + 8) = c1;
    }
}

// z-batched GEMM (64x64), 1D grid, XCD-swizzled; iz = (ipack>>(2z))&3
__global__ __launch_bounds__(256) void gemm2_kernel(
    const u16* __restrict__ A, int lda, int zA,
    const u16* __restrict__ Bt, int K, int ipack, int Bsz,
    const float* __restrict__ bias, int bN,
    u16* __restrict__ C, int ldc, int zC, int act, int nN, int nwg)
{
    int wg = xcd_swz(blockIdx.x, nwg);
    int n = wg % nN, rest = wg / nN;
    int m = rest % 49, z = rest / 49;
    int iz = (ipack >> (2*z)) & 3;
    gemm_core(A + (size_t)z * zA, lda,
              Bt + (size_t)iz * Bsz, K,
              bias + (size_t)iz * bN,
              C + (size_t)z * zC, ldc, act, m * 64, n * 64, nullptr);
}

// projections: z = inv*2 + ab; Q|K -> projqk[z] (ld 512), V -> vt[z^1]
__global__ __launch_bounds__(256) void proj_kernel(
    const u16* __restrict__ s, int apack, int bpack, int ipack,
    const u16* __restrict__ projWt, const float* __restrict__ biasc,
    u16* __restrict__ projqk, u16* __restrict__ vt, int nwg)
{
    int wg = xcd_swz(blockIdx.x, nwg);
    int n = wg % 12, rest = wg / 12;
    int m = rest % 49, z = rest / 49;
    int inv = z >> 1, ab = z & 1;
    int ai = (apack >> (2*inv)) & 3;
    int bi = (bpack >> (2*inv)) & 3;
    int ii = (ipack >> (2*inv)) & 3;
    const u16* Aact = s + (size_t)(ab ? bi : ai) * MD;
    int widx = ii * 2 + ab;
    gemm_core(Aact, 256, projWt + (size_t)widx * 768 * 256, 256,
              biasc + widx * 768,
              projqk + (size_t)z * 2 * MD, 512, 0, m * 64, n * 64,
              vt + (size_t)(z ^ 1) * MD);
}

__global__ __launch_bounds__(256) void pack_bias_kernel(
    const float* b0, const float* b1, const float* b2,
    const float* b3, const float* b4, const float* b5,
    float* __restrict__ biasc)
{
    int z = blockIdx.x;
    int tsr = z >> 2, i = z & 3;
    const float* barr[6] = {b0,b1,b2,b3,b4,b5};
    int ab = (tsr >= 3) ? 1 : 0;
    biasc[(i*2 + ab)*768 + (tsr % 3)*256 + threadIdx.x] = barr[tsr][i*256 + threadIdx.x];
}

// ---------------- flash attention core, 32x32x16 MFMA, 32 q-rows/wave -------
__device__ __forceinline__ void attn3_core(
    const u16* __restrict__ Qg, int ldq,
    const u16* __restrict__ Kg, int ldk,
    const u16* __restrict__ Vtg,
    u16* __restrict__ Og, int ldo,
    int qt, int rowbase, int qkcol, int ocol)
{
    __shared__ u16 Ks[2][64][36];
    __shared__ u16 Vts[2][32][68];
    __shared__ u16 Ps[4][32][68];
    __shared__ float Ls[4][32];

    const int tid = threadIdx.x, wave = tid >> 6, lane = tid & 63;
    const int l32 = lane & 31, hi = lane >> 5;
    const int sr = tid >> 2, sc8 = (tid & 3) * 8;
    const int vd = tid >> 3, vk8 = (tid & 7) * 8;
    const float QSC = 0.25503489f;        // 32^-0.5 * log2(e)

    bf8_4 qf0, qf1;
    {
        int qrow = qt*128 + wave*32 + l32;
        u16x8 z8 = {0,0,0,0,0,0,0,0};
        u16x8 q0 = z8, q1 = z8;
        if (qrow < 784) {
            const u16* qp = Qg + (size_t)(rowbase + qrow) * ldq + qkcol;
            q0 = *(const u16x8*)(qp + hi*8);
            q1 = *(const u16x8*)(qp + 16 + hi*8);
        }
#pragma unroll
        for (int j = 0; j < 8; j++) {
            q0[j] = f2bf(bf2f(q0[j]) * QSC);
            q1[j] = f2bf(bf2f(q1[j]) * QSC);
        }
        qf0.v8 = q0;
        qf1.v8 = q1;
    }
    {
        u8_4 k, v;
        k.v8 = *(const u16x8*)(Kg + (size_t)(rowbase + sr) * ldk + qkcol + sc8);
        v.v8 = *(const u16x8*)(Vtg + (size_t)vd * 784 + vk8);
        *(u16x4*)&Ks[0][sr][sc8]     = k.v4[0];
        *(u16x4*)&Ks[0][sr][sc8 + 4] = k.v4[1];
        *(u16x4*)&Vts[0][vd][vk8]     = v.v4[0];
        *(u16x4*)&Vts[0][vd][vk8 + 4] = v.v4[1];
    }
    __syncthreads();

    f32x16 oacc;
#pragma unroll
    for (int i = 0; i < 16; i++) oacc[i] = 0.f;
    float lsum = 0.f;

    u16x8 kr, vr;
    for (int t = 0; t < 13; ++t) {
        const int cur = t & 1;
        if (t < 12) {
            u16x8 z8 = {0,0,0,0,0,0,0,0}; kr = z8; vr = z8;
            int krow = (t+1)*64 + sr;
            if (krow < 784)
                kr = *(const u16x8*)(Kg + (size_t)(rowbase + krow) * ldk + qkcol + sc8);
            int kc = (t+1)*64 + vk8;
            if (kc + 7 < 784)
                vr = *(const u16x8*)(Vtg + (size_t)vd * 784 + kc);
        }
        const int kvalid = (t == 12) ? 16 : 64;
#pragma unroll
        for (int kb2 = 0; kb2 < 2; kb2++) {
            f32x16 sacc;
#pragma unroll
            for (int i = 0; i < 16; i++) sacc[i] = 0.f;
            bf8_4 kf0, kf1;
            kf0.h[0] = *(const u16x4*)&Ks[cur][kb2*32 + l32][hi*8];
            kf0.h[1] = *(const u16x4*)&Ks[cur][kb2*32 + l32][hi*8 + 4];
            kf1.h[0] = *(const u16x4*)&Ks[cur][kb2*32 + l32][16 + hi*8];
            kf1.h[1] = *(const u16x4*)&Ks[cur][kb2*32 + l32][16 + hi*8 + 4];
            sacc = __builtin_amdgcn_mfma_f32_32x32x16_bf16(kf0.f, qf0.f, sacc, 0,0,0);
            sacc = __builtin_amdgcn_mfma_f32_32x32x16_bf16(kf1.f, qf1.f, sacc, 0,0,0);
#pragma unroll
            for (int g = 0; g < 4; g++) {
                int k0 = kb2*32 + 8*g + 4*hi;
                union { unsigned u[2]; u16x4 v; } pk;
                if (k0 < kvalid) {
                    float p0 = exp2_hw(sacc[4*g+0]);
                    float p1 = exp2_hw(sacc[4*g+1]);
                    float p2 = exp2_hw(sacc[4*g+2]);
                    float p3 = exp2_hw(sacc[4*g+3]);
                    lsum += (p0 + p1) + (p2 + p3);
                    pk.u[0] = cvt_pk_bf16(p0, p1);
                    pk.u[1] = cvt_pk_bf16(p2, p3);
                } else { pk.u[0] = 0; pk.u[1] = 0; }
                *(u16x4*)&Ps[wave][l32][k0] = pk.v;
            }
        }
#pragma unroll
        for (int kf2 = 0; kf2 < 4; kf2++) {
            bf8_4 pf, vf;
            pf.h[0] = *(const u16x4*)&Ps[wave][l32][kf2*16 + hi*8];
            pf.h[1] = *(const u16x4*)&Ps[wave][l32][kf2*16 + hi*8 + 4];
            vf.h[0] = *(const u16x4*)&Vts[cur][l32][kf2*16 + hi*8];
            vf.h[1] = *(const u16x4*)&Vts[cur][l32][kf2*16 + hi*8 + 4];
            oacc = __builtin_amdgcn_mfma_f32_32x32x16_bf16(pf.f, vf.f, oacc, 0,0,0);
        }
        if (t < 12) {
            u8_4 k, v; k.v8 = kr; v.v8 = vr;
            *(u16x4*)&Ks[cur^1][sr][sc8]     = k.v4[0];
            *(u16x4*)&Ks[cur^1][sr][sc8 + 4] = k.v4[1];
            *(u16x4*)&Vts[cur^1][vd][vk8]     = v.v4[0];
            *(u16x4*)&Vts[cur^1][vd][vk8 + 4] = v.v4[1];
            __syncthreads();
        }
    }
    float lt = lsum + __shfl_xor(lsum, 32);
    if (hi == 0) Ls[wave][l32] = lt;
    f32x4 lv[4];
#pragma unroll
    for (int g = 0; g < 4; g++) lv[g] = *(const f32x4*)&Ls[wave][8*g + 4*hi];
#pragma unroll
    for (int g = 0; g < 4; g++)
#pragma unroll
        for (int j = 0; j < 4; j++) {
            int row = qt*128 + wave*32 + 8*g + 4*hi + j;
            if (row < 784)
                Og[(size_t)(rowbase + row) * ldo + ocol + l32] =
                    f2bf(oacc[4*g+j] * __builtin_amdgcn_rcpf(lv[g][j]));
        }
}

// attention over nz sides: grid = 224*nz; z = inv*2 + dir
__global__ __launch_bounds__(256) void attn_pair_kernel(
    const u16* __restrict__ projqk, const u16* __restrict__ vt,
    u16* __restrict__ fin)
{
    int id = blockIdx.x;
    int nper = gridDim.x >> 3;
    int wg = (id & 7) * nper + (id >> 3);
    int qt = wg % 7, bh = (wg / 7) & 31, z = wg / 224;
    int inv = z >> 1, dir = z & 1;
    const u16* Q  = projqk + (size_t)z * 2 * MD;
    const u16* K  = projqk + (size_t)(z ^ 1) * 2 * MD + 256;
    const u16* Vt = vt + (size_t)z * MD + (size_t)bh * 32 * 784;
    u16* O = fin + (size_t)inv * 2 * MD;
    int bb = bh >> 3, hh = bh & 7;
    attn3_core(Q, 512, K, 512, Vt, O, 512, qt, bb*784, hh*32, dir*256 + hh*32);
}

__global__ __launch_bounds__(256) void attn_mha_kernel(
    const u16* __restrict__ qkv, const u16* __restrict__ vtmha,
    u16* __restrict__ outp)
{
    int id = blockIdx.x;
    int wg = (id & 7) * 28 + (id >> 3);       // 224/8 = 28
    int qt = wg % 7, bh = wg / 7;
    int bb = bh >> 3, hh = bh & 7;
    const u16* Vt = vtmha + (size_t)bh * 32 * 784;
    attn3_core(qkv, 768, qkv + 256, 768, Vt, outp, 256, qt, bb*784, hh*32, hh*32);
}

// ---------------- LayerNorm: out = os*LN(res + tg*x) -----------------------
// res slot per z via respack (res += slot*MD); gamma/g/beta idx via gpack
__global__ __launch_bounds__(256) void ln_kernel(
    const u16* __restrict__ x, size_t zx,
    const u16* __restrict__ res, size_t zres, int respack,
    const float* __restrict__ gamma, int gpack,
    const float* __restrict__ g, const float* __restrict__ beta, int gN,
    u16* __restrict__ out, size_t zout,
    float outscale, int D)
{
    int z = blockIdx.y;
    int gi = (gpack >> (2*z)) & 3;
    const u16* xb = x + (size_t)z * zx;
    const u16* rb = res ? res + (size_t)z * zres + (size_t)((respack >> (2*z)) & 3) * MD
                        : (const u16*)nullptr;
    u16* ob = out + (size_t)z * zout;
    const float* gg = g + gi * gN;
    const float* bb = beta + gi * gN;
    int wave = threadIdx.x >> 6, lane = threadIdx.x & 63;
    int half = lane >> 5, l32 = lane & 31;
    size_t row = (size_t)blockIdx.x * 8 + wave * 2 + half;
    float tg = gamma ? tanhf(gamma[gi]) : 1.0f;
    const u16* xr = xb + row * D;
    const u16* rr = rb ? rb + row * D : (const u16*)nullptr;
    float vals[32];
    int nch = D >> 8;
    float s = 0.f, s2 = 0.f;
    for (int c = 0; c < nch; c++) {
        int col = c * 256 + l32 * 8;
        u16x8 v = *(const u16x8*)(xr + col);
        u16x8 r8 = {0,0,0,0,0,0,0,0};
        if (rr) r8 = *(const u16x8*)(rr + col);
#pragma unroll
        for (int j = 0; j < 8; j++) {
            float a = tg * bf2f(v[j]) + bf2f(r8[j]);
            vals[c*8 + j] = a;
            s += a; s2 += a * a;
        }
    }
#pragma unroll
    for (int off = 1; off < 32; off <<= 1) {
        s  += __shfl_xor(s, off);
        s2 += __shfl_xor(s2, off);
    }
    float inv = 1.0f / D;
    float mean = s * inv;
    float var = s2 * inv - mean * mean;
    float rstd = rsqrtf(var + 1e-5f);
    for (int c = 0; c < nch; c++) {
        int col = c * 256 + l32 * 8;
        u16x8 o8;
#pragma unroll
        for (int j = 0; j < 8; j++) {
            float o = (vals[c*8 + j] - mean) * rstd * gg[col + j] + bb[col + j];
            o8[j] = f2bf(o * outscale);
        }
        *(u16x8*)(ob + row*D + col) = o8;
    }
}

// ---------------- layout kernels --------------------------------------------
__device__ __forceinline__ void transpose_body(const float* in, u16* out,
                                               int K, int N, int bx, int by)
{
    __shared__ float t[32][33];
    int tx = threadIdx.x, ty = threadIdx.y;   // (32,8)
#pragma unroll
    for (int j = 0; j < 4; j++)
        t[ty + j*8][tx] = in[(size_t)(by*32 + ty + j*8) * N + bx*32 + tx];
    __syncthreads();
#pragma unroll
    for (int j = 0; j < 4; j++)
        out[(size_t)(bx*32 + ty + j*8) * K + by*32 + tx] =
            f2bf(t[tx][ty + j*8]);
}

struct TDesc { const float* in; u16* out; int K, N, start, bpz; };
struct TPack7 { TDesc d[7]; };

// merged weight transposes: 3136 blocks, 7 descriptors
__global__ __launch_bounds__(256) void tmerge_kernel(TPack7 p)
{
    int bid = blockIdx.x;
    int di = 0;
#pragma unroll
    for (int i = 1; i < 7; i++) if (bid >= p.d[i].start) di = i;
    TDesc d = p.d[di];
    int local = bid - d.start;
    int zz = local / d.bpz, rem = local - zz * d.bpz;
    int nbx = d.N >> 5;
    int bx = rem % nbx, by = rem / nbx;
    transpose_body(d.in + (size_t)zz * d.K * d.N,
                   d.out + (size_t)zz * d.K * d.N, d.K, d.N, bx, by);
}

// proj weights into cat layout: [i][ab][768 n][256 k]
__global__ __launch_bounds__(256) void transpose_w6(
    const float* w0, const float* w1, const float* w2,
    const float* w3, const float* w4, const float* w5,
    u16* __restrict__ out)
{
    int z = blockIdx.z;           // 0..23: tsr = z/4, i = z%4
    int tsr = z >> 2, i = z & 3;
    const float* ws[6] = {w0,w1,w2,w3,w4,w5};
    int ab = (tsr >= 3) ? 1 : 0;
    u16* ob = out + (size_t)((i*2 + ab)*3 + (tsr % 3)) * 65536;
    transpose_body(ws[tsr] + (size_t)i * 65536, ob, 256, 256,
                   blockIdx.x, blockIdx.y);
}

// transpose V (cols 512..767 of 768-wide qkv) -> [bh*32+d][784]
__global__ __launch_bounds__(256) void vtrans_kernel(
    const u16* __restrict__ base,
    u16* __restrict__ out)
{
    __shared__ u16 t[64][44];
    const u16* in = base + 512;
    int kt = blockIdx.x, bh = blockIdx.y;
    int bb = bh >> 3, hh = bh & 7;
    int tid = threadIdx.x;
    {
        int r = tid >> 2, c8 = (tid & 3) * 8;
        int krow = kt*64 + r;
        u16x8 u = {0,0,0,0,0,0,0,0};
        if (krow < 784)
            u = *(const u16x8*)(in + (size_t)(bb*784 + krow) * 768 + hh*32 + c8);
        *(u16x8*)&t[r][c8] = u;
    }
    __syncthreads();
    int d = tid >> 3, k8 = (tid & 7) * 8;
    if (kt*64 + k8 + 7 < 784) {
        u16x8 u;
#pragma unroll
        for (int j = 0; j < 8; j++) u[j] = t[k8 + j][d];
        *(u16x8*)&out[(size_t)(bh*32 + d) * 784 + kt*64 + k8] = u;
    }
}

// f[B,256,28,28] fp32 -> s[fi][b*784+hw][d] bf16
__global__ __launch_bounds__(256) void to_seq_kernel(
    const float* f0, const float* f1, const float* f2, const float* f3,
    u16* __restrict__ sbase)
{
    __shared__ float t[16][17];
    int z = blockIdx.z;
    int fi = z & 3, b = z >> 2;
    const float* fs[4] = {f0,f1,f2,f3};
    const float* f = fs[fi] + (size_t)b * 256 * 784;
    u16* s = sbase + (size_t)fi * MD + (size_t)b * 784 * 256;
    int tx = threadIdx.x, ty = threadIdx.y;  // (16,16)
    t[ty][tx] = f[(size_t)(blockIdx.y*16 + ty) * 784 + blockIdx.x*16 + tx];
    __syncthreads();
    s[(size_t)(blockIdx.x*16 + ty) * 256 + blockIdx.y*16 + tx] = f2bf(t[tx][ty]);
}

// y[b*784+hw][d] bf16 -> out[b][d][h][w] fp32
__global__ __launch_bounds__(256) void from_seq_kernel(const u16* __restrict__ y,
                                                       float* __restrict__ out)
{
    __shared__ float t[16][17];
    int b = blockIdx.z;
    const u16* yb = y + (size_t)b * 784 * 256;
    float* ob = out + (size_t)b * 256 * 784;
    int tx = threadIdx.x, ty = threadIdx.y;
    t[ty][tx] = bf2f(yb[(size_t)(blockIdx.x*16 + ty) * 256 + blockIdx.y*16 + tx]);
    __syncthreads();
    ob[(size_t)(blockIdx.y*16 + ty) * 784 + blockIdx.x*16 + tx] = t[tx][ty];
}

// ---------------- host orchestration ----------------------------------------
extern "C" void kernel_launch(void* const* d_in, const int* in_sizes, int n_in,
                              void* d_out, int out_size, void* d_ws, size_t ws_size,
                              hipStream_t stream)
{
    (void)in_sizes; (void)n_in; (void)out_size;
    const float* f0 = (const float*)d_in[0];
    const float* f1 = (const float*)d_in[1];
    const float* f2 = (const float*)d_in[2];
    const float* f3 = (const float*)d_in[3];
    const float* Wq_a = (const float*)d_in[4];
    const float* Wk_a = (const float*)d_in[5];
    const float* Wv_a = (const float*)d_in[6];
    const float* Wq_b = (const float*)d_in[7];
    const float* Wk_b = (const float*)d_in[8];
    const float* Wv_b = (const float*)d_in[9];
    const float* bq_a = (const float*)d_in[10];
    const float* bk_a = (const float*)d_in[11];
    const float* bv_a = (const float*)d_in[12];
    const float* bq_b = (const float*)d_in[13];
    const float* bk_b = (const float*)d_in[14];
    const float* bv_b = (const float*)d_in[15];
    const float* gamma = (const float*)d_in[16];
    const float* gamma_ffn = (const float*)d_in[17];
    const float* Wfuse = (const float*)d_in[18];
    const float* bfuse = (const float*)d_in[19];
    const float* W1 = (const float*)d_in[20];
    const float* b1 = (const float*)d_in[21];
    const float* W2 = (const float*)d_in[22];
    const float* b2 = (const float*)d_in[23];
    const float* ln1_g = (const float*)d_in[24];
    const float* ln1_b = (const float*)d_in[25];
    const float* ln2_g = (const float*)d_in[26];
    const float* ln2_b = (const float*)d_in[27];
    const float* fp_ln_g = (const float*)d_in[28];
    const float* fp_ln_b = (const float*)d_in[29];
    const float* fp_W = (const float*)d_in[30];
    const float* fp_b = (const float*)d_in[31];
    const float* ff_ln_g = (const float*)d_in[32];
    const float* ff_ln_b = (const float*)d_in[33];
    const float* ff_W = (const float*)d_in[34];
    const float* ff_b = (const float*)d_in[35];
    const float* mha_Wqkv = (const float*)d_in[36];
    const float* mha_bqkv = (const float*)d_in[37];
    const float* mha_Wo = (const float*)d_in[38];
    const float* mha_bo = (const float*)d_in[39];
    const float* norm_g = (const float*)d_in[40];
    const float* norm_b = (const float*)d_in[41];

    u16* W = (u16*)d_ws;
    u16* projWt = W;                          // 1572864
    u16* fuseWt = projWt + 1572864;           // 524288
    u16* W1t    = fuseWt + 524288;            // 1048576
    u16* W2t    = W1t + 1048576;              // 1048576
    u16* fpWt   = W2t + 1048576;              // 65536
    u16* ffWt   = fpWt + 65536;               // 262144
    u16* qkvWt  = ffWt + 262144;              // 196608
    u16* WoWt   = qkvWt + 196608;             // 65536
    float* biasc = (float*)(WoWt + 65536);    // 6144 floats
    u16* act    = (u16*)(biasc + 6144);

    u16* s    = act;                 // 4 MD
    u16* e8   = act + 4*MD;          // 8 MD
    u16* main_ = act + 12*MD;        // projqk | vt | fin

    const size_t actbytes_merged = (size_t)2 * 76 * MD;
    const size_t weights_bytes = (size_t)((char*)act - (char*)d_ws);
    const bool merged = ws_size >= weights_bytes + actbytes_merged;

    // prologue
    to_seq_kernel<<<dim3(49,16,16), dim3(16,16), 0, stream>>>(f0,f1,f2,f3, s);
    transpose_w6<<<dim3(8,8,24), dim3(32,8), 0, stream>>>(Wq_a,Wk_a,Wv_a,Wq_b,Wk_b,Wv_b, projWt);
    pack_bias_kernel<<<24, 256, 0, stream>>>(bq_a,bk_a,bv_a,bq_b,bk_b,bv_b, biasc);
    {
        TPack7 tp;
        tp.d[0] = { Wfuse,    fuseWt, 512, 256,    0, 128 };  // 4z*128 = 512
        tp.d[1] = { W1,       W1t,    256, 1024, 512, 256 };  // 4z*256 = 1024
        tp.d[2] = { W2,       W2t,   1024, 256, 1536, 256 };  // 4z*256 = 1024
        tp.d[3] = { fp_W,     fpWt,   256, 256, 2560,  64 };
        tp.d[4] = { ff_W,     ffWt,  1024, 256, 2624, 256 };
        tp.d[5] = { mha_Wqkv, qkvWt,  256, 768, 2880, 192 };
        tp.d[6] = { mha_Wo,   WoWt,   256, 256, 3072,  64 };
        tmerge_kernel<<<3136, dim3(32,8), 0, stream>>>(tp);
    }

    // 8 invocations: bi -> (i, a, b):
    const int IA[8] = {0,1,0,2,2,3,1,3};
    const int AA[8] = {0,0,1,1,2,2,3,3};
    const int BB[8] = {1,3,0,2,1,3,0,2};

    if (merged) {
        u16* projqk = main_;            // 32 MD
        u16* vt  = main_ + 32*MD;       // 16 MD
        u16* fin = main_ + 48*MD;       // 16 MD
        u16* ffh = projqk;              // 32 MD overlay
        u16* fb  = vt;                  // 8 MD overlay
        u16* xa1 = vt + 8*MD;           // 8 MD overlay
        u16* ffb = fin;                 // 8 MD overlay
        int ip = 0, apk = 0, bpk = 0;
        for (int j = 0; j < 8; j++) {
            ip  |= IA[j] << (2*j);
            apk |= AA[j] << (2*j);
            bpk |= BB[j] << (2*j);
        }
        proj_kernel<<<9408, 256, 0, stream>>>(s, apk, bpk, ip,
            projWt, biasc, projqk, vt, 9408);
        attn_pair_kernel<<<3584, 256, 0, stream>>>(projqk, vt, fin);
        gemm2_kernel<<<1568, 256, 0, stream>>>(fin, 512, (int)(2*MD),
            fuseWt, 512, ip, 131072, bfuse, 256, fb, 256, (int)MD, 0, 4, 1568);
        ln_kernel<<<dim3(392,8), 256, 0, stream>>>(fb, MD,
            s, 0, apk, gamma, ip, ln1_g, ln1_b, 256, xa1, MD, 1.0f, 256);
        gemm2_kernel<<<6272, 256, 0, stream>>>(xa1, 256, (int)MD,
            W1t, 256, ip, 262144, b1, 1024, ffh, 1024, (int)(4*MD), 1, 16, 6272);
        gemm2_kernel<<<1568, 256, 0, stream>>>(ffh, 1024, (int)(4*MD),
            W2t, 1024, ip, 262144, b2, 256, ffb, 256, (int)MD, 0, 4, 1568);
        ln_kernel<<<dim3(392,8), 256, 0, stream>>>(ffb, MD,
            xa1, MD, 0, gamma_ffn, ip, ln2_g, ln2_b, 256, e8, MD, 0.5f, 256);
    } else {
        u16* projqk = main_;            // 16 MD
        u16* vt  = main_ + 16*MD;       // 8 MD
        u16* fin = main_ + 24*MD;       // 8 MD
        u16* ffh = projqk;              // 16 MD overlay
        u16* fb  = vt;                  // 4 MD overlay
        u16* xa1 = vt + 4*MD;           // 4 MD overlay
        u16* ffb = fin;                 // 4 MD overlay
        for (int g = 0; g < 2; g++) {
            int ip = 0, apk = 0, bpk = 0;
            for (int j = 0; j < 4; j++) {
                int bi = 2*j + g;
                ip  |= IA[bi] << (2*j);
                apk |= AA[bi] << (2*j);
                bpk |= BB[bi] << (2*j);
            }
            proj_kernel<<<4704, 256, 0, stream>>>(s, apk, bpk, ip,
                projWt, biasc, projqk, vt, 4704);
            attn_pair_kernel<<<1792, 256, 0, stream>>>(projqk, vt, fin);
            gemm2_kernel<<<784, 256, 0, stream>>>(fin, 512, (int)(2*MD),
                fuseWt, 512, ip, 131072, bfuse, 256, fb, 256, (int)MD, 0, 4, 784);
            ln_kernel<<<dim3(392,4), 256, 0, stream>>>(fb, MD,
                s, 0, apk, gamma, ip, ln1_g, ln1_b, 256, xa1, MD, 1.0f, 256);
            gemm2_kernel<<<3136, 256, 0, stream>>>(xa1, 256, (int)MD,
                W1t, 256, ip, 262144, b1, 1024, ffh, 1024, (int)(4*MD), 1, 16, 3136);
            gemm2_kernel<<<784, 256, 0, stream>>>(ffh, 1024, (int)(4*MD),
                W2t, 1024, ip, 262144, b2, 256, ffb, 256, (int)MD, 0, 4, 784);
            ln_kernel<<<dim3(392,4), 256, 0, stream>>>(ffb, MD,
                xa1, MD, 0, gamma_ffn, ip, ln2_g, ln2_b, 256,
                e8 + (size_t)g*MD, 2*MD, 0.5f, 256);
        }
    }

    // final fuse stage (region main_; e8 live until ln4 done)
    u16* ln4    = main_;             // 4 MD
    u16* allf   = main_ + 4*MD;      // 4 MD  [3136][1024]
    u16* ffln   = main_ + 8*MD;      // 4 MD
    u16* x2     = main_ + 12*MD;     // 1 MD
    u16* qkv    = main_ + 13*MD;     // 3 MD  [3136][768]
    u16* vtmha  = main_ + 16*MD;     // 1 MD
    u16* attn_o = main_ + 17*MD;     // 1 MD
    u16* ymid   = main_ + 18*MD;     // 1 MD
    u16* yfin   = main_ + 19*MD;     // 1 MD

    // e_t = e8[2t] + e8[2t+1] (each already 0.5*LN-out); then fp LN+gelu proj
    ln_kernel<<<dim3(392,4), 256, 0, stream>>>(e8, 2*MD,
        e8 + MD, 2*MD, 0, (const float*)nullptr, 0,
        fp_ln_g, fp_ln_b, 0, ln4, MD, 1.0f, 256);
    gemm2_kernel<<<784, 256, 0, stream>>>(ln4, 256, (int)MD,
        fpWt, 256, 0, 0, fp_b, 0, allf, 1024, 256, 1, 4, 784);
    ln_kernel<<<dim3(392,1), 256, 0, stream>>>(allf, 0,
        (const u16*)nullptr, 0, 0, (const float*)nullptr, 0,
        ff_ln_g, ff_ln_b, 0, ffln, 0, 1.0f, 1024);
    gemm2_kernel<<<196, 256, 0, stream>>>(ffln, 1024, 0,
        ffWt, 1024, 0, 0, ff_b, 0, x2, 256, 0, 1, 4, 196);
    gemm2_kernel<<<588, 256, 0, stream>>>(x2, 256, 0,
        qkvWt, 256, 0, 0, mha_bqkv, 0, qkv, 768, 0, 0, 12, 588);
    vtrans_kernel<<<dim3(13,32), 256, 0, stream>>>(qkv, vtmha);
    attn_mha_kernel<<<224, 256, 0, stream>>>(qkv, vtmha, attn_o);
    gemm2_kernel<<<196, 256, 0, stream>>>(attn_o, 256, 0,
        WoWt, 256, 0, 0, mha_bo, 0, ymid, 256, 0, 0, 4, 196);
    ln_kernel<<<dim3(392,1), 256, 0, stream>>>(ymid, 0,
        (const u16*)nullptr, 0, 0, (const float*)nullptr, 0,
        norm_g, norm_b, 0, yfin, 0, 1.0f, 256);
    from_seq_kernel<<<dim3(49,16,4), dim3(16,16), 0, stream>>>(yfin, (float*)d_out);
}

// Round 18
// 306.208 us; speedup vs baseline: 1.6213x; 1.0281x over previous
//
#include <hip/hip_runtime.h>

typedef unsigned short u16;
typedef __bf16 bf16x8 __attribute__((ext_vector_type(8)));
typedef float f32x4 __attribute__((ext_vector_type(4)));
typedef float f32x16 __attribute__((ext_vector_type(16)));
typedef unsigned short u16x8 __attribute__((ext_vector_type(8)));
typedef unsigned short u16x4 __attribute__((ext_vector_type(4)));

static constexpr size_t MD = 802816;   // 3136*256 elements

__device__ __forceinline__ u16 f2bf(float f) {
    __bf16 h = (__bf16)f;
    return __builtin_bit_cast(unsigned short, h);
}
__device__ __forceinline__ float bf2f(u16 u) {
    return __uint_as_float(((unsigned)u) << 16);
}
__device__ __forceinline__ float gelu_f(float x) {
    return 0.5f * x * (1.0f + erff(x * 0.70710678118654752f));
}
__device__ __forceinline__ unsigned cvt_pk_bf16(float a, float b) {
    unsigned r;
    asm("v_cvt_pk_bf16_f32 %0, %1, %2" : "=v"(r) : "v"(a), "v"(b));
    return r;
}
// raw 2^x (v_exp_f32). NOTE: __builtin_amdgcn_exp2f is WRONG (R8/R9).
__device__ __forceinline__ float exp2_hw(float x) {
    float r;
    asm("v_exp_f32 %0, %1" : "=v"(r) : "v"(x));
    return r;
}
// bijective XCD swizzle (m204 form)
__device__ __forceinline__ int xcd_swz(int id, int nwg) {
    int q = nwg >> 3, r = nwg & 7;
    int xcd = id & 7, idx = id >> 3;
    return (xcd < r) ? (xcd * (q + 1) + idx) : (r * (q + 1) + (xcd - r) * q + idx);
}
union u8_4 { u16x8 v8; u16x4 v4[2]; };
union bf8_4 { bf16x8 f; u16x4 h[2]; u16x8 v8; };

// ------------- bf16 GEMM core, 64x64 tile, BK=64, swapped epilogue ----------
__device__ __forceinline__ void gemm_core(
    const u16* __restrict__ A, int lda,
    const u16* __restrict__ Bt, int K,
    const float* __restrict__ bias,
    u16* __restrict__ C, int ldc, int act, int m0, int n0,
    u16* __restrict__ VT)
{
    __shared__ u16 As[64][72];
    __shared__ u16 Bs[64][72];
    const int tid  = threadIdx.x;
    const int wave = tid >> 6, lane = tid & 63;
    const int wr = wave >> 1, wc = wave & 1;
    const int l16 = lane & 15, kg = lane >> 4, kb = kg * 8;
    const int srow = tid >> 2, scol = (tid & 3) * 16;

    f32x4 acc[2][2];
#pragma unroll
    for (int j = 0; j < 2; j++)
#pragma unroll
        for (int i = 0; i < 2; i++) { f32x4 z = {0.f,0.f,0.f,0.f}; acc[j][i] = z; }

    const u16* ap = A + (size_t)(m0 + srow) * lda + scol;
    const u16* bp = Bt + (size_t)(n0 + srow) * K + scol;
    u16x8 ua0 = *(const u16x8*)ap;
    u16x8 ua1 = *(const u16x8*)(ap + 8);
    u16x8 ub0 = *(const u16x8*)bp;
    u16x8 ub1 = *(const u16x8*)(bp + 8);

    for (int kt = 0; kt < K; kt += 64) {
        *(u16x8*)&As[srow][scol]     = ua0;
        *(u16x8*)&As[srow][scol + 8] = ua1;
        *(u16x8*)&Bs[srow][scol]     = ub0;
        *(u16x8*)&Bs[srow][scol + 8] = ub1;
        __syncthreads();
        if (kt + 64 < K) {
            ua0 = *(const u16x8*)(ap + kt + 64);
            ua1 = *(const u16x8*)(ap + kt + 72);
            ub0 = *(const u16x8*)(bp + kt + 64);
            ub1 = *(const u16x8*)(bp + kt + 72);
        }
#pragma unroll
        for (int h = 0; h < 2; h++) {
            bf16x8 af[2], bf[2];
#pragma unroll
            for (int j = 0; j < 2; j++)
                af[j] = *(const bf16x8*)&Bs[wc*32 + j*16 + l16][h*32 + kb];
#pragma unroll
            for (int i = 0; i < 2; i++)
                bf[i] = *(const bf16x8*)&As[wr*32 + i*16 + l16][h*32 + kb];
#pragma unroll
            for (int j = 0; j < 2; j++)
#pragma unroll
                for (int i = 0; i < 2; i++)
                    acc[j][i] = __builtin_amdgcn_mfma_f32_16x16x32_bf16(
                        af[j], bf[i], acc[j][i], 0,0,0);
        }
        __syncthreads();
    }
#pragma unroll
    for (int j = 0; j < 2; j++) {
        int lcol = wc*32 + j*16 + kg*4;
        f32x4 bv = *(const f32x4*)&bias[n0 + lcol];
#pragma unroll
        for (int i = 0; i < 2; i++) {
            int lrow = wr*32 + i*16 + l16;
            u16x4 o;
#pragma unroll
            for (int r = 0; r < 4; r++) {
                float v = acc[j][i][r] + bv[r];
                if (act == 1) v = gelu_f(v);
                o[r] = f2bf(v);
            }
            *(u16x4*)&As[lrow][lcol] = o;
        }
    }
    __syncthreads();
    if (VT && n0 >= 512) {
        int c = tid & 63, chunk = tid >> 6;
        int dg = n0 - 512 + c;
        int hh2 = dg >> 5, dd = dg & 31;
        int grow = m0 + chunk*16;
        int bb2 = grow / 784, kk0 = grow - bb2 * 784;
        u16x8 a, b;
#pragma unroll
        for (int j = 0; j < 8; j++) a[j] = As[chunk*16 + j][c];
#pragma unroll
        for (int j = 0; j < 8; j++) b[j] = As[chunk*16 + 8 + j][c];
        u16* vp = VT + ((size_t)(bb2*8 + hh2)*32 + dd)*784 + kk0;
        *(u16x8*)vp = a;
        *(u16x8*)(vp + 8) = b;
    } else {
        int crow = tid >> 2, cc = (tid & 3) * 16;
        u16x8 c0 = *(const u16x8*)&As[crow][cc];
        u16x8 c1 = *(const u16x8*)&As[crow][cc + 8];
        u16* cp = &C[(size_t)(m0 + crow) * ldc + n0 + cc];
        *(u16x8*)cp = c0;
        *(u16x8*)(cp + 8) = c1;
    }
}

// z-batched GEMM (64x64), 1D grid, XCD-swizzled; iz = (ipack>>(2z))&3
__global__ __launch_bounds__(256) void gemm2_kernel(
    const u16* __restrict__ A, int lda, int zA,
    const u16* __restrict__ Bt, int K, int ipack, int Bsz,
    const float* __restrict__ bias, int bN,
    u16* __restrict__ C, int ldc, int zC, int act, int nN, int nwg)
{
    int wg = xcd_swz(blockIdx.x, nwg);
    int n = wg % nN, rest = wg / nN;
    int m = rest % 49, z = rest / 49;
    int iz = (ipack >> (2*z)) & 3;
    gemm_core(A + (size_t)z * zA, lda,
              Bt + (size_t)iz * Bsz, K,
              bias + (size_t)iz * bN,
              C + (size_t)z * zC, ldc, act, m * 64, n * 64, nullptr);
}

// projections: z = inv*2 + ab; Q|K -> projqk[z] (ld 512), V -> vt[z^1]
__global__ __launch_bounds__(256) void proj_kernel(
    const u16* __restrict__ s, int apack, int bpack, int ipack,
    const u16* __restrict__ projWt, const float* __restrict__ biasc,
    u16* __restrict__ projqk, u16* __restrict__ vt, int nwg)
{
    int wg = xcd_swz(blockIdx.x, nwg);
    int n = wg % 12, rest = wg / 12;
    int m = rest % 49, z = rest / 49;
    int inv = z >> 1, ab = z & 1;
    int ai = (apack >> (2*inv)) & 3;
    int bi = (bpack >> (2*inv)) & 3;
    int ii = (ipack >> (2*inv)) & 3;
    const u16* Aact = s + (size_t)(ab ? bi : ai) * MD;
    int widx = ii * 2 + ab;
    gemm_core(Aact, 256, projWt + (size_t)widx * 768 * 256, 256,
              biasc + widx * 768,
              projqk + (size_t)z * 2 * MD, 512, 0, m * 64, n * 64,
              vt + (size_t)(z ^ 1) * MD);
}

__global__ __launch_bounds__(256) void pack_bias_kernel(
    const float* b0, const float* b1, const float* b2,
    const float* b3, const float* b4, const float* b5,
    float* __restrict__ biasc)
{
    int z = blockIdx.x;
    int tsr = z >> 2, i = z & 3;
    const float* barr[6] = {b0,b1,b2,b3,b4,b5};
    int ab = (tsr >= 3) ? 1 : 0;
    biasc[(i*2 + ab)*768 + (tsr % 3)*256 + threadIdx.x] = barr[tsr][i*256 + threadIdx.x];
}

// ---------------- flash attention core, 32x32x16 MFMA, 32 q-rows/wave -------
// P stays fully in-register: S^T leaves lane(q,hi) holding P[q][k] with the
// hi-half interleave; two v_permlane32_swap_b32 per PV fragment exchange the
// halves (w0..w3 = {own u0[2kf+hi], own u1[..], partner u0[..], partner u1})
// -> no Ps LDS, no write/read roundtrip. LDS 18.4KB -> 8 blocks/CU.
__device__ __forceinline__ void attn3_core(
    const u16* __restrict__ Qg, int ldq,
    const u16* __restrict__ Kg, int ldk,
    const u16* __restrict__ Vtg,
    u16* __restrict__ Og, int ldo,
    int qt, int rowbase, int qkcol, int ocol)
{
    __shared__ u16 Ks[2][64][36];
    __shared__ u16 Vts[2][32][68];
    __shared__ float Ls[4][32];

    const int tid = threadIdx.x, wave = tid >> 6, lane = tid & 63;
    const int l32 = lane & 31, hi = lane >> 5;
    const int sr = tid >> 2, sc8 = (tid & 3) * 8;
    const int vd = tid >> 3, vk8 = (tid & 7) * 8;
    const float QSC = 0.25503489f;        // 32^-0.5 * log2(e)

    bf8_4 qf0, qf1;
    {
        int qrow = qt*128 + wave*32 + l32;
        u16x8 z8 = {0,0,0,0,0,0,0,0};
        u16x8 q0 = z8, q1 = z8;
        if (qrow < 784) {
            const u16* qp = Qg + (size_t)(rowbase + qrow) * ldq + qkcol;
            q0 = *(const u16x8*)(qp + hi*8);
            q1 = *(const u16x8*)(qp + 16 + hi*8);
        }
#pragma unroll
        for (int j = 0; j < 8; j++) {
            q0[j] = f2bf(bf2f(q0[j]) * QSC);
            q1[j] = f2bf(bf2f(q1[j]) * QSC);
        }
        qf0.v8 = q0;
        qf1.v8 = q1;
    }
    {
        u8_4 k, v;
        k.v8 = *(const u16x8*)(Kg + (size_t)(rowbase + sr) * ldk + qkcol + sc8);
        v.v8 = *(const u16x8*)(Vtg + (size_t)vd * 784 + vk8);
        *(u16x4*)&Ks[0][sr][sc8]     = k.v4[0];
        *(u16x4*)&Ks[0][sr][sc8 + 4] = k.v4[1];
        *(u16x4*)&Vts[0][vd][vk8]     = v.v4[0];
        *(u16x4*)&Vts[0][vd][vk8 + 4] = v.v4[1];
    }
    __syncthreads();

    f32x16 oacc;
#pragma unroll
    for (int i = 0; i < 16; i++) oacc[i] = 0.f;
    float lsum = 0.f;

    u16x8 kr, vr;
    for (int t = 0; t < 13; ++t) {
        const int cur = t & 1;
        if (t < 12) {
            u16x8 z8 = {0,0,0,0,0,0,0,0}; kr = z8; vr = z8;
            int krow = (t+1)*64 + sr;
            if (krow < 784)
                kr = *(const u16x8*)(Kg + (size_t)(rowbase + krow) * ldk + qkcol + sc8);
            int kc = (t+1)*64 + vk8;
            if (kc + 7 < 784)
                vr = *(const u16x8*)(Vtg + (size_t)vd * 784 + kc);
        }
#pragma unroll
        for (int kb2 = 0; kb2 < 2; kb2++) {
            if (t == 12 && kb2 == 1) break;   // tile 12 has 16 valid k only
            f32x16 sacc;
#pragma unroll
            for (int i = 0; i < 16; i++) sacc[i] = 0.f;
            bf8_4 kf0, kf1;
            kf0.h[0] = *(const u16x4*)&Ks[cur][kb2*32 + l32][hi*8];
            kf0.h[1] = *(const u16x4*)&Ks[cur][kb2*32 + l32][hi*8 + 4];
            kf1.h[0] = *(const u16x4*)&Ks[cur][kb2*32 + l32][16 + hi*8];
            kf1.h[1] = *(const u16x4*)&Ks[cur][kb2*32 + l32][16 + hi*8 + 4];
            sacc = __builtin_amdgcn_mfma_f32_32x32x16_bf16(kf0.f, qf0.f, sacc, 0,0,0);
            sacc = __builtin_amdgcn_mfma_f32_32x32x16_bf16(kf1.f, qf1.f, sacc, 0,0,0);
            unsigned u0[4], u1[4];
#pragma unroll
            for (int g = 0; g < 4; g++) {
                int k0 = kb2*32 + 8*g + 4*hi;
                if (t == 12 && k0 >= 16) { u0[g] = 0; u1[g] = 0; }
                else {
                    float p0 = exp2_hw(sacc[4*g+0]);
                    float p1 = exp2_hw(sacc[4*g+1]);
                    float p2 = exp2_hw(sacc[4*g+2]);
                    float p3 = exp2_hw(sacc[4*g+3]);
                    lsum += (p0 + p1) + (p2 + p3);
                    u0[g] = cvt_pk_bf16(p0, p1);
                    u1[g] = cvt_pk_bf16(p2, p3);
                }
            }
#pragma unroll
            for (int kf = 0; kf < 2; kf++) {
                if (t == 12 && kf == 1) break;   // only k<16 live in tail
                unsigned a0 = u0[2*kf], b0 = u0[2*kf+1];
                unsigned a1 = u1[2*kf], b1 = u1[2*kf+1];
                asm("v_permlane32_swap_b32 %0, %1" : "+v"(a0), "+v"(b0));
                asm("v_permlane32_swap_b32 %0, %1" : "+v"(a1), "+v"(b1));
                union { unsigned u[4]; bf16x8 f; } pf;
                pf.u[0] = a0; pf.u[1] = a1; pf.u[2] = b0; pf.u[3] = b1;
                int kbase = kb2*32 + kf*16;
                bf8_4 vf;
                vf.h[0] = *(const u16x4*)&Vts[cur][l32][kbase + hi*8];
                vf.h[1] = *(const u16x4*)&Vts[cur][l32][kbase + hi*8 + 4];
                oacc = __builtin_amdgcn_mfma_f32_32x32x16_bf16(pf.f, vf.f, oacc, 0,0,0);
            }
        }
        if (t < 12) {
            u8_4 k, v; k.v8 = kr; v.v8 = vr;
            *(u16x4*)&Ks[cur^1][sr][sc8]     = k.v4[0];
            *(u16x4*)&Ks[cur^1][sr][sc8 + 4] = k.v4[1];
            *(u16x4*)&Vts[cur^1][vd][vk8]     = v.v4[0];
            *(u16x4*)&Vts[cur^1][vd][vk8 + 4] = v.v4[1];
            __syncthreads();
        }
    }
    float lt = lsum + __shfl_xor(lsum, 32);
    if (hi == 0) Ls[wave][l32] = lt;
    f32x4 lv[4];
#pragma unroll
    for (int g = 0; g < 4; g++) lv[g] = *(const f32x4*)&Ls[wave][8*g + 4*hi];
#pragma unroll
    for (int g = 0; g < 4; g++)
#pragma unroll
        for (int j = 0; j < 4; j++) {
            int row = qt*128 + wave*32 + 8*g + 4*hi + j;
            if (row < 784)
                Og[(size_t)(rowbase + row) * ldo + ocol + l32] =
                    f2bf(oacc[4*g+j] * __builtin_amdgcn_rcpf(lv[g][j]));
        }
}

// attention over nz sides: grid = 224*nz; z = inv*2 + dir
__global__ __launch_bounds__(256) void attn_pair_kernel(
    const u16* __restrict__ projqk, const u16* __restrict__ vt,
    u16* __restrict__ fin)
{
    int id = blockIdx.x;
    int nper = gridDim.x >> 3;
    int wg = (id & 7) * nper + (id >> 3);
    int qt = wg % 7, bh = (wg / 7) & 31, z = wg / 224;
    int inv = z >> 1, dir = z & 1;
    const u16* Q  = projqk + (size_t)z * 2 * MD;
    const u16* K  = projqk + (size_t)(z ^ 1) * 2 * MD + 256;
    const u16* Vt = vt + (size_t)z * MD + (size_t)bh * 32 * 784;
    u16* O = fin + (size_t)inv * 2 * MD;
    int bb = bh >> 3, hh = bh & 7;
    attn3_core(Q, 512, K, 512, Vt, O, 512, qt, bb*784, hh*32, dir*256 + hh*32);
}

__global__ __launch_bounds__(256) void attn_mha_kernel(
    const u16* __restrict__ qkv, const u16* __restrict__ vtmha,
    u16* __restrict__ outp)
{
    int id = blockIdx.x;
    int wg = (id & 7) * 28 + (id >> 3);       // 224/8 = 28
    int qt = wg % 7, bh = wg / 7;
    int bb = bh >> 3, hh = bh & 7;
    const u16* Vt = vtmha + (size_t)bh * 32 * 784;
    attn3_core(qkv, 768, qkv + 256, 768, Vt, outp, 256, qt, bb*784, hh*32, hh*32);
}

// ---------------- LayerNorm: out = os*LN(res + tg*x) -----------------------
__global__ __launch_bounds__(256) void ln_kernel(
    const u16* __restrict__ x, size_t zx,
    const u16* __restrict__ res, size_t zres, int respack,
    const float* __restrict__ gamma, int gpack,
    const float* __restrict__ g, const float* __restrict__ beta, int gN,
    u16* __restrict__ out, size_t zout,
    float outscale, int D)
{
    int z = blockIdx.y;
    int gi = (gpack >> (2*z)) & 3;
    const u16* xb = x + (size_t)z * zx;
    const u16* rb = res ? res + (size_t)z * zres + (size_t)((respack >> (2*z)) & 3) * MD
                        : (const u16*)nullptr;
    u16* ob = out + (size_t)z * zout;
    const float* gg = g + gi * gN;
    const float* bb = beta + gi * gN;
    int wave = threadIdx.x >> 6, lane = threadIdx.x & 63;
    int half = lane >> 5, l32 = lane & 31;
    size_t row = (size_t)blockIdx.x * 8 + wave * 2 + half;
    float tg = gamma ? tanhf(gamma[gi]) : 1.0f;
    const u16* xr = xb + row * D;
    const u16* rr = rb ? rb + row * D : (const u16*)nullptr;
    float vals[32];
    int nch = D >> 8;
    float s = 0.f, s2 = 0.f;
    for (int c = 0; c < nch; c++) {
        int col = c * 256 + l32 * 8;
        u16x8 v = *(const u16x8*)(xr + col);
        u16x8 r8 = {0,0,0,0,0,0,0,0};
        if (rr) r8 = *(const u16x8*)(rr + col);
#pragma unroll
        for (int j = 0; j < 8; j++) {
            float a = tg * bf2f(v[j]) + bf2f(r8[j]);
            vals[c*8 + j] = a;
            s += a; s2 += a * a;
        }
    }
#pragma unroll
    for (int off = 1; off < 32; off <<= 1) {
        s  += __shfl_xor(s, off);
        s2 += __shfl_xor(s2, off);
    }
    float inv = 1.0f / D;
    float mean = s * inv;
    float var = s2 * inv - mean * mean;
    float rstd = rsqrtf(var + 1e-5f);
    for (int c = 0; c < nch; c++) {
        int col = c * 256 + l32 * 8;
        u16x8 o8;
#pragma unroll
        for (int j = 0; j < 8; j++) {
            float o = (vals[c*8 + j] - mean) * rstd * gg[col + j] + bb[col + j];
            o8[j] = f2bf(o * outscale);
        }
        *(u16x8*)(ob + row*D + col) = o8;
    }
}

// ---------------- layout kernels --------------------------------------------
__device__ __forceinline__ void transpose_body(const float* in, u16* out,
                                               int K, int N, int bx, int by)
{
    __shared__ float t[32][33];
    int tx = threadIdx.x, ty = threadIdx.y;   // (32,8)
#pragma unroll
    for (int j = 0; j < 4; j++)
        t[ty + j*8][tx] = in[(size_t)(by*32 + ty + j*8) * N + bx*32 + tx];
    __syncthreads();
#pragma unroll
    for (int j = 0; j < 4; j++)
        out[(size_t)(bx*32 + ty + j*8) * K + by*32 + tx] =
            f2bf(t[tx][ty + j*8]);
}

struct TDesc { const float* in; u16* out; int K, N, start, bpz; };
struct TPack7 { TDesc d[7]; };

// merged weight transposes: 3136 blocks, 7 descriptors
__global__ __launch_bounds__(256) void tmerge_kernel(TPack7 p)
{
    int bid = blockIdx.x;
    int di = 0;
#pragma unroll
    for (int i = 1; i < 7; i++) if (bid >= p.d[i].start) di = i;
    TDesc d = p.d[di];
    int local = bid - d.start;
    int zz = local / d.bpz, rem = local - zz * d.bpz;
    int nbx = d.N >> 5;
    int bx = rem % nbx, by = rem / nbx;
    transpose_body(d.in + (size_t)zz * d.K * d.N,
                   d.out + (size_t)zz * d.K * d.N, d.K, d.N, bx, by);
}

// proj weights into cat layout: [i][ab][768 n][256 k]
__global__ __launch_bounds__(256) void transpose_w6(
    const float* w0, const float* w1, const float* w2,
    const float* w3, const float* w4, const float* w5,
    u16* __restrict__ out)
{
    int z = blockIdx.z;           // 0..23: tsr = z/4, i = z%4
    int tsr = z >> 2, i = z & 3;
    const float* ws[6] = {w0,w1,w2,w3,w4,w5};
    int ab = (tsr >= 3) ? 1 : 0;
    u16* ob = out + (size_t)((i*2 + ab)*3 + (tsr % 3)) * 65536;
    transpose_body(ws[tsr] + (size_t)i * 65536, ob, 256, 256,
                   blockIdx.x, blockIdx.y);
}

// transpose V (cols 512..767 of 768-wide qkv) -> [bh*32+d][784]
__global__ __launch_bounds__(256) void vtrans_kernel(
    const u16* __restrict__ base,
    u16* __restrict__ out)
{
    __shared__ u16 t[64][44];
    const u16* in = base + 512;
    int kt = blockIdx.x, bh = blockIdx.y;
    int bb = bh >> 3, hh = bh & 7;
    int tid = threadIdx.x;
    {
        int r = tid >> 2, c8 = (tid & 3) * 8;
        int krow = kt*64 + r;
        u16x8 u = {0,0,0,0,0,0,0,0};
        if (krow < 784)
            u = *(const u16x8*)(in + (size_t)(bb*784 + krow) * 768 + hh*32 + c8);
        *(u16x8*)&t[r][c8] = u;
    }
    __syncthreads();
    int d = tid >> 3, k8 = (tid & 7) * 8;
    if (kt*64 + k8 + 7 < 784) {
        u16x8 u;
#pragma unroll
        for (int j = 0; j < 8; j++) u[j] = t[k8 + j][d];
        *(u16x8*)&out[(size_t)(bh*32 + d) * 784 + kt*64 + k8] = u;
    }
}

// f[B,256,28,28] fp32 -> s[fi][b*784+hw][d] bf16
__global__ __launch_bounds__(256) void to_seq_kernel(
    const float* f0, const float* f1, const float* f2, const float* f3,
    u16* __restrict__ sbase)
{
    __shared__ float t[16][17];
    int z = blockIdx.z;
    int fi = z & 3, b = z >> 2;
    const float* fs[4] = {f0,f1,f2,f3};
    const float* f = fs[fi] + (size_t)b * 256 * 784;
    u16* s = sbase + (size_t)fi * MD + (size_t)b * 784 * 256;
    int tx = threadIdx.x, ty = threadIdx.y;  // (16,16)
    t[ty][tx] = f[(size_t)(blockIdx.y*16 + ty) * 784 + blockIdx.x*16 + tx];
    __syncthreads();
    s[(size_t)(blockIdx.x*16 + ty) * 256 + blockIdx.y*16 + tx] = f2bf(t[tx][ty]);
}

// y[b*784+hw][d] bf16 -> out[b][d][h][w] fp32
__global__ __launch_bounds__(256) void from_seq_kernel(const u16* __restrict__ y,
                                                       float* __restrict__ out)
{
    __shared__ float t[16][17];
    int b = blockIdx.z;
    const u16* yb = y + (size_t)b * 784 * 256;
    float* ob = out + (size_t)b * 256 * 784;
    int tx = threadIdx.x, ty = threadIdx.y;
    t[ty][tx] = bf2f(yb[(size_t)(blockIdx.x*16 + ty) * 256 + blockIdx.y*16 + tx]);
    __syncthreads();
    ob[(size_t)(blockIdx.y*16 + ty) * 784 + blockIdx.x*16 + tx] = t[tx][ty];
}

// ---------------- host orchestration ----------------------------------------
extern "C" void kernel_launch(void* const* d_in, const int* in_sizes, int n_in,
                              void* d_out, int out_size, void* d_ws, size_t ws_size,
                              hipStream_t stream)
{
    (void)in_sizes; (void)n_in; (void)out_size;
    const float* f0 = (const float*)d_in[0];
    const float* f1 = (const float*)d_in[1];
    const float* f2 = (const float*)d_in[2];
    const float* f3 = (const float*)d_in[3];
    const float* Wq_a = (const float*)d_in[4];
    const float* Wk_a = (const float*)d_in[5];
    const float* Wv_a = (const float*)d_in[6];
    const float* Wq_b = (const float*)d_in[7];
    const float* Wk_b = (const float*)d_in[8];
    const float* Wv_b = (const float*)d_in[9];
    const float* bq_a = (const float*)d_in[10];
    const float* bk_a = (const float*)d_in[11];
    const float* bv_a = (const float*)d_in[12];
    const float* bq_b = (const float*)d_in[13];
    const float* bk_b = (const float*)d_in[14];
    const float* bv_b = (const float*)d_in[15];
    const float* gamma = (const float*)d_in[16];
    const float* gamma_ffn = (const float*)d_in[17];
    const float* Wfuse = (const float*)d_in[18];
    const float* bfuse = (const float*)d_in[19];
    const float* W1 = (const float*)d_in[20];
    const float* b1 = (const float*)d_in[21];
    const float* W2 = (const float*)d_in[22];
    const float* b2 = (const float*)d_in[23];
    const float* ln1_g = (const float*)d_in[24];
    const float* ln1_b = (const float*)d_in[25];
    const float* ln2_g = (const float*)d_in[26];
    const float* ln2_b = (const float*)d_in[27];
    const float* fp_ln_g = (const float*)d_in[28];
    const float* fp_ln_b = (const float*)d_in[29];
    const float* fp_W = (const float*)d_in[30];
    const float* fp_b = (const float*)d_in[31];
    const float* ff_ln_g = (const float*)d_in[32];
    const float* ff_ln_b = (const float*)d_in[33];
    const float* ff_W = (const float*)d_in[34];
    const float* ff_b = (const float*)d_in[35];
    const float* mha_Wqkv = (const float*)d_in[36];
    const float* mha_bqkv = (const float*)d_in[37];
    const float* mha_Wo = (const float*)d_in[38];
    const float* mha_bo = (const float*)d_in[39];
    const float* norm_g = (const float*)d_in[40];
    const float* norm_b = (const float*)d_in[41];

    u16* W = (u16*)d_ws;
    u16* projWt = W;                          // 1572864
    u16* fuseWt = projWt + 1572864;           // 524288
    u16* W1t    = fuseWt + 524288;            // 1048576
    u16* W2t    = W1t + 1048576;              // 1048576
    u16* fpWt   = W2t + 1048576;              // 65536
    u16* ffWt   = fpWt + 65536;               // 262144
    u16* qkvWt  = ffWt + 262144;              // 196608
    u16* WoWt   = qkvWt + 196608;             // 65536
    float* biasc = (float*)(WoWt + 65536);    // 6144 floats
    u16* act    = (u16*)(biasc + 6144);

    u16* s    = act;                 // 4 MD
    u16* e8   = act + 4*MD;          // 8 MD
    u16* main_ = act + 12*MD;        // projqk | vt | fin

    const size_t actbytes_merged = (size_t)2 * 76 * MD;
    const size_t weights_bytes = (size_t)((char*)act - (char*)d_ws);
    const bool merged = ws_size >= weights_bytes + actbytes_merged;

    // prologue
    to_seq_kernel<<<dim3(49,16,16), dim3(16,16), 0, stream>>>(f0,f1,f2,f3, s);
    transpose_w6<<<dim3(8,8,24), dim3(32,8), 0, stream>>>(Wq_a,Wk_a,Wv_a,Wq_b,Wk_b,Wv_b, projWt);
    pack_bias_kernel<<<24, 256, 0, stream>>>(bq_a,bk_a,bv_a,bq_b,bk_b,bv_b, biasc);
    {
        TPack7 tp;
        tp.d[0] = { Wfuse,    fuseWt, 512, 256,    0, 128 };
        tp.d[1] = { W1,       W1t,    256, 1024, 512, 256 };
        tp.d[2] = { W2,       W2t,   1024, 256, 1536, 256 };
        tp.d[3] = { fp_W,     fpWt,   256, 256, 2560,  64 };
        tp.d[4] = { ff_W,     ffWt,  1024, 256, 2624, 256 };
        tp.d[5] = { mha_Wqkv, qkvWt,  256, 768, 2880, 192 };
        tp.d[6] = { mha_Wo,   WoWt,   256, 256, 3072,  64 };
        tmerge_kernel<<<3136, dim3(32,8), 0, stream>>>(tp);
    }

    // 8 invocations: bi -> (i, a, b):
    const int IA[8] = {0,1,0,2,2,3,1,3};
    const int AA[8] = {0,0,1,1,2,2,3,3};
    const int BB[8] = {1,3,0,2,1,3,0,2};

    if (merged) {
        u16* projqk = main_;            // 32 MD
        u16* vt  = main_ + 32*MD;       // 16 MD
        u16* fin = main_ + 48*MD;       // 16 MD
        u16* ffh = projqk;              // 32 MD overlay
        u16* fb  = vt;                  // 8 MD overlay
        u16* xa1 = vt + 8*MD;           // 8 MD overlay
        u16* ffb = fin;                 // 8 MD overlay
        int ip = 0, apk = 0, bpk = 0;
        for (int j = 0; j < 8; j++) {
            ip  |= IA[j] << (2*j);
            apk |= AA[j] << (2*j);
            bpk |= BB[j] << (2*j);
        }
        proj_kernel<<<9408, 256, 0, stream>>>(s, apk, bpk, ip,
            projWt, biasc, projqk, vt, 9408);
        attn_pair_kernel<<<3584, 256, 0, stream>>>(projqk, vt, fin);
        gemm2_kernel<<<1568, 256, 0, stream>>>(fin, 512, (int)(2*MD),
            fuseWt, 512, ip, 131072, bfuse, 256, fb, 256, (int)MD, 0, 4, 1568);
        ln_kernel<<<dim3(392,8), 256, 0, stream>>>(fb, MD,
            s, 0, apk, gamma, ip, ln1_g, ln1_b, 256, xa1, MD, 1.0f, 256);
        gemm2_kernel<<<6272, 256, 0, stream>>>(xa1, 256, (int)MD,
            W1t, 256, ip, 262144, b1, 1024, ffh, 1024, (int)(4*MD), 1, 16, 6272);
        gemm2_kernel<<<1568, 256, 0, stream>>>(ffh, 1024, (int)(4*MD),
            W2t, 1024, ip, 262144, b2, 256, ffb, 256, (int)MD, 0, 4, 1568);
        ln_kernel<<<dim3(392,8), 256, 0, stream>>>(ffb, MD,
            xa1, MD, 0, gamma_ffn, ip, ln2_g, ln2_b, 256, e8, MD, 0.5f, 256);
    } else {
        u16* projqk = main_;            // 16 MD
        u16* vt  = main_ + 16*MD;       // 8 MD
        u16* fin = main_ + 24*MD;       // 8 MD
        u16* ffh = projqk;              // 16 MD overlay
        u16* fb  = vt;                  // 4 MD overlay
        u16* xa1 = vt + 4*MD;           // 4 MD overlay
        u16* ffb = fin;                 // 4 MD overlay
        for (int g = 0; g < 2; g++) {
            int ip = 0, apk = 0, bpk = 0;
            for (int j = 0; j < 4; j++) {
                int bi = 2*j + g;
                ip  |= IA[bi] << (2*j);
                apk |= AA[bi] << (2*j);
                bpk |= BB[bi] << (2*j);
            }
            proj_kernel<<<4704, 256, 0, stream>>>(s, apk, bpk, ip,
                projWt, biasc, projqk, vt, 4704);
            attn_pair_kernel<<<1792, 256, 0, stream>>>(projqk, vt, fin);
            gemm2_kernel<<<784, 256, 0, stream>>>(fin, 512, (int)(2*MD),
                fuseWt, 512, ip, 131072, bfuse, 256, fb, 256, (int)MD, 0, 4, 784);
            ln_kernel<<<dim3(392,4), 256, 0, stream>>>(fb, MD,
                s, 0, apk, gamma, ip, ln1_g, ln1_b, 256, xa1, MD, 1.0f, 256);
            gemm2_kernel<<<3136, 256, 0, stream>>>(xa1, 256, (int)MD,
                W1t, 256, ip, 262144, b1, 1024, ffh, 1024, (int)(4*MD), 1, 16, 3136);
            gemm2_kernel<<<784, 256, 0, stream>>>(ffh, 1024, (int)(4*MD),
                W2t, 1024, ip, 262144, b2, 256, ffb, 256, (int)MD, 0, 4, 784);
            ln_kernel<<<dim3(392,4), 256, 0, stream>>>(ffb, MD,
                xa1, MD, 0, gamma_ffn, ip, ln2_g, ln2_b, 256,
                e8 + (size_t)g*MD, 2*MD, 0.5f, 256);
        }
    }

    // final fuse stage (region main_; e8 live until ln4 done)
    u16* ln4    = main_;             // 4 MD
    u16* allf   = main_ + 4*MD;      // 4 MD  [3136][1024]
    u16* ffln   = main_ + 8*MD;      // 4 MD
    u16* x2     = main_ + 12*MD;     // 1 MD
    u16* qkv    = main_ + 13*MD;     // 3 MD  [3136][768]
    u16* vtmha  = main_ + 16*MD;     // 1 MD
    u16* attn_o = main_ + 17*MD;     // 1 MD
    u16* ymid   = main_ + 18*MD;     // 1 MD
    u16* yfin   = main_ + 19*MD;     // 1 MD

    ln_kernel<<<dim3(392,4), 256, 0, stream>>>(e8, 2*MD,
        e8 + MD, 2*MD, 0, (const float*)nullptr, 0,
        fp_ln_g, fp_ln_b, 0, ln4, MD, 1.0f, 256);
    gemm2_kernel<<<784, 256, 0, stream>>>(ln4, 256, (int)MD,
        fpWt, 256, 0, 0, fp_b, 0, allf, 1024, 256, 1, 4, 784);
    ln_kernel<<<dim3(392,1), 256, 0, stream>>>(allf, 0,
        (const u16*)nullptr, 0, 0, (const float*)nullptr, 0,
        ff_ln_g, ff_ln_b, 0, ffln, 0, 1.0f, 1024);
    gemm2_kernel<<<196, 256, 0, stream>>>(ffln, 1024, 0,
        ffWt, 1024, 0, 0, ff_b, 0, x2, 256, 0, 1, 4, 196);
    gemm2_kernel<<<588, 256, 0, stream>>>(x2, 256, 0,
        qkvWt, 256, 0, 0, mha_bqkv, 0, qkv, 768, 0, 0, 12, 588);
    vtrans_kernel<<<dim3(13,32), 256, 0, stream>>>(qkv, vtmha);
    attn_mha_kernel<<<224, 256, 0, stream>>>(qkv, vtmha, attn_o);
    gemm2_kernel<<<196, 256, 0, stream>>>(attn_o, 256, 0,
        WoWt, 256, 0, 0, mha_bo, 0, ymid, 256, 0, 0, 4, 196);
    ln_kernel<<<dim3(392,1), 256, 0, stream>>>(ymid, 0,
        (const u16*)nullptr, 0, 0, (const float*)nullptr, 0,
        norm_g, norm_b, 0, yfin, 0, 1.0f, 256);
    from_seq_kernel<<<dim3(49,16,4), dim3(16,16), 0, stream>>>(yfin, (float*)d_out);
}